// Round 1
// baseline (1048.077 us; speedup 1.0000x reference)
//
#include <hip/hip_runtime.h>

#define N_NODES   8000
#define N_EDGES   128000
#define N_GRAPHS  64
#define DIM       256
#define IN_DIM    128

// ---------------------------------------------------------------------------
// CSR build
// ---------------------------------------------------------------------------
__global__ __launch_bounds__(256) void k_count(const int* __restrict__ dst,
                                               int* __restrict__ counts) {
  int e = blockIdx.x * 256 + threadIdx.x;
  if (e < N_EDGES) atomicAdd(&counts[dst[e]], 1);
}

__global__ __launch_bounds__(256) void k_scan(const int* __restrict__ counts,
                                              int* __restrict__ row_ofs,
                                              int* __restrict__ cursor,
                                              float* __restrict__ invdeg) {
  __shared__ int chunk[256];
  const int per = (N_NODES + 255) / 256;  // 32
  int t = threadIdx.x;
  int base = t * per;
  int s = 0;
  for (int i = 0; i < per; ++i) {
    int idx = base + i;
    if (idx < N_NODES) s += counts[idx];
  }
  chunk[t] = s;
  __syncthreads();
  for (int off = 1; off < 256; off <<= 1) {
    int v = 0;
    if (t >= off) v = chunk[t - off];
    __syncthreads();
    if (t >= off) chunk[t] += v;
    __syncthreads();
  }
  int run = (t > 0) ? chunk[t - 1] : 0;
  for (int i = 0; i < per; ++i) {
    int idx = base + i;
    if (idx < N_NODES) {
      row_ofs[idx] = run;
      cursor[idx] = run;
      int c = counts[idx];
      invdeg[idx] = 1.0f / (float)(c > 1 ? c : 1);
      run += c;
    }
  }
  if (t == 0) row_ofs[N_NODES] = chunk[255];
}

__global__ __launch_bounds__(256) void k_fill(const int* __restrict__ src,
                                              const int* __restrict__ dst,
                                              int* __restrict__ cursor,
                                              int* __restrict__ csr_src) {
  int e = blockIdx.x * 256 + threadIdx.x;
  if (e < N_EDGES) {
    int p = atomicAdd(&cursor[dst[e]], 1);
    csr_src[p] = src[e];
  }
}

// ---------------------------------------------------------------------------
// Softmax over the 20 architecture rows (4 candidates each)
// wsoft layout: [0..23]=wf (6x4), [24..39]=wm (4x4), [40..79]=wl (10x4)
// ---------------------------------------------------------------------------
__global__ __launch_bounds__(64) void k_softmax(const float* __restrict__ af,
                                                const float* __restrict__ am,
                                                const float* __restrict__ al,
                                                float* __restrict__ w) {
  int t = threadIdx.x;
  const float* sp;
  float* dp;
  if (t < 6)       { sp = af + t * 4;        dp = w + t * 4; }
  else if (t < 10) { sp = am + (t - 6) * 4;  dp = w + 24 + (t - 6) * 4; }
  else if (t < 20) { sp = al + (t - 10) * 4; dp = w + 40 + (t - 10) * 4; }
  else return;
  float a0 = sp[0], a1 = sp[1], a2 = sp[2], a3 = sp[3];
  float m = fmaxf(fmaxf(a0, a1), fmaxf(a2, a3));
  float e0 = expf(a0 - m), e1 = expf(a1 - m), e2 = expf(a2 - m), e3 = expf(a3 - m);
  float si = 1.0f / (e0 + e1 + e2 + e3);
  dp[0] = e0 * si; dp[1] = e1 * si; dp[2] = e2 * si; dp[3] = e3 * si;
}

// ---------------------------------------------------------------------------
// Segment reductions over CSR (one block per node, 256 threads = 256 dims)
// ---------------------------------------------------------------------------
__global__ __launch_bounds__(256) void k_segmean(const float* __restrict__ X,
                                                 const int* __restrict__ row_ofs,
                                                 const int* __restrict__ csr_src,
                                                 const float* __restrict__ invdeg,
                                                 float* __restrict__ out) {
  int i = blockIdx.x, t = threadIdx.x;
  int beg = row_ofs[i], end = row_ofs[i + 1];
  float s = 0.f;
  for (int e = beg; e < end; ++e) {
    int si = csr_src[e];
    s += X[(size_t)si * DIM + t];
  }
  out[(size_t)i * DIM + t] = s * invdeg[i];
}

// two segment-means sharing the CSR walk
__global__ __launch_bounds__(256) void k_segmean2(const float* __restrict__ X0,
                                                  const float* __restrict__ X1,
                                                  const int* __restrict__ row_ofs,
                                                  const int* __restrict__ csr_src,
                                                  const float* __restrict__ invdeg,
                                                  float* __restrict__ out0,
                                                  float* __restrict__ out1) {
  int i = blockIdx.x, t = threadIdx.x;
  int beg = row_ofs[i], end = row_ofs[i + 1];
  float s0 = 0.f, s1 = 0.f;
  for (int e = beg; e < end; ++e) {
    int si = csr_src[e];
    s0 += X0[(size_t)si * DIM + t];
    s1 += X1[(size_t)si * DIM + t];
  }
  float iv = invdeg[i];
  out0[(size_t)i * DIM + t] = s0 * iv;
  out1[(size_t)i * DIM + t] = s1 * iv;
}

// sum + max over incoming msgs of a relu'd (>=0) input; epilogue computes the
// middle-stage mixture; optionally also writes the mean (used as DAG agg).
__global__ __launch_bounds__(256) void k_segmid(const float* __restrict__ Xn,
                                                const int* __restrict__ row_ofs,
                                                const int* __restrict__ csr_src,
                                                const float* __restrict__ invdeg,
                                                const float* __restrict__ wrow,
                                                float* __restrict__ mean_out,
                                                float* __restrict__ mids_out) {
  int i = blockIdx.x, t = threadIdx.x;
  int beg = row_ofs[i], end = row_ofs[i + 1];
  float s = 0.f, mx = 0.f;  // inputs are relu outputs (>= 0); has_nb handled by mx=0 init
  for (int e = beg; e < end; ++e) {
    int si = csr_src[e];
    float v = Xn[(size_t)si * DIM + t];
    s += v;
    mx = fmaxf(mx, v);
  }
  float mean = s * invdeg[i];
  if (mean_out) mean_out[(size_t)i * DIM + t] = mean;
  float w0 = wrow[0], w1 = wrow[1], w2 = wrow[2], w3 = wrow[3];
  float xn = Xn[(size_t)i * DIM + t];
  mids_out[(size_t)i * DIM + t] = w0 * xn + w1 * mx + w2 * mean + w3 * s;
}

// ---------------------------------------------------------------------------
// Generic multi-term GEMM:
//   out = [resid + 0.5*(addl + )] relu( sum_t c_t*(A_t@W_t + b_t) + sum_u ic_u*I_u )
// All A_t are M x K (row stride K), W_t are K x 256, out is M x 256.
// 64x64 tile per block, 256 threads, 4x4 accum per thread.
// ---------------------------------------------------------------------------
struct GemmDesc {
  const float* A[6]; const float* W[6]; const float* b[6]; const float* c[6];
  const float* I[3]; const float* ic[3];
  const float* resid; const float* addl;
  int nmat; int nid; int K; int relu;
};

__global__ __launch_bounds__(256) void k_gemm(GemmDesc d, float* __restrict__ out) {
  const int bm = blockIdx.x * 64;
  const int bn = blockIdx.y * 64;
  __shared__ float As[16][64];
  __shared__ float Bs[16][64];
  const int tid = threadIdx.x;
  const int tm = tid >> 4, tn = tid & 15;          // 16x16 thread grid, 4x4 each
  const int lm = tid >> 2, lk4 = (tid & 3) * 4;    // A-tile load mapping
  const int lkB = tid >> 4, lnB = (tid & 15) * 4;  // W-tile load mapping
  float acc[4][4] = {};
  const int K = d.K;
  for (int t = 0; t < d.nmat; ++t) {
    const float* __restrict__ A = d.A[t];
    const float* __restrict__ W = d.W[t];
    const float coef = d.c[t] ? *d.c[t] : 1.0f;
    for (int k0 = 0; k0 < K; k0 += 16) {
      float4 av = *(const float4*)(A + (size_t)(bm + lm) * K + k0 + lk4);
      As[lk4 + 0][lm] = coef * av.x;
      As[lk4 + 1][lm] = coef * av.y;
      As[lk4 + 2][lm] = coef * av.z;
      As[lk4 + 3][lm] = coef * av.w;
      *(float4*)&Bs[lkB][lnB] =
          *(const float4*)(W + (size_t)(k0 + lkB) * DIM + bn + lnB);
      __syncthreads();
#pragma unroll
      for (int kk = 0; kk < 16; ++kk) {
        const float4 a = *(const float4*)&As[kk][tm * 4];
        const float4 b = *(const float4*)&Bs[kk][tn * 4];
        const float ar[4] = {a.x, a.y, a.z, a.w};
        const float br[4] = {b.x, b.y, b.z, b.w};
#pragma unroll
        for (int i = 0; i < 4; ++i)
#pragma unroll
          for (int j = 0; j < 4; ++j) acc[i][j] = fmaf(ar[i], br[j], acc[i][j]);
      }
      __syncthreads();
    }
  }
  // epilogue
  float bias[4] = {0.f, 0.f, 0.f, 0.f};
  for (int t = 0; t < d.nmat; ++t) {
    if (d.b[t]) {
      float coef = d.c[t] ? *d.c[t] : 1.0f;
#pragma unroll
      for (int j = 0; j < 4; ++j) bias[j] += coef * d.b[t][bn + tn * 4 + j];
    }
  }
  float icf[3];
  for (int u = 0; u < d.nid; ++u) icf[u] = *d.ic[u];
#pragma unroll
  for (int i = 0; i < 4; ++i) {
    int row = bm + tm * 4 + i;
    size_t rb = (size_t)row * DIM;
#pragma unroll
    for (int j = 0; j < 4; ++j) {
      int col = bn + tn * 4 + j;
      float v = acc[i][j] + bias[j];
      for (int u = 0; u < d.nid; ++u) v += icf[u] * d.I[u][rb + col];
      if (d.relu) v = fmaxf(v, 0.f);
      if (d.resid) v = d.resid[rb + col] + 0.5f * (d.addl[rb + col] + v);
      out[rb + col] = v;
    }
  }
}

// ---------------------------------------------------------------------------
// Readout: per-graph mean (graph_ids sorted) then 256->128->64->10 MLP
// ---------------------------------------------------------------------------
__global__ __launch_bounds__(256) void k_readout(const float* __restrict__ x,
                                                 const int* __restrict__ gid,
                                                 float* __restrict__ hg) {
  int g = blockIdx.x, t = threadIdx.x;
  int lo = 0, hi = N_NODES;
  while (lo < hi) { int m = (lo + hi) >> 1; if (gid[m] < g) lo = m + 1; else hi = m; }
  int beg = lo;
  lo = beg; hi = N_NODES;
  while (lo < hi) { int m = (lo + hi) >> 1; if (gid[m] <= g) lo = m + 1; else hi = m; }
  int end = lo;
  float s = 0.f;
  for (int i = beg; i < end; ++i) s += x[(size_t)i * DIM + t];
  int cnt = end - beg;
  hg[g * DIM + t] = s / (float)(cnt > 1 ? cnt : 1);
}

__global__ __launch_bounds__(256) void k_mlp(const float* __restrict__ hg,
                                             const float* __restrict__ C1,
                                             const float* __restrict__ c1b,
                                             const float* __restrict__ C2,
                                             const float* __restrict__ c2b,
                                             const float* __restrict__ C3,
                                             const float* __restrict__ c3b,
                                             float* __restrict__ out) {
  int g = blockIdx.x, t = threadIdx.x;
  __shared__ float h0[256], h1[128], h2[64];
  h0[t] = hg[g * DIM + t];
  __syncthreads();
  if (t < 128) {
    float s = c1b[t];
    for (int k = 0; k < 256; ++k) s = fmaf(h0[k], C1[k * 128 + t], s);
    h1[t] = fmaxf(s, 0.f);
  }
  __syncthreads();
  if (t < 64) {
    float s = c2b[t];
    for (int k = 0; k < 128; ++k) s = fmaf(h1[k], C2[k * 64 + t], s);
    h2[t] = fmaxf(s, 0.f);
  }
  __syncthreads();
  if (t < 10) {
    float s = c3b[t];
    for (int k = 0; k < 64; ++k) s = fmaf(h2[k], C3[k * 10 + t], s);
    out[g * 10 + t] = s;
  }
}

// ---------------------------------------------------------------------------
extern "C" void kernel_launch(void* const* d_in, const int* in_sizes, int n_in,
                              void* d_out, int out_size, void* d_ws, size_t ws_size,
                              hipStream_t stream) {
  const float* h     = (const float*)d_in[0];
  const float* W_emb = (const float*)d_in[1];
  const float* b_emb = (const float*)d_in[2];
  const float* Wf_d  = (const float*)d_in[3];
  const float* bf_d  = (const float*)d_in[4];
  const float* Wf_s  = (const float*)d_in[5];
  const float* bf_s  = (const float*)d_in[6];
  const float* Wl_d  = (const float*)d_in[7];
  const float* bl_d  = (const float*)d_in[8];
  const float* Wl_s  = (const float*)d_in[9];
  const float* bl_s  = (const float*)d_in[10];
  const float* a_first = (const float*)d_in[11];
  const float* a_mid   = (const float*)d_in[12];
  const float* a_last  = (const float*)d_in[13];
  const float* C1 = (const float*)d_in[14];
  const float* c1b = (const float*)d_in[15];
  const float* C2 = (const float*)d_in[16];
  const float* c2b = (const float*)d_in[17];
  const float* C3 = (const float*)d_in[18];
  const float* c3b = (const float*)d_in[19];
  const int* src = (const int*)d_in[20];
  const int* dst = (const int*)d_in[21];
  const int* gid = (const int*)d_in[22];
  (void)in_sizes; (void)n_in; (void)out_size; (void)ws_size;

  // workspace carve-up
  char* p = (char*)d_ws;
  auto alloc = [&](size_t bytes) {
    void* r = (void*)p;
    p += (bytes + 255) & ~(size_t)255;
    return r;
  };
  const size_t NB = (size_t)N_NODES * DIM * sizeof(float);  // 8.192 MB
  float* x     = (float*)alloc(NB);
  float* s1    = (float*)alloc(NB);
  float* s2    = (float*)alloc(NB);
  float* mids0 = (float*)alloc(NB);
  float* mids1 = (float*)alloc(NB);
  float* l0    = (float*)alloc(NB);
  float* aggA  = (float*)alloc(NB);
  float* aggB  = (float*)alloc(NB);
  float* invdeg = (float*)alloc(N_NODES * sizeof(float));
  int* counts  = (int*)alloc(N_NODES * sizeof(int));
  int* row_ofs = (int*)alloc((N_NODES + 1) * sizeof(int));
  int* cursor  = (int*)alloc(N_NODES * sizeof(int));
  int* csr_src = (int*)alloc(N_EDGES * sizeof(int));
  float* wsoft = (float*)alloc(80 * sizeof(float));
  float* hg    = (float*)alloc(N_GRAPHS * DIM * sizeof(float));

  const int EB = (N_EDGES + 255) / 256;  // 500

  hipMemsetAsync(counts, 0, N_NODES * sizeof(int), stream);
  k_count<<<EB, 256, 0, stream>>>(dst, counts);
  k_scan<<<1, 256, 0, stream>>>(counts, row_ofs, cursor, invdeg);
  k_fill<<<EB, 256, 0, stream>>>(src, dst, cursor, csr_src);
  k_softmax<<<1, 64, 0, stream>>>(a_first, a_mid, a_last, wsoft);

  const dim3 ggrid(N_NODES / 64, DIM / 64);  // 125 x 4

  // embedding: x = h @ W_emb + b_emb
  {
    GemmDesc d{};
    d.A[0] = h; d.W[0] = W_emb; d.b[0] = b_emb; d.c[0] = nullptr;
    d.nmat = 1; d.nid = 0; d.K = IN_DIM; d.relu = 0;
    d.resid = nullptr; d.addl = nullptr;
    k_gemm<<<ggrid, 256, 0, stream>>>(d, x);
  }

  const float* wf = wsoft;       // 6 rows
  const float* wm = wsoft + 24;  // 4 rows
  const float* wl = wsoft + 40;  // 10 rows

  for (int l = 0; l < 2; ++l) {
    auto WFD = [&](int e) { return Wf_d + (size_t)(l * 3 + e) * DIM * DIM; };
    auto BFD = [&](int e) { return bf_d + (size_t)(l * 3 + e) * DIM; };
    auto WFS = [&](int e) { return Wf_s + (size_t)(l * 3 + e) * DIM * DIM; };
    auto BFS = [&](int e) { return bf_s + (size_t)(l * 3 + e) * DIM; };
    auto WLD = [&](int e) { return Wl_d + (size_t)(l * 5 + e) * DIM * DIM; };
    auto BLD = [&](int e) { return bl_d + (size_t)(l * 5 + e) * DIM; };
    auto WLS = [&](int e) { return Wl_s + (size_t)(l * 5 + e) * DIM; };
    auto BLS2 = [&](int e) { return bl_s + (size_t)(l * 5 + e) * DIM; };
    auto WLSm = [&](int e) { return Wl_s + (size_t)(l * 5 + e) * DIM * DIM; };
    auto WFrow = [&](int e) { return wf + (l * 3 + e) * 4; };
    auto WMrow = [&](int n) { return wm + (l * 2 + n) * 4; };
    auto WLrow = [&](int e) { return wl + (l * 5 + e) * 4; };
    (void)WLS;

    auto edge = [&](GemmDesc& d, const float* X, const float* AG,
                    const float* Wd, const float* bd,
                    const float* Ws, const float* bs, const float* wrow) {
      d.A[d.nmat] = X;  d.W[d.nmat] = Wd; d.b[d.nmat] = bd; d.c[d.nmat] = wrow + 2; d.nmat++;
      d.A[d.nmat] = AG; d.W[d.nmat] = Ws; d.b[d.nmat] = bs; d.c[d.nmat] = wrow + 3; d.nmat++;
      d.I[d.nid] = X; d.ic[d.nid] = wrow + 1; d.nid++;
    };

    // aggA = mean-agg(x)
    k_segmean<<<N_NODES, 256, 0, stream>>>(x, row_ofs, csr_src, invdeg, aggA);

    // first-stage node 1: s1 = relu(mixed(x, e0))
    {
      GemmDesc d{}; d.K = DIM; d.relu = 1;
      edge(d, x, aggA, WFD(0), BFD(0), WFS(0), BFS(0), WFrow(0));
      k_gemm<<<ggrid, 256, 0, stream>>>(d, s1);
    }

    // mid for s1: sum/max pass; writes mean -> aggB (DAG agg of states[1]) and mids0
    k_segmid<<<N_NODES, 256, 0, stream>>>(s1, row_ofs, csr_src, invdeg, WMrow(0), aggB, mids0);

    // first-stage node 2: s2 = relu(mixed(x, e1) + mixed(s1, e2))
    {
      GemmDesc d{}; d.K = DIM; d.relu = 1;
      edge(d, x,  aggA, WFD(1), BFD(1), WFS(1), BFS(1), WFrow(1));
      edge(d, s1, aggB, WFD(2), BFD(2), WFS(2), BFS(2), WFrow(2));
      k_gemm<<<ggrid, 256, 0, stream>>>(d, s2);
    }

    // mid for s2 -> mids1
    k_segmid<<<N_NODES, 256, 0, stream>>>(s2, row_ofs, csr_src, invdeg, WMrow(1), nullptr, mids1);

    // mean-aggs of mids0, mids1 (shared CSR walk)
    k_segmean2<<<N_NODES, 256, 0, stream>>>(mids0, mids1, row_ofs, csr_src, invdeg, aggA, aggB);

    // last-stage node 0: l0 = relu(mixed(mids0,e0) + mixed(mids1,e1))
    {
      GemmDesc d{}; d.K = DIM; d.relu = 1;
      edge(d, mids0, aggA, WLD(0), BLD(0), WLSm(0), BLS2(0), WLrow(0));
      edge(d, mids1, aggB, WLD(1), BLD(1), WLSm(1), BLS2(1), WLrow(1));
      k_gemm<<<ggrid, 256, 0, stream>>>(d, l0);
    }

    // mean-agg of l0 -> s1 buffer (s1 dead now)
    k_segmean<<<N_NODES, 256, 0, stream>>>(l0, row_ofs, csr_src, invdeg, s1);

    // last-stage node 1 + residual cell output, fused:
    // x = x + 0.5*(l0 + relu(mixed(mids0,e2)+mixed(mids1,e3)+mixed(l0,e4)))
    {
      GemmDesc d{}; d.K = DIM; d.relu = 1;
      edge(d, mids0, aggA, WLD(2), BLD(2), WLSm(2), BLS2(2), WLrow(2));
      edge(d, mids1, aggB, WLD(3), BLD(3), WLSm(3), BLS2(3), WLrow(3));
      edge(d, l0,    s1,   WLD(4), BLD(4), WLSm(4), BLS2(4), WLrow(4));
      d.resid = x; d.addl = l0;
      k_gemm<<<ggrid, 256, 0, stream>>>(d, x);
    }
  }

  // readout
  k_readout<<<N_GRAPHS, 256, 0, stream>>>(x, gid, hg);
  k_mlp<<<N_GRAPHS, 256, 0, stream>>>(hg, C1, c1b, C2, c2b, C3, c3b, (float*)d_out);
}

// Round 3
// 537.982 us; speedup vs baseline: 1.9482x; 1.9482x over previous
//
#include <hip/hip_runtime.h>

#define N_NODES   8000
#define N_EDGES   128000
#define N_GRAPHS  64
#define DIM       256
#define IN_DIM    128

typedef short bf16x8 __attribute__((ext_vector_type(8)));
typedef float f32x4 __attribute__((ext_vector_type(4)));

static __device__ __forceinline__ float bf2f(unsigned v) {
  return __uint_as_float(v << 16);
}
static __device__ __forceinline__ unsigned f2bf(float f) {
  unsigned u = __float_as_uint(f);
  return (u + 0x7fffu + ((u >> 16) & 1u)) >> 16;
}

// ---------------------------------------------------------------------------
// CSR build
// ---------------------------------------------------------------------------
__global__ __launch_bounds__(256) void k_count(const int* __restrict__ dst,
                                               int* __restrict__ counts) {
  int e = blockIdx.x * 256 + threadIdx.x;
  if (e < N_EDGES) atomicAdd(&counts[dst[e]], 1);
}

__global__ __launch_bounds__(256) void k_scan(const int* __restrict__ counts,
                                              int* __restrict__ row_ofs,
                                              int* __restrict__ cursor,
                                              float* __restrict__ invdeg) {
  __shared__ int chunk[256];
  const int per = (N_NODES + 255) / 256;  // 32
  int t = threadIdx.x;
  int base = t * per;
  int s = 0;
  for (int i = 0; i < per; ++i) {
    int idx = base + i;
    if (idx < N_NODES) s += counts[idx];
  }
  chunk[t] = s;
  __syncthreads();
  for (int off = 1; off < 256; off <<= 1) {
    int v = 0;
    if (t >= off) v = chunk[t - off];
    __syncthreads();
    if (t >= off) chunk[t] += v;
    __syncthreads();
  }
  int run = (t > 0) ? chunk[t - 1] : 0;
  for (int i = 0; i < per; ++i) {
    int idx = base + i;
    if (idx < N_NODES) {
      row_ofs[idx] = run;
      cursor[idx] = run;
      int c = counts[idx];
      invdeg[idx] = 1.0f / (float)(c > 1 ? c : 1);
      run += c;
    }
  }
  if (t == 0) row_ofs[N_NODES] = chunk[255];
}

__global__ __launch_bounds__(256) void k_fill(const int* __restrict__ src,
                                              const int* __restrict__ dst,
                                              int* __restrict__ cursor,
                                              int* __restrict__ csr_src) {
  int e = blockIdx.x * 256 + threadIdx.x;
  if (e < N_EDGES) {
    int p = atomicAdd(&cursor[dst[e]], 1);
    csr_src[p] = src[e];
  }
}

// ---------------------------------------------------------------------------
// Softmax over architecture rows; wsoft: [0..23]=wf, [24..39]=wm, [40..79]=wl
// ---------------------------------------------------------------------------
__global__ __launch_bounds__(64) void k_softmax(const float* __restrict__ af,
                                                const float* __restrict__ am,
                                                const float* __restrict__ al,
                                                float* __restrict__ w) {
  int t = threadIdx.x;
  const float* sp;
  float* dp;
  if (t < 6)       { sp = af + t * 4;        dp = w + t * 4; }
  else if (t < 10) { sp = am + (t - 6) * 4;  dp = w + 24 + (t - 6) * 4; }
  else if (t < 20) { sp = al + (t - 10) * 4; dp = w + 40 + (t - 10) * 4; }
  else return;
  float a0 = sp[0], a1 = sp[1], a2 = sp[2], a3 = sp[3];
  float m = fmaxf(fmaxf(a0, a1), fmaxf(a2, a3));
  float e0 = expf(a0 - m), e1 = expf(a1 - m), e2 = expf(a2 - m), e3 = expf(a3 - m);
  float si = 1.0f / (e0 + e1 + e2 + e3);
  dp[0] = e0 * si; dp[1] = e1 * si; dp[2] = e2 * si; dp[3] = e3 * si;
}

// ---------------------------------------------------------------------------
// Conversions
// ---------------------------------------------------------------------------
__global__ __launch_bounds__(256) void k_cvt_bf16(const float* __restrict__ in,
                                                  unsigned short* __restrict__ out,
                                                  int n) {
  int i = blockIdx.x * 256 + threadIdx.x;
  if (i < n) out[i] = (unsigned short)f2bf(in[i]);
}

// in: f32 [K][N] row-major (+z*K*N); out: bf16 [N][K] (+z*K*N)
__global__ __launch_bounds__(256) void k_transpose_cvt(const float* __restrict__ in,
                                                       unsigned short* __restrict__ out,
                                                       int K, int N) {
  __shared__ float tile[32][33];
  size_t mofs = (size_t)blockIdx.z * K * N;
  in += mofs; out += mofs;
  int k0 = blockIdx.x * 32, n0 = blockIdx.y * 32;
  int tx = threadIdx.x & 31, ty = threadIdx.x >> 5;  // 32 x 8
#pragma unroll
  for (int i = 0; i < 4; ++i)
    tile[ty + 8 * i][tx] = in[(size_t)(k0 + ty + 8 * i) * N + n0 + tx];
  __syncthreads();
#pragma unroll
  for (int i = 0; i < 4; ++i)
    out[(size_t)(n0 + ty + 8 * i) * K + k0 + tx] =
        (unsigned short)f2bf(tile[tx][ty + 8 * i]);
}

// ---------------------------------------------------------------------------
// Segment reductions (bf16 features). One wave per node, 4 nodes/block.
// Lane l handles dims 4l..4l+3 (uint2 = 4 bf16 per edge per lane).
// ---------------------------------------------------------------------------
__global__ __launch_bounds__(256) void k_segmean_bf(const unsigned short* __restrict__ X,
                                                    const int* __restrict__ row_ofs,
                                                    const int* __restrict__ csr_src,
                                                    const float* __restrict__ invdeg,
                                                    unsigned short* __restrict__ out) {
  int node = blockIdx.x * 4 + (threadIdx.x >> 6);
  int l = threadIdx.x & 63;
  if (node >= N_NODES) return;
  int beg = row_ofs[node], end = row_ofs[node + 1];
  float s0 = 0.f, s1 = 0.f, s2 = 0.f, s3 = 0.f;
  for (int e = beg; e < end; ++e) {
    int si = csr_src[e];
    uint2 u = *(const uint2*)&X[(size_t)si * DIM + 4 * l];
    s0 += bf2f(u.x & 0xffffu); s1 += bf2f(u.x >> 16);
    s2 += bf2f(u.y & 0xffffu); s3 += bf2f(u.y >> 16);
  }
  float iv = invdeg[node];
  uint2 o;
  o.x = f2bf(s0 * iv) | (f2bf(s1 * iv) << 16);
  o.y = f2bf(s2 * iv) | (f2bf(s3 * iv) << 16);
  *(uint2*)&out[(size_t)node * DIM + 4 * l] = o;
}

__global__ __launch_bounds__(256) void k_segmean2_bf(const unsigned short* __restrict__ X0,
                                                     const unsigned short* __restrict__ X1,
                                                     const int* __restrict__ row_ofs,
                                                     const int* __restrict__ csr_src,
                                                     const float* __restrict__ invdeg,
                                                     unsigned short* __restrict__ out0,
                                                     unsigned short* __restrict__ out1) {
  int node = blockIdx.x * 4 + (threadIdx.x >> 6);
  int l = threadIdx.x & 63;
  if (node >= N_NODES) return;
  int beg = row_ofs[node], end = row_ofs[node + 1];
  float a0 = 0.f, a1 = 0.f, a2 = 0.f, a3 = 0.f;
  float b0 = 0.f, b1 = 0.f, b2 = 0.f, b3 = 0.f;
  for (int e = beg; e < end; ++e) {
    size_t rb = (size_t)csr_src[e] * DIM + 4 * l;
    uint2 u = *(const uint2*)&X0[rb];
    uint2 v = *(const uint2*)&X1[rb];
    a0 += bf2f(u.x & 0xffffu); a1 += bf2f(u.x >> 16);
    a2 += bf2f(u.y & 0xffffu); a3 += bf2f(u.y >> 16);
    b0 += bf2f(v.x & 0xffffu); b1 += bf2f(v.x >> 16);
    b2 += bf2f(v.y & 0xffffu); b3 += bf2f(v.y >> 16);
  }
  float iv = invdeg[node];
  uint2 o;
  o.x = f2bf(a0 * iv) | (f2bf(a1 * iv) << 16);
  o.y = f2bf(a2 * iv) | (f2bf(a3 * iv) << 16);
  *(uint2*)&out0[(size_t)node * DIM + 4 * l] = o;
  o.x = f2bf(b0 * iv) | (f2bf(b1 * iv) << 16);
  o.y = f2bf(b2 * iv) | (f2bf(b3 * iv) << 16);
  *(uint2*)&out1[(size_t)node * DIM + 4 * l] = o;
}

// sum+max over incoming msgs of relu'd input; epilogue = middle-stage mixture.
__global__ __launch_bounds__(256) void k_segmid_bf(const unsigned short* __restrict__ Xn,
                                                   const int* __restrict__ row_ofs,
                                                   const int* __restrict__ csr_src,
                                                   const float* __restrict__ invdeg,
                                                   const float* __restrict__ wrow,
                                                   unsigned short* __restrict__ mean_out,
                                                   unsigned short* __restrict__ mids_out) {
  int node = blockIdx.x * 4 + (threadIdx.x >> 6);
  int l = threadIdx.x & 63;
  if (node >= N_NODES) return;
  int beg = row_ofs[node], end = row_ofs[node + 1];
  float s0 = 0.f, s1 = 0.f, s2 = 0.f, s3 = 0.f;
  float m0 = 0.f, m1 = 0.f, m2 = 0.f, m3 = 0.f;  // inputs >= 0 (relu)
  for (int e = beg; e < end; ++e) {
    int si = csr_src[e];
    uint2 u = *(const uint2*)&Xn[(size_t)si * DIM + 4 * l];
    float v0 = bf2f(u.x & 0xffffu), v1 = bf2f(u.x >> 16);
    float v2 = bf2f(u.y & 0xffffu), v3 = bf2f(u.y >> 16);
    s0 += v0; s1 += v1; s2 += v2; s3 += v3;
    m0 = fmaxf(m0, v0); m1 = fmaxf(m1, v1);
    m2 = fmaxf(m2, v2); m3 = fmaxf(m3, v3);
  }
  float iv = invdeg[node];
  float e0 = s0 * iv, e1 = s1 * iv, e2 = s2 * iv, e3 = s3 * iv;
  if (mean_out) {
    uint2 o;
    o.x = f2bf(e0) | (f2bf(e1) << 16);
    o.y = f2bf(e2) | (f2bf(e3) << 16);
    *(uint2*)&mean_out[(size_t)node * DIM + 4 * l] = o;
  }
  float w0 = wrow[0], w1 = wrow[1], w2 = wrow[2], w3 = wrow[3];
  uint2 xu = *(const uint2*)&Xn[(size_t)node * DIM + 4 * l];
  float x0 = bf2f(xu.x & 0xffffu), x1 = bf2f(xu.x >> 16);
  float x2 = bf2f(xu.y & 0xffffu), x3 = bf2f(xu.y >> 16);
  uint2 o;
  o.x = f2bf(w0 * x0 + w1 * m0 + w2 * e0 + w3 * s0) |
        (f2bf(w0 * x1 + w1 * m1 + w2 * e1 + w3 * s1) << 16);
  o.y = f2bf(w0 * x2 + w1 * m2 + w2 * e2 + w3 * s2) |
        (f2bf(w0 * x3 + w1 * m3 + w2 * e3 + w3 * s3) << 16);
  *(uint2*)&mids_out[(size_t)node * DIM + 4 * l] = o;
}

// ---------------------------------------------------------------------------
// MFMA multi-term GEMM (bf16 in, f32 accumulate):
//   r = relu( sum_t c_t*(A_t@W_t + b_t) + sum_u ic_u*I_u )
//   out = resid ? resid + 0.5*(addl + r) : r
// A_t: bf16 [M][K]; W_t: bf16 W^T [256][K]; out cols = 256.
// Block 64x64, 4 waves (2x2), wave tile 32x32 = 2x2 mfma_16x16x32 frags.
// ---------------------------------------------------------------------------
struct GemmDescB {
  const unsigned short* A[6];
  const unsigned short* W[6];
  const float* b[6];
  const float* c[6];
  const unsigned short* I[3];
  const float* ic[3];
  const float* resid;          // f32 x (residual stream)
  const unsigned short* addl;  // bf16 l0
  float* out_f32;              // optional f32 copy (residual stream)
  unsigned short* out_bf;
  int nmat, nid, K, relu;
};

__global__ __launch_bounds__(256) void k_gemm_mfma(GemmDescB d) {
  __shared__ __align__(16) unsigned short As[64][72];
  __shared__ __align__(16) unsigned short Bs[64][72];
  const int tid = threadIdx.x;
  const int bm = blockIdx.x * 64, bn = blockIdx.y * 64;
  const int w = tid >> 6, l = tid & 63;
  const int wm = (w >> 1) * 32, wn = (w & 1) * 32;
  const int lr = l & 15, lk = (l >> 4) * 8;
  const int ldr = tid >> 3, ldk = (tid & 7) * 8;  // staging: rows ldr, ldr+32

  f32x4 zero = {0.f, 0.f, 0.f, 0.f};
  f32x4 accT[2][2];
  accT[0][0] = zero; accT[0][1] = zero; accT[1][0] = zero; accT[1][1] = zero;

  const int K = d.K;
  for (int t = 0; t < d.nmat; ++t) {
    const unsigned short* __restrict__ A = d.A[t];
    const unsigned short* __restrict__ W = d.W[t];
    f32x4 acc[2][2];
    acc[0][0] = zero; acc[0][1] = zero; acc[1][0] = zero; acc[1][1] = zero;
    for (int k0 = 0; k0 < K; k0 += 64) {
      // stage full 64x64 tiles: each thread writes rows ldr and ldr+32
      *(uint4*)&As[ldr][ldk]      = *(const uint4*)&A[(size_t)(bm + ldr) * K + k0 + ldk];
      *(uint4*)&As[ldr + 32][ldk] = *(const uint4*)&A[(size_t)(bm + ldr + 32) * K + k0 + ldk];
      *(uint4*)&Bs[ldr][ldk]      = *(const uint4*)&W[(size_t)(bn + ldr) * K + k0 + ldk];
      *(uint4*)&Bs[ldr + 32][ldk] = *(const uint4*)&W[(size_t)(bn + ldr + 32) * K + k0 + ldk];
      __syncthreads();
#pragma unroll
      for (int ks = 0; ks < 2; ++ks) {
        bf16x8 a0 = *(const bf16x8*)&As[wm + lr][ks * 32 + lk];
        bf16x8 a1 = *(const bf16x8*)&As[wm + 16 + lr][ks * 32 + lk];
        bf16x8 b0 = *(const bf16x8*)&Bs[wn + lr][ks * 32 + lk];
        bf16x8 b1 = *(const bf16x8*)&Bs[wn + 16 + lr][ks * 32 + lk];
        acc[0][0] = __builtin_amdgcn_mfma_f32_16x16x32_bf16(a0, b0, acc[0][0], 0, 0, 0);
        acc[0][1] = __builtin_amdgcn_mfma_f32_16x16x32_bf16(a0, b1, acc[0][1], 0, 0, 0);
        acc[1][0] = __builtin_amdgcn_mfma_f32_16x16x32_bf16(a1, b0, acc[1][0], 0, 0, 0);
        acc[1][1] = __builtin_amdgcn_mfma_f32_16x16x32_bf16(a1, b1, acc[1][1], 0, 0, 0);
      }
      __syncthreads();
    }
    float coef = d.c[t] ? *d.c[t] : 1.0f;
#pragma unroll
    for (int m = 0; m < 2; ++m)
#pragma unroll
      for (int n = 0; n < 2; ++n)
#pragma unroll
        for (int i = 0; i < 4; ++i) accT[m][n][i] += coef * acc[m][n][i];
  }

  // epilogue
  float bias[2] = {0.f, 0.f};
  for (int t = 0; t < d.nmat; ++t) {
    if (d.b[t]) {
      float c = d.c[t] ? *d.c[t] : 1.0f;
      bias[0] += c * d.b[t][bn + wn + lr];
      bias[1] += c * d.b[t][bn + wn + 16 + lr];
    }
  }
  float vout[2][2][4];
#pragma unroll
  for (int m = 0; m < 2; ++m)
#pragma unroll
    for (int n = 0; n < 2; ++n)
#pragma unroll
      for (int i = 0; i < 4; ++i) vout[m][n][i] = accT[m][n][i] + bias[n];
#pragma unroll
  for (int u = 0; u < 3; ++u) {
    if (u < d.nid) {
      float icu = *d.ic[u];
      const unsigned short* __restrict__ I = d.I[u];
#pragma unroll
      for (int m = 0; m < 2; ++m)
#pragma unroll
        for (int n = 0; n < 2; ++n)
#pragma unroll
          for (int i = 0; i < 4; ++i) {
            int row = bm + wm + m * 16 + (l >> 4) * 4 + i;
            int col = bn + wn + n * 16 + lr;
            vout[m][n][i] += icu * bf2f(I[(size_t)row * DIM + col]);
          }
    }
  }
#pragma unroll
  for (int m = 0; m < 2; ++m)
#pragma unroll
    for (int n = 0; n < 2; ++n)
#pragma unroll
      for (int i = 0; i < 4; ++i) {
        int row = bm + wm + m * 16 + (l >> 4) * 4 + i;
        int col = bn + wn + n * 16 + lr;
        size_t idx = (size_t)row * DIM + col;
        float v = vout[m][n][i];
        if (d.relu) v = fmaxf(v, 0.f);
        if (d.resid) v = d.resid[idx] + 0.5f * (bf2f(d.addl[idx]) + v);
        d.out_bf[idx] = (unsigned short)f2bf(v);
        if (d.out_f32) d.out_f32[idx] = v;
      }
}

// ---------------------------------------------------------------------------
// Readout + MLP
// ---------------------------------------------------------------------------
__global__ __launch_bounds__(256) void k_readout(const float* __restrict__ x,
                                                 const int* __restrict__ gid,
                                                 float* __restrict__ hg) {
  int g = blockIdx.x, t = threadIdx.x;
  int lo = 0, hi = N_NODES;
  while (lo < hi) { int m = (lo + hi) >> 1; if (gid[m] < g) lo = m + 1; else hi = m; }
  int beg = lo;
  lo = beg; hi = N_NODES;
  while (lo < hi) { int m = (lo + hi) >> 1; if (gid[m] <= g) lo = m + 1; else hi = m; }
  int end = lo;
  float s = 0.f;
  for (int i = beg; i < end; ++i) s += x[(size_t)i * DIM + t];
  int cnt = end - beg;
  hg[g * DIM + t] = s / (float)(cnt > 1 ? cnt : 1);
}

__global__ __launch_bounds__(256) void k_mlp(const float* __restrict__ hg,
                                             const float* __restrict__ C1,
                                             const float* __restrict__ c1b,
                                             const float* __restrict__ C2,
                                             const float* __restrict__ c2b,
                                             const float* __restrict__ C3,
                                             const float* __restrict__ c3b,
                                             float* __restrict__ out) {
  int g = blockIdx.x, t = threadIdx.x;
  __shared__ float h0[256], h1[128], h2[64];
  h0[t] = hg[g * DIM + t];
  __syncthreads();
  if (t < 128) {
    float s = c1b[t];
    for (int k = 0; k < 256; ++k) s = fmaf(h0[k], C1[k * 128 + t], s);
    h1[t] = fmaxf(s, 0.f);
  }
  __syncthreads();
  if (t < 64) {
    float s = c2b[t];
    for (int k = 0; k < 128; ++k) s = fmaf(h1[k], C2[k * 64 + t], s);
    h2[t] = fmaxf(s, 0.f);
  }
  __syncthreads();
  if (t < 10) {
    float s = c3b[t];
    for (int k = 0; k < 64; ++k) s = fmaf(h2[k], C3[k * 10 + t], s);
    out[g * 10 + t] = s;
  }
}

// ---------------------------------------------------------------------------
extern "C" void kernel_launch(void* const* d_in, const int* in_sizes, int n_in,
                              void* d_out, int out_size, void* d_ws, size_t ws_size,
                              hipStream_t stream) {
  const float* h     = (const float*)d_in[0];
  const float* W_emb = (const float*)d_in[1];
  const float* b_emb = (const float*)d_in[2];
  const float* Wf_d  = (const float*)d_in[3];
  const float* bf_d  = (const float*)d_in[4];
  const float* Wf_s  = (const float*)d_in[5];
  const float* bf_s  = (const float*)d_in[6];
  const float* Wl_d  = (const float*)d_in[7];
  const float* bl_d  = (const float*)d_in[8];
  const float* Wl_s  = (const float*)d_in[9];
  const float* bl_s  = (const float*)d_in[10];
  const float* a_first = (const float*)d_in[11];
  const float* a_mid   = (const float*)d_in[12];
  const float* a_last  = (const float*)d_in[13];
  const float* C1 = (const float*)d_in[14];
  const float* c1b = (const float*)d_in[15];
  const float* C2 = (const float*)d_in[16];
  const float* c2b = (const float*)d_in[17];
  const float* C3 = (const float*)d_in[18];
  const float* c3b = (const float*)d_in[19];
  const int* src = (const int*)d_in[20];
  const int* dst = (const int*)d_in[21];
  const int* gid = (const int*)d_in[22];
  (void)in_sizes; (void)n_in; (void)out_size; (void)ws_size;

  char* p = (char*)d_ws;
  auto alloc = [&](size_t bytes) {
    void* r = (void*)p;
    p += (bytes + 255) & ~(size_t)255;
    return r;
  };
  typedef unsigned short u16;
  const size_t NBF = (size_t)N_NODES * DIM * sizeof(u16);  // 4.096 MB
  float* x_f32 = (float*)alloc((size_t)N_NODES * DIM * sizeof(float));
  u16* xb    = (u16*)alloc(NBF);
  u16* s1b   = (u16*)alloc(NBF);
  u16* s2b   = (u16*)alloc(NBF);
  u16* m0b   = (u16*)alloc(NBF);
  u16* m1b   = (u16*)alloc(NBF);
  u16* l0b   = (u16*)alloc(NBF);
  u16* aggAb = (u16*)alloc(NBF);
  u16* aggBb = (u16*)alloc(NBF);
  u16* h_bf  = (u16*)alloc((size_t)N_NODES * IN_DIM * sizeof(u16));
  // transposed bf16 weights: W_emb^T, then Wf_d(6), Wf_s(6), Wl_d(10), Wl_s(10)
  u16* WT    = (u16*)alloc((size_t)(DIM * IN_DIM + 32 * DIM * DIM) * sizeof(u16));
  u16* WTe   = WT;
  u16* WTfd  = WT + DIM * IN_DIM;
  u16* WTfs  = WTfd + 6 * DIM * DIM;
  u16* WTld  = WTfs + 6 * DIM * DIM;
  u16* WTls  = WTld + 10 * DIM * DIM;
  float* invdeg = (float*)alloc(N_NODES * sizeof(float));
  int* counts  = (int*)alloc(N_NODES * sizeof(int));
  int* row_ofs = (int*)alloc((N_NODES + 1) * sizeof(int));
  int* cursor  = (int*)alloc(N_NODES * sizeof(int));
  int* csr_src = (int*)alloc(N_EDGES * sizeof(int));
  float* wsoft = (float*)alloc(80 * sizeof(float));
  float* hg    = (float*)alloc(N_GRAPHS * DIM * sizeof(float));

  const int EB = (N_EDGES + 255) / 256;

  hipMemsetAsync(counts, 0, N_NODES * sizeof(int), stream);
  k_count<<<EB, 256, 0, stream>>>(dst, counts);
  k_scan<<<1, 256, 0, stream>>>(counts, row_ofs, cursor, invdeg);
  k_fill<<<EB, 256, 0, stream>>>(src, dst, cursor, csr_src);
  k_softmax<<<1, 64, 0, stream>>>(a_first, a_mid, a_last, wsoft);

  // conversions
  k_cvt_bf16<<<(N_NODES * IN_DIM + 255) / 256, 256, 0, stream>>>(h, h_bf, N_NODES * IN_DIM);
  k_transpose_cvt<<<dim3(IN_DIM / 32, DIM / 32, 1), 256, 0, stream>>>(W_emb, WTe, IN_DIM, DIM);
  k_transpose_cvt<<<dim3(8, 8, 6), 256, 0, stream>>>(Wf_d, WTfd, DIM, DIM);
  k_transpose_cvt<<<dim3(8, 8, 6), 256, 0, stream>>>(Wf_s, WTfs, DIM, DIM);
  k_transpose_cvt<<<dim3(8, 8, 10), 256, 0, stream>>>(Wl_d, WTld, DIM, DIM);
  k_transpose_cvt<<<dim3(8, 8, 10), 256, 0, stream>>>(Wl_s, WTls, DIM, DIM);

  const dim3 ggrid(N_NODES / 64, DIM / 64);  // 125 x 4
  const int SB = (N_NODES + 3) / 4;          // seg blocks

  // embedding: x = h @ W_emb + b_emb   (f32 + bf16 outputs)
  {
    GemmDescB d{};
    d.A[0] = h_bf; d.W[0] = WTe; d.b[0] = b_emb; d.c[0] = nullptr;
    d.nmat = 1; d.nid = 0; d.K = IN_DIM; d.relu = 0;
    d.out_f32 = x_f32; d.out_bf = xb;
    k_gemm_mfma<<<ggrid, 256, 0, stream>>>(d);
  }

  const float* wf = wsoft;
  const float* wm = wsoft + 24;
  const float* wl = wsoft + 40;

  for (int l = 0; l < 2; ++l) {
    auto WFD = [&](int e) { return WTfd + (size_t)(l * 3 + e) * DIM * DIM; };
    auto BFD = [&](int e) { return bf_d + (size_t)(l * 3 + e) * DIM; };
    auto WFS = [&](int e) { return WTfs + (size_t)(l * 3 + e) * DIM * DIM; };
    auto BFS = [&](int e) { return bf_s + (size_t)(l * 3 + e) * DIM; };
    auto WLD = [&](int e) { return WTld + (size_t)(l * 5 + e) * DIM * DIM; };
    auto BLD = [&](int e) { return bl_d + (size_t)(l * 5 + e) * DIM; };
    auto WLS = [&](int e) { return WTls + (size_t)(l * 5 + e) * DIM * DIM; };
    auto BLS = [&](int e) { return bl_s + (size_t)(l * 5 + e) * DIM; };
    auto WFrow = [&](int e) { return wf + (l * 3 + e) * 4; };
    auto WMrow = [&](int n) { return wm + (l * 2 + n) * 4; };
    auto WLrow = [&](int e) { return wl + (l * 5 + e) * 4; };

    auto edge = [&](GemmDescB& d, const u16* X, const u16* AG,
                    const u16* Wd, const float* bd,
                    const u16* Ws, const float* bs, const float* wrow) {
      d.A[d.nmat] = X;  d.W[d.nmat] = Wd; d.b[d.nmat] = bd; d.c[d.nmat] = wrow + 2; d.nmat++;
      d.A[d.nmat] = AG; d.W[d.nmat] = Ws; d.b[d.nmat] = bs; d.c[d.nmat] = wrow + 3; d.nmat++;
      d.I[d.nid] = X; d.ic[d.nid] = wrow + 1; d.nid++;
    };

    // aggA = mean-agg(x)
    k_segmean_bf<<<SB, 256, 0, stream>>>(xb, row_ofs, csr_src, invdeg, aggAb);

    // s1 = relu(mixed(x, e0))
    {
      GemmDescB d{}; d.K = DIM; d.relu = 1; d.out_bf = s1b;
      edge(d, xb, aggAb, WFD(0), BFD(0), WFS(0), BFS(0), WFrow(0));
      k_gemm_mfma<<<ggrid, 256, 0, stream>>>(d);
    }

    // mid of s1: mean -> aggB (DAG agg of states[1]); mixture -> mids0
    k_segmid_bf<<<SB, 256, 0, stream>>>(s1b, row_ofs, csr_src, invdeg, WMrow(0), aggBb, m0b);

    // s2 = relu(mixed(x, e1) + mixed(s1, e2))
    {
      GemmDescB d{}; d.K = DIM; d.relu = 1; d.out_bf = s2b;
      edge(d, xb,  aggAb, WFD(1), BFD(1), WFS(1), BFS(1), WFrow(1));
      edge(d, s1b, aggBb, WFD(2), BFD(2), WFS(2), BFS(2), WFrow(2));
      k_gemm_mfma<<<ggrid, 256, 0, stream>>>(d);
    }

    // mid of s2 -> mids1
    k_segmid_bf<<<SB, 256, 0, stream>>>(s2b, row_ofs, csr_src, invdeg, WMrow(1), nullptr, m1b);

    // mean-aggs of mids0, mids1
    k_segmean2_bf<<<SB, 256, 0, stream>>>(m0b, m1b, row_ofs, csr_src, invdeg, aggAb, aggBb);

    // l0 = relu(mixed(mids0,e0) + mixed(mids1,e1))
    {
      GemmDescB d{}; d.K = DIM; d.relu = 1; d.out_bf = l0b;
      edge(d, m0b, aggAb, WLD(0), BLD(0), WLS(0), BLS(0), WLrow(0));
      edge(d, m1b, aggBb, WLD(1), BLD(1), WLS(1), BLS(1), WLrow(1));
      k_gemm_mfma<<<ggrid, 256, 0, stream>>>(d);
    }

    // mean-agg of l0 -> s1b (dead)
    k_segmean_bf<<<SB, 256, 0, stream>>>(l0b, row_ofs, csr_src, invdeg, s1b);

    // x = x + 0.5*(l0 + relu(mixed(mids0,e2)+mixed(mids1,e3)+mixed(l0,e4)))
    {
      GemmDescB d{}; d.K = DIM; d.relu = 1;
      edge(d, m0b, aggAb, WLD(2), BLD(2), WLS(2), BLS(2), WLrow(2));
      edge(d, m1b, aggBb, WLD(3), BLD(3), WLS(3), BLS(3), WLrow(3));
      edge(d, l0b, s1b,   WLD(4), BLD(4), WLS(4), BLS(4), WLrow(4));
      d.resid = x_f32; d.addl = l0b;
      d.out_f32 = x_f32; d.out_bf = xb;
      k_gemm_mfma<<<ggrid, 256, 0, stream>>>(d);
    }
  }

  k_readout<<<N_GRAPHS, 256, 0, stream>>>(x_f32, gid, hg);
  k_mlp<<<N_GRAPHS, 256, 0, stream>>>(hg, C1, c1b, C2, c2b, C3, c3b, (float*)d_out);
}

// Round 4
// 432.844 us; speedup vs baseline: 2.4214x; 1.2429x over previous
//
#include <hip/hip_runtime.h>

#define N_NODES   8000
#define N_EDGES   128000
#define N_GRAPHS  64
#define DIM       256
#define IN_DIM    128

typedef short bf16x8 __attribute__((ext_vector_type(8)));
typedef float f32x4 __attribute__((ext_vector_type(4)));

static __device__ __forceinline__ float bf2f(unsigned v) {
  return __uint_as_float(v << 16);
}
static __device__ __forceinline__ unsigned f2bf(float f) {
  unsigned u = __float_as_uint(f);
  return (u + 0x7fffu + ((u >> 16) & 1u)) >> 16;
}

// ---------------------------------------------------------------------------
// CSR build
// ---------------------------------------------------------------------------
__global__ __launch_bounds__(256) void k_count(const int* __restrict__ dst,
                                               int* __restrict__ counts) {
  int e = blockIdx.x * 256 + threadIdx.x;
  if (e < N_EDGES) atomicAdd(&counts[dst[e]], 1);
}

__global__ __launch_bounds__(256) void k_scan(const int* __restrict__ counts,
                                              int* __restrict__ row_ofs,
                                              int* __restrict__ cursor,
                                              float* __restrict__ invdeg) {
  __shared__ int chunk[256];
  const int per = (N_NODES + 255) / 256;  // 32
  int t = threadIdx.x;
  int base = t * per;
  int s = 0;
  for (int i = 0; i < per; ++i) {
    int idx = base + i;
    if (idx < N_NODES) s += counts[idx];
  }
  chunk[t] = s;
  __syncthreads();
  for (int off = 1; off < 256; off <<= 1) {
    int v = 0;
    if (t >= off) v = chunk[t - off];
    __syncthreads();
    if (t >= off) chunk[t] += v;
    __syncthreads();
  }
  int run = (t > 0) ? chunk[t - 1] : 0;
  for (int i = 0; i < per; ++i) {
    int idx = base + i;
    if (idx < N_NODES) {
      row_ofs[idx] = run;
      cursor[idx] = run;
      int c = counts[idx];
      invdeg[idx] = 1.0f / (float)(c > 1 ? c : 1);
      run += c;
    }
  }
  if (t == 0) row_ofs[N_NODES] = chunk[255];
}

__global__ __launch_bounds__(256) void k_fill(const int* __restrict__ src,
                                              const int* __restrict__ dst,
                                              int* __restrict__ cursor,
                                              int* __restrict__ csr_src) {
  int e = blockIdx.x * 256 + threadIdx.x;
  if (e < N_EDGES) {
    int p = atomicAdd(&cursor[dst[e]], 1);
    csr_src[p] = src[e];
  }
}

// ---------------------------------------------------------------------------
// Softmax over architecture rows; wsoft: [0..23]=wf, [24..39]=wm, [40..79]=wl
// ---------------------------------------------------------------------------
__global__ __launch_bounds__(64) void k_softmax(const float* __restrict__ af,
                                                const float* __restrict__ am,
                                                const float* __restrict__ al,
                                                float* __restrict__ w) {
  int t = threadIdx.x;
  const float* sp;
  float* dp;
  if (t < 6)       { sp = af + t * 4;        dp = w + t * 4; }
  else if (t < 10) { sp = am + (t - 6) * 4;  dp = w + 24 + (t - 6) * 4; }
  else if (t < 20) { sp = al + (t - 10) * 4; dp = w + 40 + (t - 10) * 4; }
  else return;
  float a0 = sp[0], a1 = sp[1], a2 = sp[2], a3 = sp[3];
  float m = fmaxf(fmaxf(a0, a1), fmaxf(a2, a3));
  float e0 = expf(a0 - m), e1 = expf(a1 - m), e2 = expf(a2 - m), e3 = expf(a3 - m);
  float si = 1.0f / (e0 + e1 + e2 + e3);
  dp[0] = e0 * si; dp[1] = e1 * si; dp[2] = e2 * si; dp[3] = e3 * si;
}

// ---------------------------------------------------------------------------
// Conversions
// ---------------------------------------------------------------------------
__global__ __launch_bounds__(256) void k_cvt_bf16(const float* __restrict__ in,
                                                  unsigned short* __restrict__ out,
                                                  int n) {
  int i = blockIdx.x * 256 + threadIdx.x;
  if (i < n) out[i] = (unsigned short)f2bf(in[i]);
}

// in: f32 [K][N] row-major (+z*K*N); out: bf16 [N][K] (+z*K*N), scaled by
// cbase[z*4+cofs] (mixture coefficient folded into the weight).
__global__ __launch_bounds__(256) void k_transpose_cvt(const float* __restrict__ in,
                                                       unsigned short* __restrict__ out,
                                                       int K, int N,
                                                       const float* __restrict__ cbase,
                                                       int cofs) {
  __shared__ float tile[32][33];
  int z = blockIdx.z;
  float coef = cbase ? cbase[z * 4 + cofs] : 1.0f;
  size_t mofs = (size_t)z * K * N;
  in += mofs; out += mofs;
  int k0 = blockIdx.x * 32, n0 = blockIdx.y * 32;
  int tx = threadIdx.x & 31, ty = threadIdx.x >> 5;  // 32 x 8
#pragma unroll
  for (int i = 0; i < 4; ++i)
    tile[ty + 8 * i][tx] = in[(size_t)(k0 + ty + 8 * i) * N + n0 + tx];
  __syncthreads();
#pragma unroll
  for (int i = 0; i < 4; ++i)
    out[(size_t)(n0 + ty + 8 * i) * K + k0 + tx] =
        (unsigned short)f2bf(coef * tile[tx][ty + 8 * i]);
}

// ---------------------------------------------------------------------------
// Segment reductions (bf16 features). One wave per node, 4 nodes/block.
// ---------------------------------------------------------------------------
__global__ __launch_bounds__(256) void k_segmean_bf(const unsigned short* __restrict__ X,
                                                    const int* __restrict__ row_ofs,
                                                    const int* __restrict__ csr_src,
                                                    const float* __restrict__ invdeg,
                                                    unsigned short* __restrict__ out) {
  int node = blockIdx.x * 4 + (threadIdx.x >> 6);
  int l = threadIdx.x & 63;
  if (node >= N_NODES) return;
  int beg = row_ofs[node], end = row_ofs[node + 1];
  float s0 = 0.f, s1 = 0.f, s2 = 0.f, s3 = 0.f;
  for (int e = beg; e < end; ++e) {
    int si = csr_src[e];
    uint2 u = *(const uint2*)&X[(size_t)si * DIM + 4 * l];
    s0 += bf2f(u.x & 0xffffu); s1 += bf2f(u.x >> 16);
    s2 += bf2f(u.y & 0xffffu); s3 += bf2f(u.y >> 16);
  }
  float iv = invdeg[node];
  uint2 o;
  o.x = f2bf(s0 * iv) | (f2bf(s1 * iv) << 16);
  o.y = f2bf(s2 * iv) | (f2bf(s3 * iv) << 16);
  *(uint2*)&out[(size_t)node * DIM + 4 * l] = o;
}

__global__ __launch_bounds__(256) void k_segmean2_bf(const unsigned short* __restrict__ X0,
                                                     const unsigned short* __restrict__ X1,
                                                     const int* __restrict__ row_ofs,
                                                     const int* __restrict__ csr_src,
                                                     const float* __restrict__ invdeg,
                                                     unsigned short* __restrict__ out0,
                                                     unsigned short* __restrict__ out1) {
  int node = blockIdx.x * 4 + (threadIdx.x >> 6);
  int l = threadIdx.x & 63;
  if (node >= N_NODES) return;
  int beg = row_ofs[node], end = row_ofs[node + 1];
  float a0 = 0.f, a1 = 0.f, a2 = 0.f, a3 = 0.f;
  float b0 = 0.f, b1 = 0.f, b2 = 0.f, b3 = 0.f;
  for (int e = beg; e < end; ++e) {
    size_t rb = (size_t)csr_src[e] * DIM + 4 * l;
    uint2 u = *(const uint2*)&X0[rb];
    uint2 v = *(const uint2*)&X1[rb];
    a0 += bf2f(u.x & 0xffffu); a1 += bf2f(u.x >> 16);
    a2 += bf2f(u.y & 0xffffu); a3 += bf2f(u.y >> 16);
    b0 += bf2f(v.x & 0xffffu); b1 += bf2f(v.x >> 16);
    b2 += bf2f(v.y & 0xffffu); b3 += bf2f(v.y >> 16);
  }
  float iv = invdeg[node];
  uint2 o;
  o.x = f2bf(a0 * iv) | (f2bf(a1 * iv) << 16);
  o.y = f2bf(a2 * iv) | (f2bf(a3 * iv) << 16);
  *(uint2*)&out0[(size_t)node * DIM + 4 * l] = o;
  o.x = f2bf(b0 * iv) | (f2bf(b1 * iv) << 16);
  o.y = f2bf(b2 * iv) | (f2bf(b3 * iv) << 16);
  *(uint2*)&out1[(size_t)node * DIM + 4 * l] = o;
}

// sum+max over incoming msgs of relu'd input; epilogue = middle-stage mixture.
__global__ __launch_bounds__(256) void k_segmid_bf(const unsigned short* __restrict__ Xn,
                                                   const int* __restrict__ row_ofs,
                                                   const int* __restrict__ csr_src,
                                                   const float* __restrict__ invdeg,
                                                   const float* __restrict__ wrow,
                                                   unsigned short* __restrict__ mean_out,
                                                   unsigned short* __restrict__ mids_out) {
  int node = blockIdx.x * 4 + (threadIdx.x >> 6);
  int l = threadIdx.x & 63;
  if (node >= N_NODES) return;
  int beg = row_ofs[node], end = row_ofs[node + 1];
  float s0 = 0.f, s1 = 0.f, s2 = 0.f, s3 = 0.f;
  float m0 = 0.f, m1 = 0.f, m2 = 0.f, m3 = 0.f;  // inputs >= 0 (relu)
  for (int e = beg; e < end; ++e) {
    int si = csr_src[e];
    uint2 u = *(const uint2*)&Xn[(size_t)si * DIM + 4 * l];
    float v0 = bf2f(u.x & 0xffffu), v1 = bf2f(u.x >> 16);
    float v2 = bf2f(u.y & 0xffffu), v3 = bf2f(u.y >> 16);
    s0 += v0; s1 += v1; s2 += v2; s3 += v3;
    m0 = fmaxf(m0, v0); m1 = fmaxf(m1, v1);
    m2 = fmaxf(m2, v2); m3 = fmaxf(m3, v3);
  }
  float iv = invdeg[node];
  float e0 = s0 * iv, e1 = s1 * iv, e2 = s2 * iv, e3 = s3 * iv;
  if (mean_out) {
    uint2 o;
    o.x = f2bf(e0) | (f2bf(e1) << 16);
    o.y = f2bf(e2) | (f2bf(e3) << 16);
    *(uint2*)&mean_out[(size_t)node * DIM + 4 * l] = o;
  }
  float w0 = wrow[0], w1 = wrow[1], w2 = wrow[2], w3 = wrow[3];
  uint2 xu = *(const uint2*)&Xn[(size_t)node * DIM + 4 * l];
  float x0 = bf2f(xu.x & 0xffffu), x1 = bf2f(xu.x >> 16);
  float x2 = bf2f(xu.y & 0xffffu), x3 = bf2f(xu.y >> 16);
  uint2 o;
  o.x = f2bf(w0 * x0 + w1 * m0 + w2 * e0 + w3 * s0) |
        (f2bf(w0 * x1 + w1 * m1 + w2 * e1 + w3 * s1) << 16);
  o.y = f2bf(w0 * x2 + w1 * m2 + w2 * e2 + w3 * s2) |
        (f2bf(w0 * x3 + w1 * m3 + w2 * e3 + w3 * s3) << 16);
  *(uint2*)&mids_out[(size_t)node * DIM + 4 * l] = o;
}

// ---------------------------------------------------------------------------
// MFMA multi-term GEMM, coefficients pre-folded into W:
//   r = relu( sum_t (A_t@W_t) + c_t*b_t + sum_u ic_u*I_u )
//   out = resid ? resid + 0.5*(addl + r) : r
// Fused K loop across terms, double-buffered LDS, 1 barrier per k-step.
// Block 64x64, 4 waves (2x2), wave tile 32x32 = 2x2 mfma_16x16x32 frags.
// ---------------------------------------------------------------------------
struct GemmDescB {
  const unsigned short* A[6];
  const unsigned short* W[6];
  const float* b[6];
  const float* c[6];
  const unsigned short* I[3];
  const float* ic[3];
  const float* resid;          // f32 x (residual stream)
  const unsigned short* addl;  // bf16 l0
  float* out_f32;              // optional f32 copy (residual stream)
  unsigned short* out_bf;
  int nmat, nid, K, relu;
};

__global__ __launch_bounds__(256) void k_gemm_mfma(GemmDescB d) {
  __shared__ __align__(16) unsigned short As[2][64][72];
  __shared__ __align__(16) unsigned short Bs[2][64][72];
  const int tid = threadIdx.x;
  const int bm = blockIdx.x * 64, bn = blockIdx.y * 64;
  const int w = tid >> 6, l = tid & 63;
  const int wm = (w >> 1) * 32, wn = (w & 1) * 32;
  const int lr = l & 15, lk = (l >> 4) * 8;
  const int ldr = tid >> 3, ldk = (tid & 7) * 8;

  const int K = d.K;
  const int kds = (K == 256) ? 2 : 1;  // log2(k-steps per term)
  const int kmask = (1 << kds) - 1;
  const int nsteps = d.nmat << kds;

  f32x4 zero = {0.f, 0.f, 0.f, 0.f};
  f32x4 acc[2][2];
  acc[0][0] = zero; acc[0][1] = zero; acc[1][0] = zero; acc[1][1] = zero;

  auto gload = [&](int s, uint4& a0, uint4& a1, uint4& b0, uint4& b1) {
    int t = s >> kds;
    int k0 = (s & kmask) << 6;
    const unsigned short* __restrict__ A = d.A[t];
    const unsigned short* __restrict__ W = d.W[t];
    a0 = *(const uint4*)&A[(size_t)(bm + ldr) * K + k0 + ldk];
    a1 = *(const uint4*)&A[(size_t)(bm + ldr + 32) * K + k0 + ldk];
    b0 = *(const uint4*)&W[(size_t)(bn + ldr) * K + k0 + ldk];
    b1 = *(const uint4*)&W[(size_t)(bn + ldr + 32) * K + k0 + ldk];
  };

  {
    uint4 a0, a1, b0, b1;
    gload(0, a0, a1, b0, b1);
    *(uint4*)&As[0][ldr][ldk] = a0;
    *(uint4*)&As[0][ldr + 32][ldk] = a1;
    *(uint4*)&Bs[0][ldr][ldk] = b0;
    *(uint4*)&Bs[0][ldr + 32][ldk] = b1;
  }
  __syncthreads();

  int buf = 0;
  for (int s = 0; s < nsteps; ++s) {
    uint4 na0, na1, nb0, nb1;
    const bool more = (s + 1 < nsteps);
    if (more) gload(s + 1, na0, na1, nb0, nb1);  // issue early; latency hides
#pragma unroll
    for (int ks = 0; ks < 2; ++ks) {
      bf16x8 a0 = *(const bf16x8*)&As[buf][wm + lr][ks * 32 + lk];
      bf16x8 a1 = *(const bf16x8*)&As[buf][wm + 16 + lr][ks * 32 + lk];
      bf16x8 b0 = *(const bf16x8*)&Bs[buf][wn + lr][ks * 32 + lk];
      bf16x8 b1 = *(const bf16x8*)&Bs[buf][wn + 16 + lr][ks * 32 + lk];
      acc[0][0] = __builtin_amdgcn_mfma_f32_16x16x32_bf16(a0, b0, acc[0][0], 0, 0, 0);
      acc[0][1] = __builtin_amdgcn_mfma_f32_16x16x32_bf16(a0, b1, acc[0][1], 0, 0, 0);
      acc[1][0] = __builtin_amdgcn_mfma_f32_16x16x32_bf16(a1, b0, acc[1][0], 0, 0, 0);
      acc[1][1] = __builtin_amdgcn_mfma_f32_16x16x32_bf16(a1, b1, acc[1][1], 0, 0, 0);
    }
    if (more) {
      *(uint4*)&As[buf ^ 1][ldr][ldk] = na0;
      *(uint4*)&As[buf ^ 1][ldr + 32][ldk] = na1;
      *(uint4*)&Bs[buf ^ 1][ldr][ldk] = nb0;
      *(uint4*)&Bs[buf ^ 1][ldr + 32][ldk] = nb1;
    }
    __syncthreads();
    buf ^= 1;
  }

  // epilogue
  float bias[2] = {0.f, 0.f};
  for (int t = 0; t < d.nmat; ++t) {
    if (d.b[t]) {
      float c = d.c[t] ? *d.c[t] : 1.0f;
      bias[0] += c * d.b[t][bn + wn + lr];
      bias[1] += c * d.b[t][bn + wn + 16 + lr];
    }
  }
  float vout[2][2][4];
#pragma unroll
  for (int m = 0; m < 2; ++m)
#pragma unroll
    for (int n = 0; n < 2; ++n)
#pragma unroll
      for (int i = 0; i < 4; ++i) vout[m][n][i] = acc[m][n][i] + bias[n];
#pragma unroll
  for (int u = 0; u < 3; ++u) {
    if (u < d.nid) {
      float icu = *d.ic[u];
      const unsigned short* __restrict__ I = d.I[u];
#pragma unroll
      for (int m = 0; m < 2; ++m)
#pragma unroll
        for (int n = 0; n < 2; ++n)
#pragma unroll
          for (int i = 0; i < 4; ++i) {
            int row = bm + wm + m * 16 + (l >> 4) * 4 + i;
            int col = bn + wn + n * 16 + lr;
            vout[m][n][i] += icu * bf2f(I[(size_t)row * DIM + col]);
          }
    }
  }
#pragma unroll
  for (int m = 0; m < 2; ++m)
#pragma unroll
    for (int n = 0; n < 2; ++n)
#pragma unroll
      for (int i = 0; i < 4; ++i) {
        int row = bm + wm + m * 16 + (l >> 4) * 4 + i;
        int col = bn + wn + n * 16 + lr;
        size_t idx = (size_t)row * DIM + col;
        float v = vout[m][n][i];
        if (d.relu) v = fmaxf(v, 0.f);
        if (d.resid) v = d.resid[idx] + 0.5f * (bf2f(d.addl[idx]) + v);
        d.out_bf[idx] = (unsigned short)f2bf(v);
        if (d.out_f32) d.out_f32[idx] = v;
      }
}

// ---------------------------------------------------------------------------
// Readout + MLP
// ---------------------------------------------------------------------------
__global__ __launch_bounds__(256) void k_readout(const float* __restrict__ x,
                                                 const int* __restrict__ gid,
                                                 float* __restrict__ hg) {
  int g = blockIdx.x, t = threadIdx.x;
  int lo = 0, hi = N_NODES;
  while (lo < hi) { int m = (lo + hi) >> 1; if (gid[m] < g) lo = m + 1; else hi = m; }
  int beg = lo;
  lo = beg; hi = N_NODES;
  while (lo < hi) { int m = (lo + hi) >> 1; if (gid[m] <= g) lo = m + 1; else hi = m; }
  int end = lo;
  float s = 0.f;
  for (int i = beg; i < end; ++i) s += x[(size_t)i * DIM + t];
  int cnt = end - beg;
  hg[g * DIM + t] = s / (float)(cnt > 1 ? cnt : 1);
}

__global__ __launch_bounds__(256) void k_mlp(const float* __restrict__ hg,
                                             const float* __restrict__ C1,
                                             const float* __restrict__ c1b,
                                             const float* __restrict__ C2,
                                             const float* __restrict__ c2b,
                                             const float* __restrict__ C3,
                                             const float* __restrict__ c3b,
                                             float* __restrict__ out) {
  int g = blockIdx.x, t = threadIdx.x;
  __shared__ float h0[256], h1[128], h2[64];
  h0[t] = hg[g * DIM + t];
  __syncthreads();
  if (t < 128) {
    float s = c1b[t];
    for (int k = 0; k < 256; ++k) s = fmaf(h0[k], C1[k * 128 + t], s);
    h1[t] = fmaxf(s, 0.f);
  }
  __syncthreads();
  if (t < 64) {
    float s = c2b[t];
    for (int k = 0; k < 128; ++k) s = fmaf(h1[k], C2[k * 64 + t], s);
    h2[t] = fmaxf(s, 0.f);
  }
  __syncthreads();
  if (t < 10) {
    float s = c3b[t];
    for (int k = 0; k < 64; ++k) s = fmaf(h2[k], C3[k * 10 + t], s);
    out[g * 10 + t] = s;
  }
}

// ---------------------------------------------------------------------------
extern "C" void kernel_launch(void* const* d_in, const int* in_sizes, int n_in,
                              void* d_out, int out_size, void* d_ws, size_t ws_size,
                              hipStream_t stream) {
  const float* h     = (const float*)d_in[0];
  const float* W_emb = (const float*)d_in[1];
  const float* b_emb = (const float*)d_in[2];
  const float* Wf_d  = (const float*)d_in[3];
  const float* bf_d  = (const float*)d_in[4];
  const float* Wf_s  = (const float*)d_in[5];
  const float* bf_s  = (const float*)d_in[6];
  const float* Wl_d  = (const float*)d_in[7];
  const float* bl_d  = (const float*)d_in[8];
  const float* Wl_s  = (const float*)d_in[9];
  const float* bl_s  = (const float*)d_in[10];
  const float* a_first = (const float*)d_in[11];
  const float* a_mid   = (const float*)d_in[12];
  const float* a_last  = (const float*)d_in[13];
  const float* C1 = (const float*)d_in[14];
  const float* c1b = (const float*)d_in[15];
  const float* C2 = (const float*)d_in[16];
  const float* c2b = (const float*)d_in[17];
  const float* C3 = (const float*)d_in[18];
  const float* c3b = (const float*)d_in[19];
  const int* src = (const int*)d_in[20];
  const int* dst = (const int*)d_in[21];
  const int* gid = (const int*)d_in[22];
  (void)in_sizes; (void)n_in; (void)out_size; (void)ws_size;

  char* p = (char*)d_ws;
  auto alloc = [&](size_t bytes) {
    void* r = (void*)p;
    p += (bytes + 255) & ~(size_t)255;
    return r;
  };
  typedef unsigned short u16;
  const size_t NBF = (size_t)N_NODES * DIM * sizeof(u16);  // 4.096 MB
  float* x_f32 = (float*)alloc((size_t)N_NODES * DIM * sizeof(float));
  u16* xb    = (u16*)alloc(NBF);
  u16* s1b   = (u16*)alloc(NBF);
  u16* s2b   = (u16*)alloc(NBF);
  u16* m0b   = (u16*)alloc(NBF);
  u16* m1b   = (u16*)alloc(NBF);
  u16* l0b   = (u16*)alloc(NBF);
  u16* aggAb = (u16*)alloc(NBF);
  u16* aggBb = (u16*)alloc(NBF);
  u16* h_bf  = (u16*)alloc((size_t)N_NODES * IN_DIM * sizeof(u16));
  // transposed bf16 weights (coef-prescaled): W_emb^T, Wf_d(6), Wf_s(6), Wl_d(10), Wl_s(10)
  u16* WT    = (u16*)alloc((size_t)(DIM * IN_DIM + 32 * DIM * DIM) * sizeof(u16));
  u16* WTe   = WT;
  u16* WTfd  = WT + DIM * IN_DIM;
  u16* WTfs  = WTfd + 6 * DIM * DIM;
  u16* WTld  = WTfs + 6 * DIM * DIM;
  u16* WTls  = WTld + 10 * DIM * DIM;
  float* invdeg = (float*)alloc(N_NODES * sizeof(float));
  int* counts  = (int*)alloc(N_NODES * sizeof(int));
  int* row_ofs = (int*)alloc((N_NODES + 1) * sizeof(int));
  int* cursor  = (int*)alloc(N_NODES * sizeof(int));
  int* csr_src = (int*)alloc(N_EDGES * sizeof(int));
  float* wsoft = (float*)alloc(80 * sizeof(float));
  float* hg    = (float*)alloc(N_GRAPHS * DIM * sizeof(float));

  const int EB = (N_EDGES + 255) / 256;

  hipMemsetAsync(counts, 0, N_NODES * sizeof(int), stream);
  k_count<<<EB, 256, 0, stream>>>(dst, counts);
  k_scan<<<1, 256, 0, stream>>>(counts, row_ofs, cursor, invdeg);
  k_fill<<<EB, 256, 0, stream>>>(src, dst, cursor, csr_src);
  k_softmax<<<1, 64, 0, stream>>>(a_first, a_mid, a_last, wsoft);

  const float* wf = wsoft;
  const float* wm = wsoft + 24;
  const float* wl = wsoft + 40;

  // conversions (W prescaled by its mixture coefficient: dense -> w[2], sparse -> w[3])
  k_cvt_bf16<<<(N_NODES * IN_DIM + 255) / 256, 256, 0, stream>>>(h, h_bf, N_NODES * IN_DIM);
  k_transpose_cvt<<<dim3(IN_DIM / 32, DIM / 32, 1), 256, 0, stream>>>(W_emb, WTe, IN_DIM, DIM, nullptr, 0);
  k_transpose_cvt<<<dim3(8, 8, 6), 256, 0, stream>>>(Wf_d, WTfd, DIM, DIM, wf, 2);
  k_transpose_cvt<<<dim3(8, 8, 6), 256, 0, stream>>>(Wf_s, WTfs, DIM, DIM, wf, 3);
  k_transpose_cvt<<<dim3(8, 8, 10), 256, 0, stream>>>(Wl_d, WTld, DIM, DIM, wl, 2);
  k_transpose_cvt<<<dim3(8, 8, 10), 256, 0, stream>>>(Wl_s, WTls, DIM, DIM, wl, 3);

  const dim3 ggrid(N_NODES / 64, DIM / 64);  // 125 x 4
  const int SB = (N_NODES + 3) / 4;          // seg blocks

  // embedding: x = h @ W_emb + b_emb   (f32 + bf16 outputs)
  {
    GemmDescB d{};
    d.A[0] = h_bf; d.W[0] = WTe; d.b[0] = b_emb; d.c[0] = nullptr;
    d.nmat = 1; d.nid = 0; d.K = IN_DIM; d.relu = 0;
    d.out_f32 = x_f32; d.out_bf = xb;
    k_gemm_mfma<<<ggrid, 256, 0, stream>>>(d);
  }

  for (int l = 0; l < 2; ++l) {
    auto WFD = [&](int e) { return WTfd + (size_t)(l * 3 + e) * DIM * DIM; };
    auto BFD = [&](int e) { return bf_d + (size_t)(l * 3 + e) * DIM; };
    auto WFS = [&](int e) { return WTfs + (size_t)(l * 3 + e) * DIM * DIM; };
    auto BFS = [&](int e) { return bf_s + (size_t)(l * 3 + e) * DIM; };
    auto WLD = [&](int e) { return WTld + (size_t)(l * 5 + e) * DIM * DIM; };
    auto BLD = [&](int e) { return bl_d + (size_t)(l * 5 + e) * DIM; };
    auto WLS = [&](int e) { return WTls + (size_t)(l * 5 + e) * DIM * DIM; };
    auto BLS = [&](int e) { return bl_s + (size_t)(l * 5 + e) * DIM; };
    auto WFrow = [&](int e) { return wf + (l * 3 + e) * 4; };
    auto WMrow = [&](int n) { return wm + (l * 2 + n) * 4; };
    auto WLrow = [&](int e) { return wl + (l * 5 + e) * 4; };

    auto edge = [&](GemmDescB& d, const u16* X, const u16* AG,
                    const u16* Wd, const float* bd,
                    const u16* Ws, const float* bs, const float* wrow) {
      d.A[d.nmat] = X;  d.W[d.nmat] = Wd; d.b[d.nmat] = bd; d.c[d.nmat] = wrow + 2; d.nmat++;
      d.A[d.nmat] = AG; d.W[d.nmat] = Ws; d.b[d.nmat] = bs; d.c[d.nmat] = wrow + 3; d.nmat++;
      d.I[d.nid] = X; d.ic[d.nid] = wrow + 1; d.nid++;
    };

    // aggA = mean-agg(x)
    k_segmean_bf<<<SB, 256, 0, stream>>>(xb, row_ofs, csr_src, invdeg, aggAb);

    // s1 = relu(mixed(x, e0))
    {
      GemmDescB d{}; d.K = DIM; d.relu = 1; d.out_bf = s1b;
      edge(d, xb, aggAb, WFD(0), BFD(0), WFS(0), BFS(0), WFrow(0));
      k_gemm_mfma<<<ggrid, 256, 0, stream>>>(d);
    }

    // mid of s1: mean -> aggB (DAG agg of states[1]); mixture -> mids0
    k_segmid_bf<<<SB, 256, 0, stream>>>(s1b, row_ofs, csr_src, invdeg, WMrow(0), aggBb, m0b);

    // s2 = relu(mixed(x, e1) + mixed(s1, e2))
    {
      GemmDescB d{}; d.K = DIM; d.relu = 1; d.out_bf = s2b;
      edge(d, xb,  aggAb, WFD(1), BFD(1), WFS(1), BFS(1), WFrow(1));
      edge(d, s1b, aggBb, WFD(2), BFD(2), WFS(2), BFS(2), WFrow(2));
      k_gemm_mfma<<<ggrid, 256, 0, stream>>>(d);
    }

    // mid of s2 -> mids1
    k_segmid_bf<<<SB, 256, 0, stream>>>(s2b, row_ofs, csr_src, invdeg, WMrow(1), nullptr, m1b);

    // mean-aggs of mids0, mids1
    k_segmean2_bf<<<SB, 256, 0, stream>>>(m0b, m1b, row_ofs, csr_src, invdeg, aggAb, aggBb);

    // l0 = relu(mixed(mids0,e0) + mixed(mids1,e1))
    {
      GemmDescB d{}; d.K = DIM; d.relu = 1; d.out_bf = l0b;
      edge(d, m0b, aggAb, WLD(0), BLD(0), WLS(0), BLS(0), WLrow(0));
      edge(d, m1b, aggBb, WLD(1), BLD(1), WLS(1), BLS(1), WLrow(1));
      k_gemm_mfma<<<ggrid, 256, 0, stream>>>(d);
    }

    // mean-agg of l0 -> s1b (dead)
    k_segmean_bf<<<SB, 256, 0, stream>>>(l0b, row_ofs, csr_src, invdeg, s1b);

    // x = x + 0.5*(l0 + relu(mixed(mids0,e2)+mixed(mids1,e3)+mixed(l0,e4)))
    {
      GemmDescB d{}; d.K = DIM; d.relu = 1;
      edge(d, m0b, aggAb, WLD(2), BLD(2), WLS(2), BLS(2), WLrow(2));
      edge(d, m1b, aggBb, WLD(3), BLD(3), WLS(3), BLS(3), WLrow(3));
      edge(d, l0b, s1b,   WLD(4), BLD(4), WLS(4), BLS(4), WLrow(4));
      d.resid = x_f32; d.addl = l0b;
      d.out_f32 = x_f32; d.out_bf = xb;
      k_gemm_mfma<<<ggrid, 256, 0, stream>>>(d);
    }
  }

  k_readout<<<N_GRAPHS, 256, 0, stream>>>(x_f32, gid, hg);
  k_mlp<<<N_GRAPHS, 256, 0, stream>>>(hg, C1, c1b, C2, c2b, C3, c3b, (float*)d_out);
}

// Round 5
// 361.335 us; speedup vs baseline: 2.9006x; 1.1979x over previous
//
#include <hip/hip_runtime.h>

#define N_NODES   8000
#define M_PAD     8192
#define N_EDGES   128000
#define N_GRAPHS  64
#define DIM       256
#define IN_DIM    128

typedef short bf16x8 __attribute__((ext_vector_type(8)));
typedef float f32x4 __attribute__((ext_vector_type(4)));

static __device__ __forceinline__ float bf2f(unsigned v) {
  return __uint_as_float(v << 16);
}
static __device__ __forceinline__ unsigned f2bf(float f) {
  unsigned u = __float_as_uint(f);
  return (u + 0x7fffu + ((u >> 16) & 1u)) >> 16;
}

// ---------------------------------------------------------------------------
// CSR build
// ---------------------------------------------------------------------------
__global__ __launch_bounds__(256) void k_count(const int* __restrict__ dst,
                                               int* __restrict__ counts) {
  int e = blockIdx.x * 256 + threadIdx.x;
  if (e < N_EDGES) atomicAdd(&counts[dst[e]], 1);
}

__global__ __launch_bounds__(256) void k_scan(const int* __restrict__ counts,
                                              int* __restrict__ row_ofs,
                                              int* __restrict__ cursor,
                                              float* __restrict__ invdeg) {
  __shared__ int chunk[256];
  const int per = (N_NODES + 255) / 256;  // 32
  int t = threadIdx.x;
  int base = t * per;
  int s = 0;
  for (int i = 0; i < per; ++i) {
    int idx = base + i;
    if (idx < N_NODES) s += counts[idx];
  }
  chunk[t] = s;
  __syncthreads();
  for (int off = 1; off < 256; off <<= 1) {
    int v = 0;
    if (t >= off) v = chunk[t - off];
    __syncthreads();
    if (t >= off) chunk[t] += v;
    __syncthreads();
  }
  int run = (t > 0) ? chunk[t - 1] : 0;
  for (int i = 0; i < per; ++i) {
    int idx = base + i;
    if (idx < N_NODES) {
      row_ofs[idx] = run;
      cursor[idx] = run;
      int c = counts[idx];
      invdeg[idx] = 1.0f / (float)(c > 1 ? c : 1);
      run += c;
    }
  }
  if (t == 0) row_ofs[N_NODES] = chunk[255];
}

__global__ __launch_bounds__(256) void k_fill(const int* __restrict__ src,
                                              const int* __restrict__ dst,
                                              int* __restrict__ cursor,
                                              int* __restrict__ csr_src) {
  int e = blockIdx.x * 256 + threadIdx.x;
  if (e < N_EDGES) {
    int p = atomicAdd(&cursor[dst[e]], 1);
    csr_src[p] = src[e];
  }
}

// ---------------------------------------------------------------------------
// Softmax over architecture rows; wsoft: [0..23]=wf, [24..39]=wm, [40..79]=wl
// ---------------------------------------------------------------------------
__global__ __launch_bounds__(64) void k_softmax(const float* __restrict__ af,
                                                const float* __restrict__ am,
                                                const float* __restrict__ al,
                                                float* __restrict__ w) {
  int t = threadIdx.x;
  const float* sp;
  float* dp;
  if (t < 6)       { sp = af + t * 4;        dp = w + t * 4; }
  else if (t < 10) { sp = am + (t - 6) * 4;  dp = w + 24 + (t - 6) * 4; }
  else if (t < 20) { sp = al + (t - 10) * 4; dp = w + 40 + (t - 10) * 4; }
  else return;
  float a0 = sp[0], a1 = sp[1], a2 = sp[2], a3 = sp[3];
  float m = fmaxf(fmaxf(a0, a1), fmaxf(a2, a3));
  float e0 = expf(a0 - m), e1 = expf(a1 - m), e2 = expf(a2 - m), e3 = expf(a3 - m);
  float si = 1.0f / (e0 + e1 + e2 + e3);
  dp[0] = e0 * si; dp[1] = e1 * si; dp[2] = e2 * si; dp[3] = e3 * si;
}

// ---------------------------------------------------------------------------
// Conversions
// ---------------------------------------------------------------------------
__global__ __launch_bounds__(256) void k_cvt_bf16(const float* __restrict__ in,
                                                  unsigned short* __restrict__ out,
                                                  int n) {
  int i = blockIdx.x * 256 + threadIdx.x;
  if (i < n) out[i] = (unsigned short)f2bf(in[i]);
}

// W_emb^T only (K=IN_DIM)
__global__ __launch_bounds__(256) void k_transpose_cvt(const float* __restrict__ in,
                                                       unsigned short* __restrict__ out,
                                                       int K, int N) {
  __shared__ float tile[32][33];
  int k0 = blockIdx.x * 32, n0 = blockIdx.y * 32;
  int tx = threadIdx.x & 31, ty = threadIdx.x >> 5;  // 32 x 8
#pragma unroll
  for (int i = 0; i < 4; ++i)
    tile[ty + 8 * i][tx] = in[(size_t)(k0 + ty + 8 * i) * N + n0 + tx];
  __syncthreads();
#pragma unroll
  for (int i = 0; i < 4; ++i)
    out[(size_t)(n0 + ty + 8 * i) * K + k0 + tx] =
        (unsigned short)f2bf(tile[tx][ty + 8 * i]);
}

// all 32 DIMxDIM cell weights in one launch, coef-prescaled:
// z<6: Wf_d (coef wf[z,2]); z<12: Wf_s (wf[z-6,3]); z<22: Wl_d (wl[z-12,2]);
// z<32: Wl_s (wl[z-22,3]). out = WTbase + z*DIM*DIM (contiguous).
__global__ __launch_bounds__(256) void k_transpose_cvt32(const float* __restrict__ Wfd,
                                                         const float* __restrict__ Wfs,
                                                         const float* __restrict__ Wld,
                                                         const float* __restrict__ Wls,
                                                         const float* __restrict__ wsoft,
                                                         unsigned short* __restrict__ out) {
  __shared__ float tile[32][33];
  int z = blockIdx.z;
  const float* in;
  float coef;
  const float* wf = wsoft;
  const float* wl = wsoft + 40;
  if (z < 6)       { in = Wfd + (size_t)z * DIM * DIM;        coef = wf[z * 4 + 2]; }
  else if (z < 12) { in = Wfs + (size_t)(z - 6) * DIM * DIM;  coef = wf[(z - 6) * 4 + 3]; }
  else if (z < 22) { in = Wld + (size_t)(z - 12) * DIM * DIM; coef = wl[(z - 12) * 4 + 2]; }
  else             { in = Wls + (size_t)(z - 22) * DIM * DIM; coef = wl[(z - 22) * 4 + 3]; }
  unsigned short* o = out + (size_t)z * DIM * DIM;
  int k0 = blockIdx.x * 32, n0 = blockIdx.y * 32;
  int tx = threadIdx.x & 31, ty = threadIdx.x >> 5;
#pragma unroll
  for (int i = 0; i < 4; ++i)
    tile[ty + 8 * i][tx] = in[(size_t)(k0 + ty + 8 * i) * DIM + n0 + tx];
  __syncthreads();
#pragma unroll
  for (int i = 0; i < 4; ++i)
    o[(size_t)(n0 + ty + 8 * i) * DIM + k0 + tx] =
        (unsigned short)f2bf(coef * tile[tx][ty + 8 * i]);
}

// ---------------------------------------------------------------------------
// Segment reductions (bf16). One wave per node, 4 nodes/block, 4-edge unroll.
// ---------------------------------------------------------------------------
#define SEG_ACC(u) \
  { s0 += bf2f((u).x & 0xffffu); s1 += bf2f((u).x >> 16); \
    s2 += bf2f((u).y & 0xffffu); s3 += bf2f((u).y >> 16); }

__global__ __launch_bounds__(256) void k_segmean_bf(const unsigned short* __restrict__ X,
                                                    const int* __restrict__ row_ofs,
                                                    const int* __restrict__ csr_src,
                                                    const float* __restrict__ invdeg,
                                                    unsigned short* __restrict__ out) {
  int node = blockIdx.x * 4 + (threadIdx.x >> 6);
  int l = threadIdx.x & 63;
  if (node >= N_NODES) return;
  int beg = row_ofs[node], end = row_ofs[node + 1];
  float s0 = 0.f, s1 = 0.f, s2 = 0.f, s3 = 0.f;
  int e = beg;
  for (; e + 4 <= end; e += 4) {
    int i0 = csr_src[e], i1 = csr_src[e + 1], i2 = csr_src[e + 2], i3 = csr_src[e + 3];
    uint2 u0 = *(const uint2*)&X[(size_t)i0 * DIM + 4 * l];
    uint2 u1 = *(const uint2*)&X[(size_t)i1 * DIM + 4 * l];
    uint2 u2 = *(const uint2*)&X[(size_t)i2 * DIM + 4 * l];
    uint2 u3 = *(const uint2*)&X[(size_t)i3 * DIM + 4 * l];
    SEG_ACC(u0) SEG_ACC(u1) SEG_ACC(u2) SEG_ACC(u3)
  }
  for (; e < end; ++e) {
    uint2 u = *(const uint2*)&X[(size_t)csr_src[e] * DIM + 4 * l];
    SEG_ACC(u)
  }
  float iv = invdeg[node];
  uint2 o;
  o.x = f2bf(s0 * iv) | (f2bf(s1 * iv) << 16);
  o.y = f2bf(s2 * iv) | (f2bf(s3 * iv) << 16);
  *(uint2*)&out[(size_t)node * DIM + 4 * l] = o;
}

__global__ __launch_bounds__(256) void k_segmean2_bf(const unsigned short* __restrict__ X0,
                                                     const unsigned short* __restrict__ X1,
                                                     const int* __restrict__ row_ofs,
                                                     const int* __restrict__ csr_src,
                                                     const float* __restrict__ invdeg,
                                                     unsigned short* __restrict__ out0,
                                                     unsigned short* __restrict__ out1) {
  int node = blockIdx.x * 4 + (threadIdx.x >> 6);
  int l = threadIdx.x & 63;
  if (node >= N_NODES) return;
  int beg = row_ofs[node], end = row_ofs[node + 1];
  float a0 = 0.f, a1 = 0.f, a2 = 0.f, a3 = 0.f;
  float b0 = 0.f, b1 = 0.f, b2 = 0.f, b3 = 0.f;
  int e = beg;
  for (; e + 2 <= end; e += 2) {
    size_t r0 = (size_t)csr_src[e] * DIM + 4 * l;
    size_t r1 = (size_t)csr_src[e + 1] * DIM + 4 * l;
    uint2 u0 = *(const uint2*)&X0[r0];
    uint2 v0 = *(const uint2*)&X1[r0];
    uint2 u1 = *(const uint2*)&X0[r1];
    uint2 v1 = *(const uint2*)&X1[r1];
    a0 += bf2f(u0.x & 0xffffu) + bf2f(u1.x & 0xffffu);
    a1 += bf2f(u0.x >> 16) + bf2f(u1.x >> 16);
    a2 += bf2f(u0.y & 0xffffu) + bf2f(u1.y & 0xffffu);
    a3 += bf2f(u0.y >> 16) + bf2f(u1.y >> 16);
    b0 += bf2f(v0.x & 0xffffu) + bf2f(v1.x & 0xffffu);
    b1 += bf2f(v0.x >> 16) + bf2f(v1.x >> 16);
    b2 += bf2f(v0.y & 0xffffu) + bf2f(v1.y & 0xffffu);
    b3 += bf2f(v0.y >> 16) + bf2f(v1.y >> 16);
  }
  for (; e < end; ++e) {
    size_t rb = (size_t)csr_src[e] * DIM + 4 * l;
    uint2 u = *(const uint2*)&X0[rb];
    uint2 v = *(const uint2*)&X1[rb];
    a0 += bf2f(u.x & 0xffffu); a1 += bf2f(u.x >> 16);
    a2 += bf2f(u.y & 0xffffu); a3 += bf2f(u.y >> 16);
    b0 += bf2f(v.x & 0xffffu); b1 += bf2f(v.x >> 16);
    b2 += bf2f(v.y & 0xffffu); b3 += bf2f(v.y >> 16);
  }
  float iv = invdeg[node];
  uint2 o;
  o.x = f2bf(a0 * iv) | (f2bf(a1 * iv) << 16);
  o.y = f2bf(a2 * iv) | (f2bf(a3 * iv) << 16);
  *(uint2*)&out0[(size_t)node * DIM + 4 * l] = o;
  o.x = f2bf(b0 * iv) | (f2bf(b1 * iv) << 16);
  o.y = f2bf(b2 * iv) | (f2bf(b3 * iv) << 16);
  *(uint2*)&out1[(size_t)node * DIM + 4 * l] = o;
}

// sum+max over incoming msgs of relu'd input; epilogue = middle-stage mixture.
__global__ __launch_bounds__(256) void k_segmid_bf(const unsigned short* __restrict__ Xn,
                                                   const int* __restrict__ row_ofs,
                                                   const int* __restrict__ csr_src,
                                                   const float* __restrict__ invdeg,
                                                   const float* __restrict__ wrow,
                                                   unsigned short* __restrict__ mean_out,
                                                   unsigned short* __restrict__ mids_out) {
  int node = blockIdx.x * 4 + (threadIdx.x >> 6);
  int l = threadIdx.x & 63;
  if (node >= N_NODES) return;
  int beg = row_ofs[node], end = row_ofs[node + 1];
  float s0 = 0.f, s1 = 0.f, s2 = 0.f, s3 = 0.f;
  float m0 = 0.f, m1 = 0.f, m2 = 0.f, m3 = 0.f;  // inputs >= 0 (relu)
  int e = beg;
  for (; e + 4 <= end; e += 4) {
    int i0 = csr_src[e], i1 = csr_src[e + 1], i2 = csr_src[e + 2], i3 = csr_src[e + 3];
    uint2 u0 = *(const uint2*)&Xn[(size_t)i0 * DIM + 4 * l];
    uint2 u1 = *(const uint2*)&Xn[(size_t)i1 * DIM + 4 * l];
    uint2 u2 = *(const uint2*)&Xn[(size_t)i2 * DIM + 4 * l];
    uint2 u3 = *(const uint2*)&Xn[(size_t)i3 * DIM + 4 * l];
#pragma unroll
    for (int j = 0; j < 4; ++j) {
      uint2 u = (j == 0) ? u0 : (j == 1) ? u1 : (j == 2) ? u2 : u3;
      float v0 = bf2f(u.x & 0xffffu), v1 = bf2f(u.x >> 16);
      float v2 = bf2f(u.y & 0xffffu), v3 = bf2f(u.y >> 16);
      s0 += v0; s1 += v1; s2 += v2; s3 += v3;
      m0 = fmaxf(m0, v0); m1 = fmaxf(m1, v1);
      m2 = fmaxf(m2, v2); m3 = fmaxf(m3, v3);
    }
  }
  for (; e < end; ++e) {
    uint2 u = *(const uint2*)&Xn[(size_t)csr_src[e] * DIM + 4 * l];
    float v0 = bf2f(u.x & 0xffffu), v1 = bf2f(u.x >> 16);
    float v2 = bf2f(u.y & 0xffffu), v3 = bf2f(u.y >> 16);
    s0 += v0; s1 += v1; s2 += v2; s3 += v3;
    m0 = fmaxf(m0, v0); m1 = fmaxf(m1, v1);
    m2 = fmaxf(m2, v2); m3 = fmaxf(m3, v3);
  }
  float iv = invdeg[node];
  float e0 = s0 * iv, e1 = s1 * iv, e2 = s2 * iv, e3 = s3 * iv;
  if (mean_out) {
    uint2 o;
    o.x = f2bf(e0) | (f2bf(e1) << 16);
    o.y = f2bf(e2) | (f2bf(e3) << 16);
    *(uint2*)&mean_out[(size_t)node * DIM + 4 * l] = o;
  }
  float w0 = wrow[0], w1 = wrow[1], w2 = wrow[2], w3 = wrow[3];
  uint2 xu = *(const uint2*)&Xn[(size_t)node * DIM + 4 * l];
  float x0 = bf2f(xu.x & 0xffffu), x1 = bf2f(xu.x >> 16);
  float x2 = bf2f(xu.y & 0xffffu), x3 = bf2f(xu.y >> 16);
  uint2 o;
  o.x = f2bf(w0 * x0 + w1 * m0 + w2 * e0 + w3 * s0) |
        (f2bf(w0 * x1 + w1 * m1 + w2 * e1 + w3 * s1) << 16);
  o.y = f2bf(w0 * x2 + w1 * m2 + w2 * e2 + w3 * s2) |
        (f2bf(w0 * x3 + w1 * m3 + w2 * e3 + w3 * s3) << 16);
  *(uint2*)&mids_out[(size_t)node * DIM + 4 * l] = o;
}

// ---------------------------------------------------------------------------
// MFMA multi-term GEMM, coefficients pre-folded into W.
// 1-D grid, XCD-swizzled: all 4 column tiles of a row band land on one XCD
// so the A panel is fetched from HBM once and L2-hit 3 times.
// ---------------------------------------------------------------------------
struct GemmDescB {
  const unsigned short* A[6];
  const unsigned short* W[6];
  const float* b[6];
  const float* c[6];
  const unsigned short* I[3];
  const float* ic[3];
  const float* resid;          // f32 x (residual stream)
  const unsigned short* addl;  // bf16 l0
  float* out_f32;              // optional f32 copy (residual stream)
  unsigned short* out_bf;
  int nmat, nid, K, relu;
};

__global__ __launch_bounds__(256) void k_gemm_mfma(GemmDescB d) {
  __shared__ __align__(16) unsigned short As[2][64][72];
  __shared__ __align__(16) unsigned short Bs[2][64][72];
  const int tid = threadIdx.x;
  // XCD swizzle: b&7 = xcd (dispatch round-robin), row = xcd + 8*(b>>5),
  // col = (b>>3)&3.  512 blocks = 128 row bands x 4 col tiles.
  const int b = blockIdx.x;
  const int bm = ((b & 7) + 8 * (b >> 5)) * 64;
  const int bn = ((b >> 3) & 3) * 64;
  const int w = tid >> 6, l = tid & 63;
  const int wm = (w >> 1) * 32, wn = (w & 1) * 32;
  const int lr = l & 15, lk = (l >> 4) * 8;
  const int ldr = tid >> 3, ldk = (tid & 7) * 8;

  const int K = d.K;
  const int kds = (K == 256) ? 2 : 1;  // log2(k-steps per term)
  const int kmask = (1 << kds) - 1;
  const int nsteps = d.nmat << kds;

  f32x4 zero = {0.f, 0.f, 0.f, 0.f};
  f32x4 acc[2][2];
  acc[0][0] = zero; acc[0][1] = zero; acc[1][0] = zero; acc[1][1] = zero;

  auto gload = [&](int s, uint4& a0, uint4& a1, uint4& b0, uint4& b1) {
    int t = s >> kds;
    int k0 = (s & kmask) << 6;
    const unsigned short* __restrict__ A = d.A[t];
    const unsigned short* __restrict__ W = d.W[t];
    a0 = *(const uint4*)&A[(size_t)(bm + ldr) * K + k0 + ldk];
    a1 = *(const uint4*)&A[(size_t)(bm + ldr + 32) * K + k0 + ldk];
    b0 = *(const uint4*)&W[(size_t)(bn + ldr) * K + k0 + ldk];
    b1 = *(const uint4*)&W[(size_t)(bn + ldr + 32) * K + k0 + ldk];
  };

  {
    uint4 a0, a1, b0, b1;
    gload(0, a0, a1, b0, b1);
    *(uint4*)&As[0][ldr][ldk] = a0;
    *(uint4*)&As[0][ldr + 32][ldk] = a1;
    *(uint4*)&Bs[0][ldr][ldk] = b0;
    *(uint4*)&Bs[0][ldr + 32][ldk] = b1;
  }
  __syncthreads();

  int buf = 0;
  for (int s = 0; s < nsteps; ++s) {
    uint4 na0, na1, nb0, nb1;
    const bool more = (s + 1 < nsteps);
    if (more) gload(s + 1, na0, na1, nb0, nb1);  // issue early; latency hides
#pragma unroll
    for (int ks = 0; ks < 2; ++ks) {
      bf16x8 a0 = *(const bf16x8*)&As[buf][wm + lr][ks * 32 + lk];
      bf16x8 a1 = *(const bf16x8*)&As[buf][wm + 16 + lr][ks * 32 + lk];
      bf16x8 b0 = *(const bf16x8*)&Bs[buf][wn + lr][ks * 32 + lk];
      bf16x8 b1 = *(const bf16x8*)&Bs[buf][wn + 16 + lr][ks * 32 + lk];
      acc[0][0] = __builtin_amdgcn_mfma_f32_16x16x32_bf16(a0, b0, acc[0][0], 0, 0, 0);
      acc[0][1] = __builtin_amdgcn_mfma_f32_16x16x32_bf16(a0, b1, acc[0][1], 0, 0, 0);
      acc[1][0] = __builtin_amdgcn_mfma_f32_16x16x32_bf16(a1, b0, acc[1][0], 0, 0, 0);
      acc[1][1] = __builtin_amdgcn_mfma_f32_16x16x32_bf16(a1, b1, acc[1][1], 0, 0, 0);
    }
    if (more) {
      *(uint4*)&As[buf ^ 1][ldr][ldk] = na0;
      *(uint4*)&As[buf ^ 1][ldr + 32][ldk] = na1;
      *(uint4*)&Bs[buf ^ 1][ldr][ldk] = nb0;
      *(uint4*)&Bs[buf ^ 1][ldr + 32][ldk] = nb1;
    }
    __syncthreads();
    buf ^= 1;
  }

  // epilogue
  float bias[2] = {0.f, 0.f};
  for (int t = 0; t < d.nmat; ++t) {
    if (d.b[t]) {
      float c = d.c[t] ? *d.c[t] : 1.0f;
      bias[0] += c * d.b[t][bn + wn + lr];
      bias[1] += c * d.b[t][bn + wn + 16 + lr];
    }
  }
  float vout[2][2][4];
#pragma unroll
  for (int m = 0; m < 2; ++m)
#pragma unroll
    for (int n = 0; n < 2; ++n)
#pragma unroll
      for (int i = 0; i < 4; ++i) vout[m][n][i] = acc[m][n][i] + bias[n];
#pragma unroll
  for (int u = 0; u < 3; ++u) {
    if (u < d.nid) {
      float icu = *d.ic[u];
      const unsigned short* __restrict__ I = d.I[u];
#pragma unroll
      for (int m = 0; m < 2; ++m)
#pragma unroll
        for (int n = 0; n < 2; ++n)
#pragma unroll
          for (int i = 0; i < 4; ++i) {
            int row = bm + wm + m * 16 + (l >> 4) * 4 + i;
            int col = bn + wn + n * 16 + lr;
            vout[m][n][i] += icu * bf2f(I[(size_t)row * DIM + col]);
          }
    }
  }
#pragma unroll
  for (int m = 0; m < 2; ++m)
#pragma unroll
    for (int n = 0; n < 2; ++n)
#pragma unroll
      for (int i = 0; i < 4; ++i) {
        int row = bm + wm + m * 16 + (l >> 4) * 4 + i;
        int col = bn + wn + n * 16 + lr;
        size_t idx = (size_t)row * DIM + col;
        float v = vout[m][n][i];
        if (d.relu) v = fmaxf(v, 0.f);
        if (d.resid) v = d.resid[idx] + 0.5f * (bf2f(d.addl[idx]) + v);
        d.out_bf[idx] = (unsigned short)f2bf(v);
        if (d.out_f32) d.out_f32[idx] = v;
      }
}

// ---------------------------------------------------------------------------
// Readout + MLP
// ---------------------------------------------------------------------------
__global__ __launch_bounds__(256) void k_readout(const float* __restrict__ x,
                                                 const int* __restrict__ gid,
                                                 float* __restrict__ hg) {
  int g = blockIdx.x, t = threadIdx.x;
  int lo = 0, hi = N_NODES;
  while (lo < hi) { int m = (lo + hi) >> 1; if (gid[m] < g) lo = m + 1; else hi = m; }
  int beg = lo;
  lo = beg; hi = N_NODES;
  while (lo < hi) { int m = (lo + hi) >> 1; if (gid[m] <= g) lo = m + 1; else hi = m; }
  int end = lo;
  float s = 0.f;
  for (int i = beg; i < end; ++i) s += x[(size_t)i * DIM + t];
  int cnt = end - beg;
  hg[g * DIM + t] = s / (float)(cnt > 1 ? cnt : 1);
}

__global__ __launch_bounds__(256) void k_mlp(const float* __restrict__ hg,
                                             const float* __restrict__ C1,
                                             const float* __restrict__ c1b,
                                             const float* __restrict__ C2,
                                             const float* __restrict__ c2b,
                                             const float* __restrict__ C3,
                                             const float* __restrict__ c3b,
                                             float* __restrict__ out) {
  int g = blockIdx.x, t = threadIdx.x;
  __shared__ float h0[256], h1[128], h2[64];
  h0[t] = hg[g * DIM + t];
  __syncthreads();
  if (t < 128) {
    float s = c1b[t];
    for (int k = 0; k < 256; ++k) s = fmaf(h0[k], C1[k * 128 + t], s);
    h1[t] = fmaxf(s, 0.f);
  }
  __syncthreads();
  if (t < 64) {
    float s = c2b[t];
    for (int k = 0; k < 128; ++k) s = fmaf(h1[k], C2[k * 64 + t], s);
    h2[t] = fmaxf(s, 0.f);
  }
  __syncthreads();
  if (t < 10) {
    float s = c3b[t];
    for (int k = 0; k < 64; ++k) s = fmaf(h2[k], C3[k * 10 + t], s);
    out[g * 10 + t] = s;
  }
}

// ---------------------------------------------------------------------------
extern "C" void kernel_launch(void* const* d_in, const int* in_sizes, int n_in,
                              void* d_out, int out_size, void* d_ws, size_t ws_size,
                              hipStream_t stream) {
  const float* h     = (const float*)d_in[0];
  const float* W_emb = (const float*)d_in[1];
  const float* b_emb = (const float*)d_in[2];
  const float* Wf_d  = (const float*)d_in[3];
  const float* bf_d  = (const float*)d_in[4];
  const float* Wf_s  = (const float*)d_in[5];
  const float* bf_s  = (const float*)d_in[6];
  const float* Wl_d  = (const float*)d_in[7];
  const float* bl_d  = (const float*)d_in[8];
  const float* Wl_s  = (const float*)d_in[9];
  const float* bl_s  = (const float*)d_in[10];
  const float* a_first = (const float*)d_in[11];
  const float* a_mid   = (const float*)d_in[12];
  const float* a_last  = (const float*)d_in[13];
  const float* C1 = (const float*)d_in[14];
  const float* c1b = (const float*)d_in[15];
  const float* C2 = (const float*)d_in[16];
  const float* c2b = (const float*)d_in[17];
  const float* C3 = (const float*)d_in[18];
  const float* c3b = (const float*)d_in[19];
  const int* src = (const int*)d_in[20];
  const int* dst = (const int*)d_in[21];
  const int* gid = (const int*)d_in[22];
  (void)in_sizes; (void)n_in; (void)out_size; (void)ws_size;

  char* p = (char*)d_ws;
  auto alloc = [&](size_t bytes) {
    void* r = (void*)p;
    p += (bytes + 255) & ~(size_t)255;
    return r;
  };
  typedef unsigned short u16;
  const size_t NBF = (size_t)M_PAD * DIM * sizeof(u16);  // 4.19 MB (padded)
  float* x_f32 = (float*)alloc((size_t)M_PAD * DIM * sizeof(float));
  u16* xb    = (u16*)alloc(NBF);
  u16* s1b   = (u16*)alloc(NBF);
  u16* s2b   = (u16*)alloc(NBF);
  u16* m0b   = (u16*)alloc(NBF);
  u16* m1b   = (u16*)alloc(NBF);
  u16* l0b   = (u16*)alloc(NBF);
  u16* aggAb = (u16*)alloc(NBF);
  u16* aggBb = (u16*)alloc(NBF);
  u16* h_bf  = (u16*)alloc((size_t)M_PAD * IN_DIM * sizeof(u16));
  // transposed bf16 weights (coef-prescaled): W_emb^T, Wf_d(6), Wf_s(6), Wl_d(10), Wl_s(10)
  u16* WT    = (u16*)alloc((size_t)(DIM * IN_DIM + 32 * DIM * DIM) * sizeof(u16));
  u16* WTe   = WT;
  u16* WTfd  = WT + DIM * IN_DIM;
  u16* WTfs  = WTfd + 6 * DIM * DIM;
  u16* WTld  = WTfs + 6 * DIM * DIM;
  u16* WTls  = WTld + 10 * DIM * DIM;
  float* invdeg = (float*)alloc(N_NODES * sizeof(float));
  int* counts  = (int*)alloc(N_NODES * sizeof(int));
  int* row_ofs = (int*)alloc((N_NODES + 1) * sizeof(int));
  int* cursor  = (int*)alloc(N_NODES * sizeof(int));
  int* csr_src = (int*)alloc(N_EDGES * sizeof(int));
  float* wsoft = (float*)alloc(80 * sizeof(float));
  float* hg    = (float*)alloc(N_GRAPHS * DIM * sizeof(float));

  const int EB = (N_EDGES + 255) / 256;
  const int PADR = M_PAD - N_NODES;  // 192 pad rows

  hipMemsetAsync(counts, 0, N_NODES * sizeof(int), stream);
  // zero pad rows of buffers that are read as GEMM A but only written for
  // rows < N_NODES by seg kernels (or input conversion):
  hipMemsetAsync(h_bf + (size_t)N_NODES * IN_DIM, 0, (size_t)PADR * IN_DIM * sizeof(u16), stream);
  hipMemsetAsync(aggAb + (size_t)N_NODES * DIM, 0, (size_t)PADR * DIM * sizeof(u16), stream);
  hipMemsetAsync(aggBb + (size_t)N_NODES * DIM, 0, (size_t)PADR * DIM * sizeof(u16), stream);
  hipMemsetAsync(m0b + (size_t)N_NODES * DIM, 0, (size_t)PADR * DIM * sizeof(u16), stream);
  hipMemsetAsync(m1b + (size_t)N_NODES * DIM, 0, (size_t)PADR * DIM * sizeof(u16), stream);

  k_count<<<EB, 256, 0, stream>>>(dst, counts);
  k_scan<<<1, 256, 0, stream>>>(counts, row_ofs, cursor, invdeg);
  k_fill<<<EB, 256, 0, stream>>>(src, dst, cursor, csr_src);
  k_softmax<<<1, 64, 0, stream>>>(a_first, a_mid, a_last, wsoft);

  const float* wf = wsoft;
  const float* wm = wsoft + 24;
  const float* wl = wsoft + 40;

  // conversions (W prescaled by its mixture coefficient: dense w[2], sparse w[3])
  k_cvt_bf16<<<(N_NODES * IN_DIM + 255) / 256, 256, 0, stream>>>(h, h_bf, N_NODES * IN_DIM);
  k_transpose_cvt<<<dim3(IN_DIM / 32, DIM / 32, 1), 256, 0, stream>>>(W_emb, WTe, IN_DIM, DIM);
  k_transpose_cvt32<<<dim3(8, 8, 32), 256, 0, stream>>>(Wf_d, Wf_s, Wl_d, Wl_s, wsoft, WTfd);

  const int GG = (M_PAD / 64) * (DIM / 64);  // 512 blocks, 1-D swizzled
  const int SB = (N_NODES + 3) / 4;

  // embedding: x = h @ W_emb + b_emb   (f32 + bf16 outputs)
  {
    GemmDescB d{};
    d.A[0] = h_bf; d.W[0] = WTe; d.b[0] = b_emb; d.c[0] = nullptr;
    d.nmat = 1; d.nid = 0; d.K = IN_DIM; d.relu = 0;
    d.out_f32 = x_f32; d.out_bf = xb;
    k_gemm_mfma<<<GG, 256, 0, stream>>>(d);
  }

  for (int l = 0; l < 2; ++l) {
    auto WFD = [&](int e) { return WTfd + (size_t)(l * 3 + e) * DIM * DIM; };
    auto BFD = [&](int e) { return bf_d + (size_t)(l * 3 + e) * DIM; };
    auto WFS = [&](int e) { return WTfs + (size_t)(l * 3 + e) * DIM * DIM; };
    auto BFS = [&](int e) { return bf_s + (size_t)(l * 3 + e) * DIM; };
    auto WLD = [&](int e) { return WTld + (size_t)(l * 5 + e) * DIM * DIM; };
    auto BLD = [&](int e) { return bl_d + (size_t)(l * 5 + e) * DIM; };
    auto WLS = [&](int e) { return WTls + (size_t)(l * 5 + e) * DIM * DIM; };
    auto BLS = [&](int e) { return bl_s + (size_t)(l * 5 + e) * DIM; };
    auto WFrow = [&](int e) { return wf + (l * 3 + e) * 4; };
    auto WMrow = [&](int n) { return wm + (l * 2 + n) * 4; };
    auto WLrow = [&](int e) { return wl + (l * 5 + e) * 4; };

    auto edge = [&](GemmDescB& d, const u16* X, const u16* AG,
                    const u16* Wd, const float* bd,
                    const u16* Ws, const float* bs, const float* wrow) {
      d.A[d.nmat] = X;  d.W[d.nmat] = Wd; d.b[d.nmat] = bd; d.c[d.nmat] = wrow + 2; d.nmat++;
      d.A[d.nmat] = AG; d.W[d.nmat] = Ws; d.b[d.nmat] = bs; d.c[d.nmat] = wrow + 3; d.nmat++;
      d.I[d.nid] = X; d.ic[d.nid] = wrow + 1; d.nid++;
    };

    // aggA = mean-agg(x)
    k_segmean_bf<<<SB, 256, 0, stream>>>(xb, row_ofs, csr_src, invdeg, aggAb);

    // s1 = relu(mixed(x, e0))
    {
      GemmDescB d{}; d.K = DIM; d.relu = 1; d.out_bf = s1b;
      edge(d, xb, aggAb, WFD(0), BFD(0), WFS(0), BFS(0), WFrow(0));
      k_gemm_mfma<<<GG, 256, 0, stream>>>(d);
    }

    // mid of s1: mean -> aggB (DAG agg of states[1]); mixture -> mids0
    k_segmid_bf<<<SB, 256, 0, stream>>>(s1b, row_ofs, csr_src, invdeg, WMrow(0), aggBb, m0b);

    // s2 = relu(mixed(x, e1) + mixed(s1, e2))
    {
      GemmDescB d{}; d.K = DIM; d.relu = 1; d.out_bf = s2b;
      edge(d, xb,  aggAb, WFD(1), BFD(1), WFS(1), BFS(1), WFrow(1));
      edge(d, s1b, aggBb, WFD(2), BFD(2), WFS(2), BFS(2), WFrow(2));
      k_gemm_mfma<<<GG, 256, 0, stream>>>(d);
    }

    // mid of s2 -> mids1
    k_segmid_bf<<<SB, 256, 0, stream>>>(s2b, row_ofs, csr_src, invdeg, WMrow(1), nullptr, m1b);

    // mean-aggs of mids0, mids1
    k_segmean2_bf<<<SB, 256, 0, stream>>>(m0b, m1b, row_ofs, csr_src, invdeg, aggAb, aggBb);

    // l0 = relu(mixed(mids0,e0) + mixed(mids1,e1))
    {
      GemmDescB d{}; d.K = DIM; d.relu = 1; d.out_bf = l0b;
      edge(d, m0b, aggAb, WLD(0), BLD(0), WLS(0), BLS(0), WLrow(0));
      edge(d, m1b, aggBb, WLD(1), BLD(1), WLS(1), BLS(1), WLrow(1));
      k_gemm_mfma<<<GG, 256, 0, stream>>>(d);
    }

    // mean-agg of l0 -> s1b (dead)
    k_segmean_bf<<<SB, 256, 0, stream>>>(l0b, row_ofs, csr_src, invdeg, s1b);

    // x = x + 0.5*(l0 + relu(mixed(mids0,e2)+mixed(mids1,e3)+mixed(l0,e4)))
    {
      GemmDescB d{}; d.K = DIM; d.relu = 1;
      edge(d, m0b, aggAb, WLD(2), BLD(2), WLS(2), BLS(2), WLrow(2));
      edge(d, m1b, aggBb, WLD(3), BLD(3), WLS(3), BLS(3), WLrow(3));
      edge(d, l0b, s1b,   WLD(4), BLD(4), WLS(4), BLS(4), WLrow(4));
      d.resid = x_f32; d.addl = l0b;
      d.out_f32 = x_f32; d.out_bf = xb;
      k_gemm_mfma<<<GG, 256, 0, stream>>>(d);
    }
  }

  k_readout<<<N_GRAPHS, 256, 0, stream>>>(x_f32, gid, hg);
  k_mlp<<<N_GRAPHS, 256, 0, stream>>>(hg, C1, c1b, C2, c2b, C3, c3b, (float*)d_out);
}

// Round 6
// 359.711 us; speedup vs baseline: 2.9137x; 1.0045x over previous
//
#include <hip/hip_runtime.h>

#define N_NODES   8000
#define M_PAD     8192
#define PADR      (M_PAD - N_NODES)
#define N_EDGES   128000
#define N_GRAPHS  64
#define DIM       256
#define IN_DIM    128

typedef short bf16x8 __attribute__((ext_vector_type(8)));
typedef float f32x4 __attribute__((ext_vector_type(4)));

static __device__ __forceinline__ float bf2f(unsigned v) {
  return __uint_as_float(v << 16);
}
static __device__ __forceinline__ unsigned f2bf(float f) {
  unsigned u = __float_as_uint(f);
  return (u + 0x7fffu + ((u >> 16) & 1u)) >> 16;
}

// ---------------------------------------------------------------------------
// init: zero counts + pad rows (replaces 6 hipMemsetAsync dispatches)
// ---------------------------------------------------------------------------
__global__ __launch_bounds__(256) void k_init(int* __restrict__ counts,
                                              unsigned short* __restrict__ hpad,
                                              unsigned short* __restrict__ p0,
                                              unsigned short* __restrict__ p1,
                                              unsigned short* __restrict__ p2,
                                              unsigned short* __restrict__ p3) {
  int i = blockIdx.x * 256 + threadIdx.x;
  if (i < N_NODES) counts[i] = 0;
  if (i < PADR * IN_DIM) hpad[i] = 0;
  if (i < PADR * DIM) { p0[i] = 0; p1[i] = 0; p2[i] = 0; p3[i] = 0; }
}

// ---------------------------------------------------------------------------
// CSR build
// ---------------------------------------------------------------------------
__global__ __launch_bounds__(256) void k_count(const int* __restrict__ dst,
                                               int* __restrict__ counts) {
  int e = blockIdx.x * 256 + threadIdx.x;
  if (e < N_EDGES) atomicAdd(&counts[dst[e]], 1);
}

__global__ __launch_bounds__(256) void k_scan(const int* __restrict__ counts,
                                              int* __restrict__ row_ofs,
                                              int* __restrict__ cursor,
                                              float* __restrict__ invdeg) {
  __shared__ int chunk[256];
  const int per = (N_NODES + 255) / 256;  // 32
  int t = threadIdx.x;
  int base = t * per;
  int s = 0;
  for (int i = 0; i < per; ++i) {
    int idx = base + i;
    if (idx < N_NODES) s += counts[idx];
  }
  chunk[t] = s;
  __syncthreads();
  for (int off = 1; off < 256; off <<= 1) {
    int v = 0;
    if (t >= off) v = chunk[t - off];
    __syncthreads();
    if (t >= off) chunk[t] += v;
    __syncthreads();
  }
  int run = (t > 0) ? chunk[t - 1] : 0;
  for (int i = 0; i < per; ++i) {
    int idx = base + i;
    if (idx < N_NODES) {
      row_ofs[idx] = run;
      cursor[idx] = run;
      int c = counts[idx];
      invdeg[idx] = 1.0f / (float)(c > 1 ? c : 1);
      run += c;
    }
  }
  if (t == 0) row_ofs[N_NODES] = chunk[255];
}

__global__ __launch_bounds__(256) void k_fill(const int* __restrict__ src,
                                              const int* __restrict__ dst,
                                              int* __restrict__ cursor,
                                              int* __restrict__ csr_src) {
  int e = blockIdx.x * 256 + threadIdx.x;
  if (e < N_EDGES) {
    int p = atomicAdd(&cursor[dst[e]], 1);
    csr_src[p] = src[e];
  }
}

// ---------------------------------------------------------------------------
// Softmax over architecture rows; wsoft: [0..23]=wf, [24..39]=wm, [40..79]=wl
// ---------------------------------------------------------------------------
__global__ __launch_bounds__(64) void k_softmax(const float* __restrict__ af,
                                                const float* __restrict__ am,
                                                const float* __restrict__ al,
                                                float* __restrict__ w) {
  int t = threadIdx.x;
  const float* sp;
  float* dp;
  if (t < 6)       { sp = af + t * 4;        dp = w + t * 4; }
  else if (t < 10) { sp = am + (t - 6) * 4;  dp = w + 24 + (t - 6) * 4; }
  else if (t < 20) { sp = al + (t - 10) * 4; dp = w + 40 + (t - 10) * 4; }
  else return;
  float a0 = sp[0], a1 = sp[1], a2 = sp[2], a3 = sp[3];
  float m = fmaxf(fmaxf(a0, a1), fmaxf(a2, a3));
  float e0 = expf(a0 - m), e1 = expf(a1 - m), e2 = expf(a2 - m), e3 = expf(a3 - m);
  float si = 1.0f / (e0 + e1 + e2 + e3);
  dp[0] = e0 * si; dp[1] = e1 * si; dp[2] = e2 * si; dp[3] = e3 * si;
}

// ---------------------------------------------------------------------------
// Conversions
// ---------------------------------------------------------------------------
__global__ __launch_bounds__(256) void k_cvt_bf16(const float* __restrict__ in,
                                                  unsigned short* __restrict__ out,
                                                  int n) {
  int i = blockIdx.x * 256 + threadIdx.x;
  if (i < n) out[i] = (unsigned short)f2bf(in[i]);
}

// W_emb^T only (K=IN_DIM)
__global__ __launch_bounds__(256) void k_transpose_cvt(const float* __restrict__ in,
                                                       unsigned short* __restrict__ out,
                                                       int K, int N) {
  __shared__ float tile[32][33];
  int k0 = blockIdx.x * 32, n0 = blockIdx.y * 32;
  int tx = threadIdx.x & 31, ty = threadIdx.x >> 5;  // 32 x 8
#pragma unroll
  for (int i = 0; i < 4; ++i)
    tile[ty + 8 * i][tx] = in[(size_t)(k0 + ty + 8 * i) * N + n0 + tx];
  __syncthreads();
#pragma unroll
  for (int i = 0; i < 4; ++i)
    out[(size_t)(n0 + ty + 8 * i) * K + k0 + tx] =
        (unsigned short)f2bf(tile[tx][ty + 8 * i]);
}

// all 32 DIMxDIM cell weights in one launch, coef-prescaled.
__global__ __launch_bounds__(256) void k_transpose_cvt32(const float* __restrict__ Wfd,
                                                         const float* __restrict__ Wfs,
                                                         const float* __restrict__ Wld,
                                                         const float* __restrict__ Wls,
                                                         const float* __restrict__ wsoft,
                                                         unsigned short* __restrict__ out) {
  __shared__ float tile[32][33];
  int z = blockIdx.z;
  const float* in;
  float coef;
  const float* wf = wsoft;
  const float* wl = wsoft + 40;
  if (z < 6)       { in = Wfd + (size_t)z * DIM * DIM;        coef = wf[z * 4 + 2]; }
  else if (z < 12) { in = Wfs + (size_t)(z - 6) * DIM * DIM;  coef = wf[(z - 6) * 4 + 3]; }
  else if (z < 22) { in = Wld + (size_t)(z - 12) * DIM * DIM; coef = wl[(z - 12) * 4 + 2]; }
  else             { in = Wls + (size_t)(z - 22) * DIM * DIM; coef = wl[(z - 22) * 4 + 3]; }
  unsigned short* o = out + (size_t)z * DIM * DIM;
  int k0 = blockIdx.x * 32, n0 = blockIdx.y * 32;
  int tx = threadIdx.x & 31, ty = threadIdx.x >> 5;
#pragma unroll
  for (int i = 0; i < 4; ++i)
    tile[ty + 8 * i][tx] = in[(size_t)(k0 + ty + 8 * i) * DIM + n0 + tx];
  __syncthreads();
#pragma unroll
  for (int i = 0; i < 4; ++i)
    o[(size_t)(n0 + ty + 8 * i) * DIM + k0 + tx] =
        (unsigned short)f2bf(coef * tile[tx][ty + 8 * i]);
}

// ---------------------------------------------------------------------------
// Segment reductions (bf16). One wave per node, 4 nodes/block, 4-edge unroll.
// ---------------------------------------------------------------------------
#define SEG_ACC(u) \
  { s0 += bf2f((u).x & 0xffffu); s1 += bf2f((u).x >> 16); \
    s2 += bf2f((u).y & 0xffffu); s3 += bf2f((u).y >> 16); }

__global__ __launch_bounds__(256) void k_segmean_bf(const unsigned short* __restrict__ X,
                                                    const int* __restrict__ row_ofs,
                                                    const int* __restrict__ csr_src,
                                                    const float* __restrict__ invdeg,
                                                    unsigned short* __restrict__ out) {
  int node = blockIdx.x * 4 + (threadIdx.x >> 6);
  int l = threadIdx.x & 63;
  if (node >= N_NODES) return;
  int beg = row_ofs[node], end = row_ofs[node + 1];
  float s0 = 0.f, s1 = 0.f, s2 = 0.f, s3 = 0.f;
  int e = beg;
  for (; e + 4 <= end; e += 4) {
    int i0 = csr_src[e], i1 = csr_src[e + 1], i2 = csr_src[e + 2], i3 = csr_src[e + 3];
    uint2 u0 = *(const uint2*)&X[(size_t)i0 * DIM + 4 * l];
    uint2 u1 = *(const uint2*)&X[(size_t)i1 * DIM + 4 * l];
    uint2 u2 = *(const uint2*)&X[(size_t)i2 * DIM + 4 * l];
    uint2 u3 = *(const uint2*)&X[(size_t)i3 * DIM + 4 * l];
    SEG_ACC(u0) SEG_ACC(u1) SEG_ACC(u2) SEG_ACC(u3)
  }
  for (; e < end; ++e) {
    uint2 u = *(const uint2*)&X[(size_t)csr_src[e] * DIM + 4 * l];
    SEG_ACC(u)
  }
  float iv = invdeg[node];
  uint2 o;
  o.x = f2bf(s0 * iv) | (f2bf(s1 * iv) << 16);
  o.y = f2bf(s2 * iv) | (f2bf(s3 * iv) << 16);
  *(uint2*)&out[(size_t)node * DIM + 4 * l] = o;
}

__global__ __launch_bounds__(256) void k_segmean2_bf(const unsigned short* __restrict__ X0,
                                                     const unsigned short* __restrict__ X1,
                                                     const int* __restrict__ row_ofs,
                                                     const int* __restrict__ csr_src,
                                                     const float* __restrict__ invdeg,
                                                     unsigned short* __restrict__ out0,
                                                     unsigned short* __restrict__ out1) {
  int node = blockIdx.x * 4 + (threadIdx.x >> 6);
  int l = threadIdx.x & 63;
  if (node >= N_NODES) return;
  int beg = row_ofs[node], end = row_ofs[node + 1];
  float a0 = 0.f, a1 = 0.f, a2 = 0.f, a3 = 0.f;
  float b0 = 0.f, b1 = 0.f, b2 = 0.f, b3 = 0.f;
  int e = beg;
  for (; e + 2 <= end; e += 2) {
    size_t r0 = (size_t)csr_src[e] * DIM + 4 * l;
    size_t r1 = (size_t)csr_src[e + 1] * DIM + 4 * l;
    uint2 u0 = *(const uint2*)&X0[r0];
    uint2 v0 = *(const uint2*)&X1[r0];
    uint2 u1 = *(const uint2*)&X0[r1];
    uint2 v1 = *(const uint2*)&X1[r1];
    a0 += bf2f(u0.x & 0xffffu) + bf2f(u1.x & 0xffffu);
    a1 += bf2f(u0.x >> 16) + bf2f(u1.x >> 16);
    a2 += bf2f(u0.y & 0xffffu) + bf2f(u1.y & 0xffffu);
    a3 += bf2f(u0.y >> 16) + bf2f(u1.y >> 16);
    b0 += bf2f(v0.x & 0xffffu) + bf2f(v1.x & 0xffffu);
    b1 += bf2f(v0.x >> 16) + bf2f(v1.x >> 16);
    b2 += bf2f(v0.y & 0xffffu) + bf2f(v1.y & 0xffffu);
    b3 += bf2f(v0.y >> 16) + bf2f(v1.y >> 16);
  }
  for (; e < end; ++e) {
    size_t rb = (size_t)csr_src[e] * DIM + 4 * l;
    uint2 u = *(const uint2*)&X0[rb];
    uint2 v = *(const uint2*)&X1[rb];
    a0 += bf2f(u.x & 0xffffu); a1 += bf2f(u.x >> 16);
    a2 += bf2f(u.y & 0xffffu); a3 += bf2f(u.y >> 16);
    b0 += bf2f(v.x & 0xffffu); b1 += bf2f(v.x >> 16);
    b2 += bf2f(v.y & 0xffffu); b3 += bf2f(v.y >> 16);
  }
  float iv = invdeg[node];
  uint2 o;
  o.x = f2bf(a0 * iv) | (f2bf(a1 * iv) << 16);
  o.y = f2bf(a2 * iv) | (f2bf(a3 * iv) << 16);
  *(uint2*)&out0[(size_t)node * DIM + 4 * l] = o;
  o.x = f2bf(b0 * iv) | (f2bf(b1 * iv) << 16);
  o.y = f2bf(b2 * iv) | (f2bf(b3 * iv) << 16);
  *(uint2*)&out1[(size_t)node * DIM + 4 * l] = o;
}

// sum+max over incoming msgs of relu'd input; epilogue = middle-stage mixture.
__global__ __launch_bounds__(256) void k_segmid_bf(const unsigned short* __restrict__ Xn,
                                                   const int* __restrict__ row_ofs,
                                                   const int* __restrict__ csr_src,
                                                   const float* __restrict__ invdeg,
                                                   const float* __restrict__ wrow,
                                                   unsigned short* __restrict__ mean_out,
                                                   unsigned short* __restrict__ mids_out) {
  int node = blockIdx.x * 4 + (threadIdx.x >> 6);
  int l = threadIdx.x & 63;
  if (node >= N_NODES) return;
  int beg = row_ofs[node], end = row_ofs[node + 1];
  float s0 = 0.f, s1 = 0.f, s2 = 0.f, s3 = 0.f;
  float m0 = 0.f, m1 = 0.f, m2 = 0.f, m3 = 0.f;  // inputs >= 0 (relu)
  int e = beg;
  for (; e + 4 <= end; e += 4) {
    int i0 = csr_src[e], i1 = csr_src[e + 1], i2 = csr_src[e + 2], i3 = csr_src[e + 3];
    uint2 u0 = *(const uint2*)&Xn[(size_t)i0 * DIM + 4 * l];
    uint2 u1 = *(const uint2*)&Xn[(size_t)i1 * DIM + 4 * l];
    uint2 u2 = *(const uint2*)&Xn[(size_t)i2 * DIM + 4 * l];
    uint2 u3 = *(const uint2*)&Xn[(size_t)i3 * DIM + 4 * l];
#pragma unroll
    for (int j = 0; j < 4; ++j) {
      uint2 u = (j == 0) ? u0 : (j == 1) ? u1 : (j == 2) ? u2 : u3;
      float v0 = bf2f(u.x & 0xffffu), v1 = bf2f(u.x >> 16);
      float v2 = bf2f(u.y & 0xffffu), v3 = bf2f(u.y >> 16);
      s0 += v0; s1 += v1; s2 += v2; s3 += v3;
      m0 = fmaxf(m0, v0); m1 = fmaxf(m1, v1);
      m2 = fmaxf(m2, v2); m3 = fmaxf(m3, v3);
    }
  }
  for (; e < end; ++e) {
    uint2 u = *(const uint2*)&Xn[(size_t)csr_src[e] * DIM + 4 * l];
    float v0 = bf2f(u.x & 0xffffu), v1 = bf2f(u.x >> 16);
    float v2 = bf2f(u.y & 0xffffu), v3 = bf2f(u.y >> 16);
    s0 += v0; s1 += v1; s2 += v2; s3 += v3;
    m0 = fmaxf(m0, v0); m1 = fmaxf(m1, v1);
    m2 = fmaxf(m2, v2); m3 = fmaxf(m3, v3);
  }
  float iv = invdeg[node];
  float e0 = s0 * iv, e1 = s1 * iv, e2 = s2 * iv, e3 = s3 * iv;
  if (mean_out) {
    uint2 o;
    o.x = f2bf(e0) | (f2bf(e1) << 16);
    o.y = f2bf(e2) | (f2bf(e3) << 16);
    *(uint2*)&mean_out[(size_t)node * DIM + 4 * l] = o;
  }
  float w0 = wrow[0], w1 = wrow[1], w2 = wrow[2], w3 = wrow[3];
  uint2 xu = *(const uint2*)&Xn[(size_t)node * DIM + 4 * l];
  float x0 = bf2f(xu.x & 0xffffu), x1 = bf2f(xu.x >> 16);
  float x2 = bf2f(xu.y & 0xffffu), x3 = bf2f(xu.y >> 16);
  uint2 o;
  o.x = f2bf(w0 * x0 + w1 * m0 + w2 * e0 + w3 * s0) |
        (f2bf(w0 * x1 + w1 * m1 + w2 * e1 + w3 * s1) << 16);
  o.y = f2bf(w0 * x2 + w1 * m2 + w2 * e2 + w3 * s2) |
        (f2bf(w0 * x3 + w1 * m3 + w2 * e3 + w3 * s3) << 16);
  *(uint2*)&mids_out[(size_t)node * DIM + 4 * l] = o;
}

// ---------------------------------------------------------------------------
// Wide MFMA multi-term GEMM with per-column-half epilogues (N = 256*nhalves).
// Per half h:
//   v = sum_t A_t @ W[h][t]  + sum_t c[h][t]*b[h][t] + sum_u ic[h][u]*I[u]
//   if (pre[h])  v += pre[h]               (f32)
//   if (relu[h]) v = max(v,0)
//   if (resid[h]) v = resid[h] + 0.5*(addl[h] + v)
//   write out_bf[h] / out_f32[h]
// colshift: 2 -> 512 blocks (N=256), 3 -> 1024 blocks (N=512).
// XCD swizzle keeps all col tiles of a row band on one XCD (A L2 reuse).
// ---------------------------------------------------------------------------
struct GemmDescW {
  const unsigned short* A[4];
  const unsigned short* W[2][4];
  const float* b[2][4];
  const float* c[2][4];
  const unsigned short* I[2];
  const float* ic[2][2];
  const float* pre[2];
  const float* resid[2];
  const unsigned short* addl[2];
  float* out_f32[2];
  unsigned short* out_bf[2];
  int nmat, nid, K, relu[2], colshift;
};

__global__ __launch_bounds__(256) void k_gemm_mfma(GemmDescW d) {
  __shared__ __align__(16) unsigned short As[2][64][72];
  __shared__ __align__(16) unsigned short Bs[2][64][72];
  const int tid = threadIdx.x;
  const int b = blockIdx.x;
  const int cs = d.colshift;
  const int c = (b >> 3) & ((1 << cs) - 1);
  const int bm = ((b & 7) + 8 * (b >> (3 + cs))) * 64;
  const int half = c >> 2;          // 0 for cols 0-3, 1 for cols 4-7
  const int bn = (c & 3) * 64;      // local col within the DIM=256 output
  const int w = tid >> 6, l = tid & 63;
  const int wm = (w >> 1) * 32, wn = (w & 1) * 32;
  const int lr = l & 15, lk = (l >> 4) * 8;
  const int ldr = tid >> 3, ldk = (tid & 7) * 8;

  const int K = d.K;
  const int kds = (K == 256) ? 2 : 1;
  const int kmask = (1 << kds) - 1;
  const int nsteps = d.nmat << kds;

  f32x4 zero = {0.f, 0.f, 0.f, 0.f};
  f32x4 acc[2][2];
  acc[0][0] = zero; acc[0][1] = zero; acc[1][0] = zero; acc[1][1] = zero;

  auto gload = [&](int s, uint4& a0, uint4& a1, uint4& b0, uint4& b1) {
    int t = s >> kds;
    int k0 = (s & kmask) << 6;
    const unsigned short* __restrict__ A = d.A[t];
    const unsigned short* __restrict__ W = d.W[half][t];
    a0 = *(const uint4*)&A[(size_t)(bm + ldr) * K + k0 + ldk];
    a1 = *(const uint4*)&A[(size_t)(bm + ldr + 32) * K + k0 + ldk];
    b0 = *(const uint4*)&W[(size_t)(bn + ldr) * K + k0 + ldk];
    b1 = *(const uint4*)&W[(size_t)(bn + ldr + 32) * K + k0 + ldk];
  };

  {
    uint4 a0, a1, b0, b1;
    gload(0, a0, a1, b0, b1);
    *(uint4*)&As[0][ldr][ldk] = a0;
    *(uint4*)&As[0][ldr + 32][ldk] = a1;
    *(uint4*)&Bs[0][ldr][ldk] = b0;
    *(uint4*)&Bs[0][ldr + 32][ldk] = b1;
  }
  __syncthreads();

  int buf = 0;
  for (int s = 0; s < nsteps; ++s) {
    uint4 na0, na1, nb0, nb1;
    const bool more = (s + 1 < nsteps);
    if (more) gload(s + 1, na0, na1, nb0, nb1);  // issue early; latency hides
#pragma unroll
    for (int ks = 0; ks < 2; ++ks) {
      bf16x8 a0 = *(const bf16x8*)&As[buf][wm + lr][ks * 32 + lk];
      bf16x8 a1 = *(const bf16x8*)&As[buf][wm + 16 + lr][ks * 32 + lk];
      bf16x8 b0 = *(const bf16x8*)&Bs[buf][wn + lr][ks * 32 + lk];
      bf16x8 b1 = *(const bf16x8*)&Bs[buf][wn + 16 + lr][ks * 32 + lk];
      acc[0][0] = __builtin_amdgcn_mfma_f32_16x16x32_bf16(a0, b0, acc[0][0], 0, 0, 0);
      acc[0][1] = __builtin_amdgcn_mfma_f32_16x16x32_bf16(a0, b1, acc[0][1], 0, 0, 0);
      acc[1][0] = __builtin_amdgcn_mfma_f32_16x16x32_bf16(a1, b0, acc[1][0], 0, 0, 0);
      acc[1][1] = __builtin_amdgcn_mfma_f32_16x16x32_bf16(a1, b1, acc[1][1], 0, 0, 0);
    }
    if (more) {
      *(uint4*)&As[buf ^ 1][ldr][ldk] = na0;
      *(uint4*)&As[buf ^ 1][ldr + 32][ldk] = na1;
      *(uint4*)&Bs[buf ^ 1][ldr][ldk] = nb0;
      *(uint4*)&Bs[buf ^ 1][ldr + 32][ldk] = nb1;
    }
    __syncthreads();
    buf ^= 1;
  }

  // epilogue (per half)
  float bias[2] = {0.f, 0.f};
  for (int t = 0; t < d.nmat; ++t) {
    const float* bp = d.b[half][t];
    if (bp) {
      float cc = d.c[half][t] ? *d.c[half][t] : 1.0f;
      bias[0] += cc * bp[bn + wn + lr];
      bias[1] += cc * bp[bn + wn + 16 + lr];
    }
  }
  float vout[2][2][4];
#pragma unroll
  for (int m = 0; m < 2; ++m)
#pragma unroll
    for (int n = 0; n < 2; ++n)
#pragma unroll
      for (int i = 0; i < 4; ++i) vout[m][n][i] = acc[m][n][i] + bias[n];
#pragma unroll
  for (int u = 0; u < 2; ++u) {
    if (u < d.nid) {
      float icu = *d.ic[half][u];
      const unsigned short* __restrict__ I = d.I[u];
#pragma unroll
      for (int m = 0; m < 2; ++m)
#pragma unroll
        for (int n = 0; n < 2; ++n)
#pragma unroll
          for (int i = 0; i < 4; ++i) {
            int row = bm + wm + m * 16 + (l >> 4) * 4 + i;
            int col = bn + wn + n * 16 + lr;
            vout[m][n][i] += icu * bf2f(I[(size_t)row * DIM + col]);
          }
    }
  }
  const float* pre = d.pre[half];
  const float* resid = d.resid[half];
  const unsigned short* addl = d.addl[half];
  unsigned short* obf = d.out_bf[half];
  float* of32 = d.out_f32[half];
  const int do_relu = d.relu[half];
#pragma unroll
  for (int m = 0; m < 2; ++m)
#pragma unroll
    for (int n = 0; n < 2; ++n)
#pragma unroll
      for (int i = 0; i < 4; ++i) {
        int row = bm + wm + m * 16 + (l >> 4) * 4 + i;
        int col = bn + wn + n * 16 + lr;
        size_t idx = (size_t)row * DIM + col;
        float v = vout[m][n][i];
        if (pre) v += pre[idx];
        if (do_relu) v = fmaxf(v, 0.f);
        if (resid) v = resid[idx] + 0.5f * (bf2f(addl[idx]) + v);
        if (obf) obf[idx] = (unsigned short)f2bf(v);
        if (of32) of32[idx] = v;
      }
}

// ---------------------------------------------------------------------------
// Readout + MLP
// ---------------------------------------------------------------------------
__global__ __launch_bounds__(256) void k_readout(const float* __restrict__ x,
                                                 const int* __restrict__ gid,
                                                 float* __restrict__ hg) {
  int g = blockIdx.x, t = threadIdx.x;
  int lo = 0, hi = N_NODES;
  while (lo < hi) { int m = (lo + hi) >> 1; if (gid[m] < g) lo = m + 1; else hi = m; }
  int beg = lo;
  lo = beg; hi = N_NODES;
  while (lo < hi) { int m = (lo + hi) >> 1; if (gid[m] <= g) lo = m + 1; else hi = m; }
  int end = lo;
  float s = 0.f;
  for (int i = beg; i < end; ++i) s += x[(size_t)i * DIM + t];
  int cnt = end - beg;
  hg[g * DIM + t] = s / (float)(cnt > 1 ? cnt : 1);
}

__global__ __launch_bounds__(256) void k_mlp(const float* __restrict__ hg,
                                             const float* __restrict__ C1,
                                             const float* __restrict__ c1b,
                                             const float* __restrict__ C2,
                                             const float* __restrict__ c2b,
                                             const float* __restrict__ C3,
                                             const float* __restrict__ c3b,
                                             float* __restrict__ out) {
  int g = blockIdx.x, t = threadIdx.x;
  __shared__ float h0[256], h1[128], h2[64];
  h0[t] = hg[g * DIM + t];
  __syncthreads();
  if (t < 128) {
    float s = c1b[t];
    for (int k = 0; k < 256; ++k) s = fmaf(h0[k], C1[k * 128 + t], s);
    h1[t] = fmaxf(s, 0.f);
  }
  __syncthreads();
  if (t < 64) {
    float s = c2b[t];
    for (int k = 0; k < 128; ++k) s = fmaf(h1[k], C2[k * 64 + t], s);
    h2[t] = fmaxf(s, 0.f);
  }
  __syncthreads();
  if (t < 10) {
    float s = c3b[t];
    for (int k = 0; k < 64; ++k) s = fmaf(h2[k], C3[k * 10 + t], s);
    out[g * 10 + t] = s;
  }
}

// ---------------------------------------------------------------------------
extern "C" void kernel_launch(void* const* d_in, const int* in_sizes, int n_in,
                              void* d_out, int out_size, void* d_ws, size_t ws_size,
                              hipStream_t stream) {
  const float* h     = (const float*)d_in[0];
  const float* W_emb = (const float*)d_in[1];
  const float* b_emb = (const float*)d_in[2];
  const float* Wf_d  = (const float*)d_in[3];
  const float* bf_d  = (const float*)d_in[4];
  const float* Wf_s  = (const float*)d_in[5];
  const float* bf_s  = (const float*)d_in[6];
  const float* Wl_d  = (const float*)d_in[7];
  const float* bl_d  = (const float*)d_in[8];
  const float* Wl_s  = (const float*)d_in[9];
  const float* bl_s  = (const float*)d_in[10];
  const float* a_first = (const float*)d_in[11];
  const float* a_mid   = (const float*)d_in[12];
  const float* a_last  = (const float*)d_in[13];
  const float* C1 = (const float*)d_in[14];
  const float* c1b = (const float*)d_in[15];
  const float* C2 = (const float*)d_in[16];
  const float* c2b = (const float*)d_in[17];
  const float* C3 = (const float*)d_in[18];
  const float* c3b = (const float*)d_in[19];
  const int* src = (const int*)d_in[20];
  const int* dst = (const int*)d_in[21];
  const int* gid = (const int*)d_in[22];
  (void)in_sizes; (void)n_in; (void)out_size; (void)ws_size;

  char* p = (char*)d_ws;
  auto alloc = [&](size_t bytes) {
    void* r = (void*)p;
    p += (bytes + 255) & ~(size_t)255;
    return r;
  };
  typedef unsigned short u16;
  const size_t NBF = (size_t)M_PAD * DIM * sizeof(u16);
  float* x_f32  = (float*)alloc((size_t)M_PAD * DIM * sizeof(float));
  float* s2part = (float*)alloc((size_t)M_PAD * DIM * sizeof(float));
  float* xpart  = (float*)alloc((size_t)M_PAD * DIM * sizeof(float));
  u16* xb    = (u16*)alloc(NBF);
  u16* s1b   = (u16*)alloc(NBF);
  u16* s2b   = (u16*)alloc(NBF);
  u16* m0b   = (u16*)alloc(NBF);
  u16* m1b   = (u16*)alloc(NBF);
  u16* l0b   = (u16*)alloc(NBF);
  u16* aggAb = (u16*)alloc(NBF);
  u16* aggBb = (u16*)alloc(NBF);
  u16* h_bf  = (u16*)alloc((size_t)M_PAD * IN_DIM * sizeof(u16));
  u16* WT    = (u16*)alloc((size_t)(DIM * IN_DIM + 32 * DIM * DIM) * sizeof(u16));
  u16* WTe   = WT;
  u16* WTfd  = WT + DIM * IN_DIM;
  u16* WTfs  = WTfd + 6 * DIM * DIM;
  u16* WTld  = WTfs + 6 * DIM * DIM;
  u16* WTls  = WTld + 10 * DIM * DIM;
  float* invdeg = (float*)alloc(N_NODES * sizeof(float));
  int* counts  = (int*)alloc(N_NODES * sizeof(int));
  int* row_ofs = (int*)alloc((N_NODES + 1) * sizeof(int));
  int* cursor  = (int*)alloc(N_NODES * sizeof(int));
  int* csr_src = (int*)alloc(N_EDGES * sizeof(int));
  float* wsoft = (float*)alloc(80 * sizeof(float));
  float* hg    = (float*)alloc(N_GRAPHS * DIM * sizeof(float));

  const int EB = (N_EDGES + 255) / 256;

  // one init kernel: counts + all pad rows
  k_init<<<(PADR * DIM + 255) / 256 > 32 ? (PADR * DIM + 255) / 256 : 32, 256, 0, stream>>>(
      counts, h_bf + (size_t)N_NODES * IN_DIM,
      aggAb + (size_t)N_NODES * DIM, aggBb + (size_t)N_NODES * DIM,
      m0b + (size_t)N_NODES * DIM, m1b + (size_t)N_NODES * DIM);

  k_count<<<EB, 256, 0, stream>>>(dst, counts);
  k_scan<<<1, 256, 0, stream>>>(counts, row_ofs, cursor, invdeg);
  k_fill<<<EB, 256, 0, stream>>>(src, dst, cursor, csr_src);
  k_softmax<<<1, 64, 0, stream>>>(a_first, a_mid, a_last, wsoft);

  const float* wf = wsoft;
  const float* wm = wsoft + 24;
  const float* wl = wsoft + 40;

  k_cvt_bf16<<<(N_NODES * IN_DIM + 255) / 256, 256, 0, stream>>>(h, h_bf, N_NODES * IN_DIM);
  k_transpose_cvt<<<dim3(IN_DIM / 32, DIM / 32, 1), 256, 0, stream>>>(W_emb, WTe, IN_DIM, DIM);
  k_transpose_cvt32<<<dim3(8, 8, 32), 256, 0, stream>>>(Wf_d, Wf_s, Wl_d, Wl_s, wsoft, WTfd);

  const int GG1 = (M_PAD / 64) * 4;  // 512 blocks (N=256)
  const int GG2 = (M_PAD / 64) * 8;  // 1024 blocks (N=512)
  const int SB = (N_NODES + 3) / 4;

  // embedding: x = h @ W_emb + b_emb
  {
    GemmDescW d{};
    d.A[0] = h_bf; d.W[0][0] = WTe; d.b[0][0] = b_emb;
    d.nmat = 1; d.nid = 0; d.K = IN_DIM; d.colshift = 2;
    d.out_f32[0] = x_f32; d.out_bf[0] = xb;
    k_gemm_mfma<<<GG1, 256, 0, stream>>>(d);
  }

  for (int l = 0; l < 2; ++l) {
    auto WFD = [&](int e) { return WTfd + (size_t)(l * 3 + e) * DIM * DIM; };
    auto BFD = [&](int e) { return bf_d + (size_t)(l * 3 + e) * DIM; };
    auto WFS = [&](int e) { return WTfs + (size_t)(l * 3 + e) * DIM * DIM; };
    auto BFS = [&](int e) { return bf_s + (size_t)(l * 3 + e) * DIM; };
    auto WLD = [&](int e) { return WTld + (size_t)(l * 5 + e) * DIM * DIM; };
    auto BLD = [&](int e) { return bl_d + (size_t)(l * 5 + e) * DIM; };
    auto WLS = [&](int e) { return WTls + (size_t)(l * 5 + e) * DIM * DIM; };
    auto BLS = [&](int e) { return bl_s + (size_t)(l * 5 + e) * DIM; };
    auto WFrow = [&](int e) { return wf + (l * 3 + e) * 4; };
    auto WMrow = [&](int n) { return wm + (l * 2 + n) * 4; };
    auto WLrow = [&](int e) { return wl + (l * 5 + e) * 4; };

    // aggA = mean-agg(x)
    k_segmean_bf<<<SB, 256, 0, stream>>>(xb, row_ofs, csr_src, invdeg, aggAb);

    // G1 (wide): half0 -> s1 = relu(mixed(x,e0)); half1 -> s2part = mixed(x,e1) (f32)
    {
      GemmDescW d{};
      d.A[0] = xb; d.A[1] = aggAb; d.nmat = 2; d.K = DIM; d.colshift = 3;
      d.I[0] = xb; d.nid = 1;
      d.W[0][0] = WFD(0); d.b[0][0] = BFD(0); d.c[0][0] = WFrow(0) + 2;
      d.W[0][1] = WFS(0); d.b[0][1] = BFS(0); d.c[0][1] = WFrow(0) + 3;
      d.ic[0][0] = WFrow(0) + 1; d.relu[0] = 1; d.out_bf[0] = s1b;
      d.W[1][0] = WFD(1); d.b[1][0] = BFD(1); d.c[1][0] = WFrow(1) + 2;
      d.W[1][1] = WFS(1); d.b[1][1] = BFS(1); d.c[1][1] = WFrow(1) + 3;
      d.ic[1][0] = WFrow(1) + 1; d.relu[1] = 0; d.out_f32[1] = s2part;
      k_gemm_mfma<<<GG2, 256, 0, stream>>>(d);
    }

    // mid of s1: mean -> aggB; mixture -> m0
    k_segmid_bf<<<SB, 256, 0, stream>>>(s1b, row_ofs, csr_src, invdeg, WMrow(0), aggBb, m0b);

    // G2: s2 = relu(s2part + mixed(s1,e2))
    {
      GemmDescW d{};
      d.A[0] = s1b; d.A[1] = aggBb; d.nmat = 2; d.K = DIM; d.colshift = 2;
      d.I[0] = s1b; d.nid = 1;
      d.W[0][0] = WFD(2); d.b[0][0] = BFD(2); d.c[0][0] = WFrow(2) + 2;
      d.W[0][1] = WFS(2); d.b[0][1] = BFS(2); d.c[0][1] = WFrow(2) + 3;
      d.ic[0][0] = WFrow(2) + 1; d.pre[0] = s2part; d.relu[0] = 1; d.out_bf[0] = s2b;
      k_gemm_mfma<<<GG1, 256, 0, stream>>>(d);
    }

    // mid of s2 -> m1
    k_segmid_bf<<<SB, 256, 0, stream>>>(s2b, row_ofs, csr_src, invdeg, WMrow(1), nullptr, m1b);

    // mean-aggs of m0, m1
    k_segmean2_bf<<<SB, 256, 0, stream>>>(m0b, m1b, row_ofs, csr_src, invdeg, aggAb, aggBb);

    // G3 (wide): half0 -> l0 = relu(mixed(m0,e0)+mixed(m1,e1));
    //            half1 -> xpart = mixed(m0,e2)+mixed(m1,e3) (f32)
    {
      GemmDescW d{};
      d.A[0] = m0b; d.A[1] = aggAb; d.A[2] = m1b; d.A[3] = aggBb;
      d.nmat = 4; d.K = DIM; d.colshift = 3;
      d.I[0] = m0b; d.I[1] = m1b; d.nid = 2;
      d.W[0][0] = WLD(0); d.b[0][0] = BLD(0); d.c[0][0] = WLrow(0) + 2;
      d.W[0][1] = WLS(0); d.b[0][1] = BLS(0); d.c[0][1] = WLrow(0) + 3;
      d.W[0][2] = WLD(1); d.b[0][2] = BLD(1); d.c[0][2] = WLrow(1) + 2;
      d.W[0][3] = WLS(1); d.b[0][3] = BLS(1); d.c[0][3] = WLrow(1) + 3;
      d.ic[0][0] = WLrow(0) + 1; d.ic[0][1] = WLrow(1) + 1;
      d.relu[0] = 1; d.out_bf[0] = l0b;
      d.W[1][0] = WLD(2); d.b[1][0] = BLD(2); d.c[1][0] = WLrow(2) + 2;
      d.W[1][1] = WLS(2); d.b[1][1] = BLS(2); d.c[1][1] = WLrow(2) + 3;
      d.W[1][2] = WLD(3); d.b[1][2] = BLD(3); d.c[1][2] = WLrow(3) + 2;
      d.W[1][3] = WLS(3); d.b[1][3] = BLS(3); d.c[1][3] = WLrow(3) + 3;
      d.ic[1][0] = WLrow(2) + 1; d.ic[1][1] = WLrow(3) + 1;
      d.relu[1] = 0; d.out_f32[1] = xpart;
      k_gemm_mfma<<<GG2, 256, 0, stream>>>(d);
    }

    // mean-agg of l0 -> s1b (dead)
    k_segmean_bf<<<SB, 256, 0, stream>>>(l0b, row_ofs, csr_src, invdeg, s1b);

    // G4: x = x + 0.5*(l0 + relu(xpart + mixed(l0,e4)))
    {
      GemmDescW d{};
      d.A[0] = l0b; d.A[1] = s1b; d.nmat = 2; d.K = DIM; d.colshift = 2;
      d.I[0] = l0b; d.nid = 1;
      d.W[0][0] = WLD(4); d.b[0][0] = BLD(4); d.c[0][0] = WLrow(4) + 2;
      d.W[0][1] = WLS(4); d.b[0][1] = BLS(4); d.c[0][1] = WLrow(4) + 3;
      d.ic[0][0] = WLrow(4) + 1; d.pre[0] = xpart; d.relu[0] = 1;
      d.resid[0] = x_f32; d.addl[0] = l0b;
      d.out_f32[0] = x_f32; d.out_bf[0] = xb;
      k_gemm_mfma<<<GG1, 256, 0, stream>>>(d);
    }
  }

  k_readout<<<N_GRAPHS, 256, 0, stream>>>(x_f32, gid, hg);
  k_mlp<<<N_GRAPHS, 256, 0, stream>>>(hg, C1, c1b, C2, c2b, C3, c3b, (float*)d_out);
}

// Round 9
// 349.848 us; speedup vs baseline: 2.9958x; 1.0282x over previous
//
#include <hip/hip_runtime.h>

#define N_NODES   8000
#define M_PAD     8192
#define PADR      (M_PAD - N_NODES)
#define N_EDGES   128000
#define N_GRAPHS  64
#define DIM       256
#define IN_DIM    128

typedef short bf16x8 __attribute__((ext_vector_type(8)));
typedef float f32x4 __attribute__((ext_vector_type(4)));

static __device__ __forceinline__ float bf2f(unsigned v) {
  return __uint_as_float(v << 16);
}
static __device__ __forceinline__ unsigned f2bf(float f) {
  unsigned u = __float_as_uint(f);
  return (u + 0x7fffu + ((u >> 16) & 1u)) >> 16;
}

// ---------------------------------------------------------------------------
// init: zero counts + pad rows (round-6 version, known good)
// ---------------------------------------------------------------------------
__global__ __launch_bounds__(256) void k_init(int* __restrict__ counts,
                                              unsigned short* __restrict__ hpad,
                                              unsigned short* __restrict__ p0,
                                              unsigned short* __restrict__ p1,
                                              unsigned short* __restrict__ p2,
                                              unsigned short* __restrict__ p3) {
  int i = blockIdx.x * 256 + threadIdx.x;
  if (i < N_NODES) counts[i] = 0;
  if (i < PADR * IN_DIM) hpad[i] = 0;
  if (i < PADR * DIM) { p0[i] = 0; p1[i] = 0; p2[i] = 0; p3[i] = 0; }
}

// ---------------------------------------------------------------------------
// CSR build
// ---------------------------------------------------------------------------
__global__ __launch_bounds__(256) void k_count(const int* __restrict__ dst,
                                               int* __restrict__ counts) {
  int e = blockIdx.x * 256 + threadIdx.x;
  if (e < N_EDGES) atomicAdd(&counts[dst[e]], 1);
}

__global__ __launch_bounds__(256) void k_scan(const int* __restrict__ counts,
                                              int* __restrict__ row_ofs,
                                              int* __restrict__ cursor,
                                              float* __restrict__ invdeg) {
  __shared__ int chunk[256];
  const int per = (N_NODES + 255) / 256;  // 32
  int t = threadIdx.x;
  int base = t * per;
  int s = 0;
  for (int i = 0; i < per; ++i) {
    int idx = base + i;
    if (idx < N_NODES) s += counts[idx];
  }
  chunk[t] = s;
  __syncthreads();
  for (int off = 1; off < 256; off <<= 1) {
    int v = 0;
    if (t >= off) v = chunk[t - off];
    __syncthreads();
    if (t >= off) chunk[t] += v;
    __syncthreads();
  }
  int run = (t > 0) ? chunk[t - 1] : 0;
  for (int i = 0; i < per; ++i) {
    int idx = base + i;
    if (idx < N_NODES) {
      row_ofs[idx] = run;
      cursor[idx] = run;
      int c = counts[idx];
      invdeg[idx] = 1.0f / (float)(c > 1 ? c : 1);
      run += c;
    }
  }
  if (t == 0) row_ofs[N_NODES] = chunk[255];
}

__global__ __launch_bounds__(256) void k_fill(const int* __restrict__ src,
                                              const int* __restrict__ dst,
                                              int* __restrict__ cursor,
                                              int* __restrict__ csr_src) {
  int e = blockIdx.x * 256 + threadIdx.x;
  if (e < N_EDGES) {
    int p = atomicAdd(&cursor[dst[e]], 1);
    csr_src[p] = src[e];
  }
}

// ---------------------------------------------------------------------------
// Softmax over architecture rows; wsoft: [0..23]=wf, [24..39]=wm, [40..79]=wl
// ---------------------------------------------------------------------------
__global__ __launch_bounds__(64) void k_softmax(const float* __restrict__ af,
                                                const float* __restrict__ am,
                                                const float* __restrict__ al,
                                                float* __restrict__ w) {
  int t = threadIdx.x;
  const float* sp;
  float* dp;
  if (t < 6)       { sp = af + t * 4;        dp = w + t * 4; }
  else if (t < 10) { sp = am + (t - 6) * 4;  dp = w + 24 + (t - 6) * 4; }
  else if (t < 20) { sp = al + (t - 10) * 4; dp = w + 40 + (t - 10) * 4; }
  else return;
  float a0 = sp[0], a1 = sp[1], a2 = sp[2], a3 = sp[3];
  float m = fmaxf(fmaxf(a0, a1), fmaxf(a2, a3));
  float e0 = expf(a0 - m), e1 = expf(a1 - m), e2 = expf(a2 - m), e3 = expf(a3 - m);
  float si = 1.0f / (e0 + e1 + e2 + e3);
  dp[0] = e0 * si; dp[1] = e1 * si; dp[2] = e2 * si; dp[3] = e3 * si;
}

// ---------------------------------------------------------------------------
// Conversions (round-6 versions, known good)
// ---------------------------------------------------------------------------
__global__ __launch_bounds__(256) void k_cvt_bf16(const float* __restrict__ in,
                                                  unsigned short* __restrict__ out,
                                                  int n) {
  int i = blockIdx.x * 256 + threadIdx.x;
  if (i < n) out[i] = (unsigned short)f2bf(in[i]);
}

// W_emb^T only (K=IN_DIM)
__global__ __launch_bounds__(256) void k_transpose_cvt(const float* __restrict__ in,
                                                       unsigned short* __restrict__ out,
                                                       int K, int N) {
  __shared__ float tile[32][33];
  int k0 = blockIdx.x * 32, n0 = blockIdx.y * 32;
  int tx = threadIdx.x & 31, ty = threadIdx.x >> 5;  // 32 x 8
#pragma unroll
  for (int i = 0; i < 4; ++i)
    tile[ty + 8 * i][tx] = in[(size_t)(k0 + ty + 8 * i) * N + n0 + tx];
  __syncthreads();
#pragma unroll
  for (int i = 0; i < 4; ++i)
    out[(size_t)(n0 + ty + 8 * i) * K + k0 + tx] =
        (unsigned short)f2bf(tile[tx][ty + 8 * i]);
}

// all 32 DIMxDIM cell weights in one launch, coef-prescaled (reads wsoft).
__global__ __launch_bounds__(256) void k_transpose_cvt32(const float* __restrict__ Wfd,
                                                         const float* __restrict__ Wfs,
                                                         const float* __restrict__ Wld,
                                                         const float* __restrict__ Wls,
                                                         const float* __restrict__ wsoft,
                                                         unsigned short* __restrict__ out) {
  __shared__ float tile[32][33];
  int z = blockIdx.z;
  const float* in;
  float coef;
  const float* wf = wsoft;
  const float* wl = wsoft + 40;
  if (z < 6)       { in = Wfd + (size_t)z * DIM * DIM;        coef = wf[z * 4 + 2]; }
  else if (z < 12) { in = Wfs + (size_t)(z - 6) * DIM * DIM;  coef = wf[(z - 6) * 4 + 3]; }
  else if (z < 22) { in = Wld + (size_t)(z - 12) * DIM * DIM; coef = wl[(z - 12) * 4 + 2]; }
  else             { in = Wls + (size_t)(z - 22) * DIM * DIM; coef = wl[(z - 22) * 4 + 3]; }
  unsigned short* o = out + (size_t)z * DIM * DIM;
  int k0 = blockIdx.x * 32, n0 = blockIdx.y * 32;
  int tx = threadIdx.x & 31, ty = threadIdx.x >> 5;
#pragma unroll
  for (int i = 0; i < 4; ++i)
    tile[ty + 8 * i][tx] = in[(size_t)(k0 + ty + 8 * i) * DIM + n0 + tx];
  __syncthreads();
#pragma unroll
  for (int i = 0; i < 4; ++i)
    o[(size_t)(n0 + ty + 8 * i) * DIM + k0 + tx] =
        (unsigned short)f2bf(coef * tile[tx][ty + 8 * i]);
}

// ---------------------------------------------------------------------------
// Segment reductions (bf16). One wave per node, 4 nodes/block, 8-edge unroll.
// ---------------------------------------------------------------------------
#define SEG_ACC(u) \
  { s0 += bf2f((u).x & 0xffffu); s1 += bf2f((u).x >> 16); \
    s2 += bf2f((u).y & 0xffffu); s3 += bf2f((u).y >> 16); }

#define MID_ACC(u) \
  { float v0 = bf2f((u).x & 0xffffu), v1 = bf2f((u).x >> 16); \
    float v2 = bf2f((u).y & 0xffffu), v3 = bf2f((u).y >> 16); \
    s0 += v0; s1 += v1; s2 += v2; s3 += v3; \
    m0 = fmaxf(m0, v0); m1 = fmaxf(m1, v1); \
    m2 = fmaxf(m2, v2); m3 = fmaxf(m3, v3); }

__global__ __launch_bounds__(256) void k_segmean_bf(const unsigned short* __restrict__ X,
                                                    const int* __restrict__ row_ofs,
                                                    const int* __restrict__ csr_src,
                                                    const float* __restrict__ invdeg,
                                                    unsigned short* __restrict__ out) {
  int node = blockIdx.x * 4 + (threadIdx.x >> 6);
  int l = threadIdx.x & 63;
  if (node >= N_NODES) return;
  int beg = row_ofs[node], end = row_ofs[node + 1];
  float s0 = 0.f, s1 = 0.f, s2 = 0.f, s3 = 0.f;
  int e = beg;
  for (; e + 8 <= end; e += 8) {
    int i0 = csr_src[e], i1 = csr_src[e + 1], i2 = csr_src[e + 2], i3 = csr_src[e + 3];
    int i4 = csr_src[e + 4], i5 = csr_src[e + 5], i6 = csr_src[e + 6], i7 = csr_src[e + 7];
    uint2 u0 = *(const uint2*)&X[(size_t)i0 * DIM + 4 * l];
    uint2 u1 = *(const uint2*)&X[(size_t)i1 * DIM + 4 * l];
    uint2 u2 = *(const uint2*)&X[(size_t)i2 * DIM + 4 * l];
    uint2 u3 = *(const uint2*)&X[(size_t)i3 * DIM + 4 * l];
    uint2 u4 = *(const uint2*)&X[(size_t)i4 * DIM + 4 * l];
    uint2 u5 = *(const uint2*)&X[(size_t)i5 * DIM + 4 * l];
    uint2 u6 = *(const uint2*)&X[(size_t)i6 * DIM + 4 * l];
    uint2 u7 = *(const uint2*)&X[(size_t)i7 * DIM + 4 * l];
    SEG_ACC(u0) SEG_ACC(u1) SEG_ACC(u2) SEG_ACC(u3)
    SEG_ACC(u4) SEG_ACC(u5) SEG_ACC(u6) SEG_ACC(u7)
  }
  for (; e + 4 <= end; e += 4) {
    int i0 = csr_src[e], i1 = csr_src[e + 1], i2 = csr_src[e + 2], i3 = csr_src[e + 3];
    uint2 u0 = *(const uint2*)&X[(size_t)i0 * DIM + 4 * l];
    uint2 u1 = *(const uint2*)&X[(size_t)i1 * DIM + 4 * l];
    uint2 u2 = *(const uint2*)&X[(size_t)i2 * DIM + 4 * l];
    uint2 u3 = *(const uint2*)&X[(size_t)i3 * DIM + 4 * l];
    SEG_ACC(u0) SEG_ACC(u1) SEG_ACC(u2) SEG_ACC(u3)
  }
  for (; e < end; ++e) {
    uint2 u = *(const uint2*)&X[(size_t)csr_src[e] * DIM + 4 * l];
    SEG_ACC(u)
  }
  float iv = invdeg[node];
  uint2 o;
  o.x = f2bf(s0 * iv) | (f2bf(s1 * iv) << 16);
  o.y = f2bf(s2 * iv) | (f2bf(s3 * iv) << 16);
  *(uint2*)&out[(size_t)node * DIM + 4 * l] = o;
}

__global__ __launch_bounds__(256) void k_segmean2_bf(const unsigned short* __restrict__ X0,
                                                     const unsigned short* __restrict__ X1,
                                                     const int* __restrict__ row_ofs,
                                                     const int* __restrict__ csr_src,
                                                     const float* __restrict__ invdeg,
                                                     unsigned short* __restrict__ out0,
                                                     unsigned short* __restrict__ out1) {
  int node = blockIdx.x * 4 + (threadIdx.x >> 6);
  int l = threadIdx.x & 63;
  if (node >= N_NODES) return;
  int beg = row_ofs[node], end = row_ofs[node + 1];
  float a0 = 0.f, a1 = 0.f, a2 = 0.f, a3 = 0.f;
  float b0 = 0.f, b1 = 0.f, b2 = 0.f, b3 = 0.f;
  int e = beg;
  for (; e + 4 <= end; e += 4) {
    size_t r0 = (size_t)csr_src[e] * DIM + 4 * l;
    size_t r1 = (size_t)csr_src[e + 1] * DIM + 4 * l;
    size_t r2 = (size_t)csr_src[e + 2] * DIM + 4 * l;
    size_t r3 = (size_t)csr_src[e + 3] * DIM + 4 * l;
    uint2 u0 = *(const uint2*)&X0[r0];
    uint2 u1 = *(const uint2*)&X0[r1];
    uint2 u2 = *(const uint2*)&X0[r2];
    uint2 u3 = *(const uint2*)&X0[r3];
    uint2 v0 = *(const uint2*)&X1[r0];
    uint2 v1 = *(const uint2*)&X1[r1];
    uint2 v2 = *(const uint2*)&X1[r2];
    uint2 v3 = *(const uint2*)&X1[r3];
    a0 += bf2f(u0.x & 0xffffu) + bf2f(u1.x & 0xffffu) + bf2f(u2.x & 0xffffu) + bf2f(u3.x & 0xffffu);
    a1 += bf2f(u0.x >> 16) + bf2f(u1.x >> 16) + bf2f(u2.x >> 16) + bf2f(u3.x >> 16);
    a2 += bf2f(u0.y & 0xffffu) + bf2f(u1.y & 0xffffu) + bf2f(u2.y & 0xffffu) + bf2f(u3.y & 0xffffu);
    a3 += bf2f(u0.y >> 16) + bf2f(u1.y >> 16) + bf2f(u2.y >> 16) + bf2f(u3.y >> 16);
    b0 += bf2f(v0.x & 0xffffu) + bf2f(v1.x & 0xffffu) + bf2f(v2.x & 0xffffu) + bf2f(v3.x & 0xffffu);
    b1 += bf2f(v0.x >> 16) + bf2f(v1.x >> 16) + bf2f(v2.x >> 16) + bf2f(v3.x >> 16);
    b2 += bf2f(v0.y & 0xffffu) + bf2f(v1.y & 0xffffu) + bf2f(v2.y & 0xffffu) + bf2f(v3.y & 0xffffu);
    b3 += bf2f(v0.y >> 16) + bf2f(v1.y >> 16) + bf2f(v2.y >> 16) + bf2f(v3.y >> 16);
  }
  for (; e < end; ++e) {
    size_t rb = (size_t)csr_src[e] * DIM + 4 * l;
    uint2 u = *(const uint2*)&X0[rb];
    uint2 v = *(const uint2*)&X1[rb];
    a0 += bf2f(u.x & 0xffffu); a1 += bf2f(u.x >> 16);
    a2 += bf2f(u.y & 0xffffu); a3 += bf2f(u.y >> 16);
    b0 += bf2f(v.x & 0xffffu); b1 += bf2f(v.x >> 16);
    b2 += bf2f(v.y & 0xffffu); b3 += bf2f(v.y >> 16);
  }
  float iv = invdeg[node];
  uint2 o;
  o.x = f2bf(a0 * iv) | (f2bf(a1 * iv) << 16);
  o.y = f2bf(a2 * iv) | (f2bf(a3 * iv) << 16);
  *(uint2*)&out0[(size_t)node * DIM + 4 * l] = o;
  o.x = f2bf(b0 * iv) | (f2bf(b1 * iv) << 16);
  o.y = f2bf(b2 * iv) | (f2bf(b3 * iv) << 16);
  *(uint2*)&out1[(size_t)node * DIM + 4 * l] = o;
}

// sum+max over incoming msgs of relu'd input; epilogue = middle-stage mixture.
__global__ __launch_bounds__(256) void k_segmid_bf(const unsigned short* __restrict__ Xn,
                                                   const int* __restrict__ row_ofs,
                                                   const int* __restrict__ csr_src,
                                                   const float* __restrict__ invdeg,
                                                   const float* __restrict__ wrow,
                                                   unsigned short* __restrict__ mean_out,
                                                   unsigned short* __restrict__ mids_out) {
  int node = blockIdx.x * 4 + (threadIdx.x >> 6);
  int l = threadIdx.x & 63;
  if (node >= N_NODES) return;
  int beg = row_ofs[node], end = row_ofs[node + 1];
  float s0 = 0.f, s1 = 0.f, s2 = 0.f, s3 = 0.f;
  float m0 = 0.f, m1 = 0.f, m2 = 0.f, m3 = 0.f;  // inputs >= 0 (relu)
  int e = beg;
  for (; e + 8 <= end; e += 8) {
    int i0 = csr_src[e], i1 = csr_src[e + 1], i2 = csr_src[e + 2], i3 = csr_src[e + 3];
    int i4 = csr_src[e + 4], i5 = csr_src[e + 5], i6 = csr_src[e + 6], i7 = csr_src[e + 7];
    uint2 u0 = *(const uint2*)&Xn[(size_t)i0 * DIM + 4 * l];
    uint2 u1 = *(const uint2*)&Xn[(size_t)i1 * DIM + 4 * l];
    uint2 u2 = *(const uint2*)&Xn[(size_t)i2 * DIM + 4 * l];
    uint2 u3 = *(const uint2*)&Xn[(size_t)i3 * DIM + 4 * l];
    uint2 u4 = *(const uint2*)&Xn[(size_t)i4 * DIM + 4 * l];
    uint2 u5 = *(const uint2*)&Xn[(size_t)i5 * DIM + 4 * l];
    uint2 u6 = *(const uint2*)&Xn[(size_t)i6 * DIM + 4 * l];
    uint2 u7 = *(const uint2*)&Xn[(size_t)i7 * DIM + 4 * l];
    MID_ACC(u0) MID_ACC(u1) MID_ACC(u2) MID_ACC(u3)
    MID_ACC(u4) MID_ACC(u5) MID_ACC(u6) MID_ACC(u7)
  }
  for (; e + 4 <= end; e += 4) {
    int i0 = csr_src[e], i1 = csr_src[e + 1], i2 = csr_src[e + 2], i3 = csr_src[e + 3];
    uint2 u0 = *(const uint2*)&Xn[(size_t)i0 * DIM + 4 * l];
    uint2 u1 = *(const uint2*)&Xn[(size_t)i1 * DIM + 4 * l];
    uint2 u2 = *(const uint2*)&Xn[(size_t)i2 * DIM + 4 * l];
    uint2 u3 = *(const uint2*)&Xn[(size_t)i3 * DIM + 4 * l];
    MID_ACC(u0) MID_ACC(u1) MID_ACC(u2) MID_ACC(u3)
  }
  for (; e < end; ++e) {
    uint2 u = *(const uint2*)&Xn[(size_t)csr_src[e] * DIM + 4 * l];
    MID_ACC(u)
  }
  float iv = invdeg[node];
  float e0 = s0 * iv, e1 = s1 * iv, e2 = s2 * iv, e3 = s3 * iv;
  if (mean_out) {
    uint2 o;
    o.x = f2bf(e0) | (f2bf(e1) << 16);
    o.y = f2bf(e2) | (f2bf(e3) << 16);
    *(uint2*)&mean_out[(size_t)node * DIM + 4 * l] = o;
  }
  float w0 = wrow[0], w1 = wrow[1], w2 = wrow[2], w3 = wrow[3];
  uint2 xu = *(const uint2*)&Xn[(size_t)node * DIM + 4 * l];
  float x0 = bf2f(xu.x & 0xffffu), x1 = bf2f(xu.x >> 16);
  float x2 = bf2f(xu.y & 0xffffu), x3 = bf2f(xu.y >> 16);
  uint2 o;
  o.x = f2bf(w0 * x0 + w1 * m0 + w2 * e0 + w3 * s0) |
        (f2bf(w0 * x1 + w1 * m1 + w2 * e1 + w3 * s1) << 16);
  o.y = f2bf(w0 * x2 + w1 * m2 + w2 * e2 + w3 * s2) |
        (f2bf(w0 * x3 + w1 * m3 + w2 * e3 + w3 * s3) << 16);
  *(uint2*)&mids_out[(size_t)node * DIM + 4 * l] = o;
}

// ---------------------------------------------------------------------------
// Wide MFMA multi-term GEMM with per-column-half epilogues (N = 256*nhalves).
// ---------------------------------------------------------------------------
struct GemmDescW {
  const unsigned short* A[4];
  const unsigned short* W[2][4];
  const float* b[2][4];
  const float* c[2][4];
  const unsigned short* I[2];
  const float* ic[2][2];
  const float* pre[2];            // f32 pre-accumulated partial
  const float* resid[2];
  const unsigned short* addl[2];
  float* out_f32[2];
  unsigned short* out_bf[2];
  int nmat, nid, K, relu[2], colshift;
};

__global__ __launch_bounds__(256) void k_gemm_mfma(GemmDescW d) {
  __shared__ __align__(16) unsigned short As[2][64][72];
  __shared__ __align__(16) unsigned short Bs[2][64][72];
  const int tid = threadIdx.x;
  const int b = blockIdx.x;
  const int cs = d.colshift;
  const int c = (b >> 3) & ((1 << cs) - 1);
  const int bm = ((b & 7) + 8 * (b >> (3 + cs))) * 64;
  const int half = c >> 2;
  const int bn = (c & 3) * 64;
  const int w = tid >> 6, l = tid & 63;
  const int wm = (w >> 1) * 32, wn = (w & 1) * 32;
  const int lr = l & 15, lk = (l >> 4) * 8;
  const int ldr = tid >> 3, ldk = (tid & 7) * 8;

  const int K = d.K;
  const int kds = (K == 256) ? 2 : 1;
  const int kmask = (1 << kds) - 1;
  const int nsteps = d.nmat << kds;

  f32x4 zero = {0.f, 0.f, 0.f, 0.f};
  f32x4 acc[2][2];
  acc[0][0] = zero; acc[0][1] = zero; acc[1][0] = zero; acc[1][1] = zero;

  auto gload = [&](int s, uint4& a0, uint4& a1, uint4& b0, uint4& b1) {
    int t = s >> kds;
    int k0 = (s & kmask) << 6;
    const unsigned short* __restrict__ A = d.A[t];
    const unsigned short* __restrict__ W = d.W[half][t];
    a0 = *(const uint4*)&A[(size_t)(bm + ldr) * K + k0 + ldk];
    a1 = *(const uint4*)&A[(size_t)(bm + ldr + 32) * K + k0 + ldk];
    b0 = *(const uint4*)&W[(size_t)(bn + ldr) * K + k0 + ldk];
    b1 = *(const uint4*)&W[(size_t)(bn + ldr + 32) * K + k0 + ldk];
  };

  {
    uint4 a0, a1, b0, b1;
    gload(0, a0, a1, b0, b1);
    *(uint4*)&As[0][ldr][ldk] = a0;
    *(uint4*)&As[0][ldr + 32][ldk] = a1;
    *(uint4*)&Bs[0][ldr][ldk] = b0;
    *(uint4*)&Bs[0][ldr + 32][ldk] = b1;
  }
  __syncthreads();

  int buf = 0;
  for (int s = 0; s < nsteps; ++s) {
    uint4 na0, na1, nb0, nb1;
    const bool more = (s + 1 < nsteps);
    if (more) gload(s + 1, na0, na1, nb0, nb1);
#pragma unroll
    for (int ks = 0; ks < 2; ++ks) {
      bf16x8 a0 = *(const bf16x8*)&As[buf][wm + lr][ks * 32 + lk];
      bf16x8 a1 = *(const bf16x8*)&As[buf][wm + 16 + lr][ks * 32 + lk];
      bf16x8 b0 = *(const bf16x8*)&Bs[buf][wn + lr][ks * 32 + lk];
      bf16x8 b1 = *(const bf16x8*)&Bs[buf][wn + 16 + lr][ks * 32 + lk];
      acc[0][0] = __builtin_amdgcn_mfma_f32_16x16x32_bf16(a0, b0, acc[0][0], 0, 0, 0);
      acc[0][1] = __builtin_amdgcn_mfma_f32_16x16x32_bf16(a0, b1, acc[0][1], 0, 0, 0);
      acc[1][0] = __builtin_amdgcn_mfma_f32_16x16x32_bf16(a1, b0, acc[1][0], 0, 0, 0);
      acc[1][1] = __builtin_amdgcn_mfma_f32_16x16x32_bf16(a1, b1, acc[1][1], 0, 0, 0);
    }
    if (more) {
      *(uint4*)&As[buf ^ 1][ldr][ldk] = na0;
      *(uint4*)&As[buf ^ 1][ldr + 32][ldk] = na1;
      *(uint4*)&Bs[buf ^ 1][ldr][ldk] = nb0;
      *(uint4*)&Bs[buf ^ 1][ldr + 32][ldk] = nb1;
    }
    __syncthreads();
    buf ^= 1;
  }

  // epilogue (per half)
  float bias[2] = {0.f, 0.f};
  for (int t = 0; t < d.nmat; ++t) {
    const float* bp = d.b[half][t];
    if (bp) {
      float cc = d.c[half][t] ? *d.c[half][t] : 1.0f;
      bias[0] += cc * bp[bn + wn + lr];
      bias[1] += cc * bp[bn + wn + 16 + lr];
    }
  }
  float vout[2][2][4];
#pragma unroll
  for (int m = 0; m < 2; ++m)
#pragma unroll
    for (int n = 0; n < 2; ++n)
#pragma unroll
      for (int i = 0; i < 4; ++i) vout[m][n][i] = acc[m][n][i] + bias[n];
#pragma unroll
  for (int u = 0; u < 2; ++u) {
    if (u < d.nid) {
      float icu = *d.ic[half][u];
      const unsigned short* __restrict__ I = d.I[u];
#pragma unroll
      for (int m = 0; m < 2; ++m)
#pragma unroll
        for (int n = 0; n < 2; ++n)
#pragma unroll
          for (int i = 0; i < 4; ++i) {
            int row = bm + wm + m * 16 + (l >> 4) * 4 + i;
            int col = bn + wn + n * 16 + lr;
            vout[m][n][i] += icu * bf2f(I[(size_t)row * DIM + col]);
          }
    }
  }
  const float* pre = d.pre[half];
  const float* resid = d.resid[half];
  const unsigned short* addl = d.addl[half];
  unsigned short* obf = d.out_bf[half];
  float* of32 = d.out_f32[half];
  const int do_relu = d.relu[half];
#pragma unroll
  for (int m = 0; m < 2; ++m)
#pragma unroll
    for (int n = 0; n < 2; ++n)
#pragma unroll
      for (int i = 0; i < 4; ++i) {
        int row = bm + wm + m * 16 + (l >> 4) * 4 + i;
        int col = bn + wn + n * 16 + lr;
        size_t idx = (size_t)row * DIM + col;
        float v = vout[m][n][i];
        if (pre) v += pre[idx];
        if (do_relu) v = fmaxf(v, 0.f);
        if (resid) v = resid[idx] + 0.5f * (bf2f(addl[idx]) + v);
        if (obf) obf[idx] = (unsigned short)f2bf(v);
        if (of32) of32[idx] = v;
      }
}

// ---------------------------------------------------------------------------
// Fused readout + MLP: block g computes its graph mean then the 3-layer MLP.
// ---------------------------------------------------------------------------
__global__ __launch_bounds__(256) void k_readout_mlp(const float* __restrict__ x,
                                                     const int* __restrict__ gid,
                                                     const float* __restrict__ C1,
                                                     const float* __restrict__ c1b,
                                                     const float* __restrict__ C2,
                                                     const float* __restrict__ c2b,
                                                     const float* __restrict__ C3,
                                                     const float* __restrict__ c3b,
                                                     float* __restrict__ out) {
  int g = blockIdx.x, t = threadIdx.x;
  int lo = 0, hi = N_NODES;
  while (lo < hi) { int m = (lo + hi) >> 1; if (gid[m] < g) lo = m + 1; else hi = m; }
  int beg = lo;
  lo = beg; hi = N_NODES;
  while (lo < hi) { int m = (lo + hi) >> 1; if (gid[m] <= g) lo = m + 1; else hi = m; }
  int end = lo;
  float s = 0.f;
  for (int i = beg; i < end; ++i) s += x[(size_t)i * DIM + t];
  int cnt = end - beg;
  __shared__ float h0[256], h1[128], h2[64];
  h0[t] = s / (float)(cnt > 1 ? cnt : 1);
  __syncthreads();
  if (t < 128) {
    float v = c1b[t];
    for (int k = 0; k < 256; ++k) v = fmaf(h0[k], C1[k * 128 + t], v);
    h1[t] = fmaxf(v, 0.f);
  }
  __syncthreads();
  if (t < 64) {
    float v = c2b[t];
    for (int k = 0; k < 128; ++k) v = fmaf(h1[k], C2[k * 64 + t], v);
    h2[t] = fmaxf(v, 0.f);
  }
  __syncthreads();
  if (t < 10) {
    float v = c3b[t];
    for (int k = 0; k < 64; ++k) v = fmaf(h2[k], C3[k * 10 + t], v);
    out[g * 10 + t] = v;
  }
}

// ---------------------------------------------------------------------------
extern "C" void kernel_launch(void* const* d_in, const int* in_sizes, int n_in,
                              void* d_out, int out_size, void* d_ws, size_t ws_size,
                              hipStream_t stream) {
  const float* h     = (const float*)d_in[0];
  const float* W_emb = (const float*)d_in[1];
  const float* b_emb = (const float*)d_in[2];
  const float* Wf_d  = (const float*)d_in[3];
  const float* bf_d  = (const float*)d_in[4];
  const float* Wf_s  = (const float*)d_in[5];
  const float* bf_s  = (const float*)d_in[6];
  const float* Wl_d  = (const float*)d_in[7];
  const float* bl_d  = (const float*)d_in[8];
  const float* Wl_s  = (const float*)d_in[9];
  const float* bl_s  = (const float*)d_in[10];
  const float* a_first = (const float*)d_in[11];
  const float* a_mid   = (const float*)d_in[12];
  const float* a_last  = (const float*)d_in[13];
  const float* C1 = (const float*)d_in[14];
  const float* c1b = (const float*)d_in[15];
  const float* C2 = (const float*)d_in[16];
  const float* c2b = (const float*)d_in[17];
  const float* C3 = (const float*)d_in[18];
  const float* c3b = (const float*)d_in[19];
  const int* src = (const int*)d_in[20];
  const int* dst = (const int*)d_in[21];
  const int* gid = (const int*)d_in[22];
  (void)in_sizes; (void)n_in; (void)out_size; (void)ws_size;

  char* p = (char*)d_ws;
  auto alloc = [&](size_t bytes) {
    void* r = (void*)p;
    p += (bytes + 255) & ~(size_t)255;
    return r;
  };
  typedef unsigned short u16;
  const size_t NBF = (size_t)M_PAD * DIM * sizeof(u16);
  float* x_f32  = (float*)alloc((size_t)M_PAD * DIM * sizeof(float));
  float* s2part = (float*)alloc((size_t)M_PAD * DIM * sizeof(float));
  float* xpart  = (float*)alloc((size_t)M_PAD * DIM * sizeof(float));
  u16* xb    = (u16*)alloc(NBF);
  u16* s1b   = (u16*)alloc(NBF);
  u16* s2b   = (u16*)alloc(NBF);
  u16* m0b   = (u16*)alloc(NBF);
  u16* m1b   = (u16*)alloc(NBF);
  u16* l0b   = (u16*)alloc(NBF);
  u16* aggAb = (u16*)alloc(NBF);
  u16* aggBb = (u16*)alloc(NBF);
  u16* h_bf  = (u16*)alloc((size_t)M_PAD * IN_DIM * sizeof(u16));
  u16* WT    = (u16*)alloc((size_t)(DIM * IN_DIM + 32 * DIM * DIM) * sizeof(u16));
  u16* WTe   = WT;
  u16* WTfd  = WT + DIM * IN_DIM;
  u16* WTfs  = WTfd + 6 * DIM * DIM;
  u16* WTld  = WTfs + 6 * DIM * DIM;
  u16* WTls  = WTld + 10 * DIM * DIM;
  float* invdeg = (float*)alloc(N_NODES * sizeof(float));
  int* counts  = (int*)alloc(N_NODES * sizeof(int));
  int* row_ofs = (int*)alloc((N_NODES + 1) * sizeof(int));
  int* cursor  = (int*)alloc(N_NODES * sizeof(int));
  int* csr_src = (int*)alloc(N_EDGES * sizeof(int));
  float* wsoft = (float*)alloc(80 * sizeof(float));

  const int EB = (N_EDGES + 255) / 256;

  // round-6 prep path (known good)
  k_init<<<192, 256, 0, stream>>>(
      counts, h_bf + (size_t)N_NODES * IN_DIM,
      aggAb + (size_t)N_NODES * DIM, aggBb + (size_t)N_NODES * DIM,
      m0b + (size_t)N_NODES * DIM, m1b + (size_t)N_NODES * DIM);

  k_count<<<EB, 256, 0, stream>>>(dst, counts);
  k_scan<<<1, 256, 0, stream>>>(counts, row_ofs, cursor, invdeg);
  k_fill<<<EB, 256, 0, stream>>>(src, dst, cursor, csr_src);
  k_softmax<<<1, 64, 0, stream>>>(a_first, a_mid, a_last, wsoft);

  const float* wf = wsoft;
  const float* wm = wsoft + 24;
  const float* wl = wsoft + 40;

  k_cvt_bf16<<<(N_NODES * IN_DIM + 255) / 256, 256, 0, stream>>>(h, h_bf, N_NODES * IN_DIM);
  k_transpose_cvt<<<dim3(IN_DIM / 32, DIM / 32, 1), 256, 0, stream>>>(W_emb, WTe, IN_DIM, DIM);
  k_transpose_cvt32<<<dim3(8, 8, 32), 256, 0, stream>>>(Wf_d, Wf_s, Wl_d, Wl_s, wsoft, WTfd);

  const int GG1 = (M_PAD / 64) * 4;  // 512 blocks (N=256)
  const int GG2 = (M_PAD / 64) * 8;  // 1024 blocks (N=512)
  const int SB = (N_NODES + 3) / 4;

  // embedding: x = h @ W_emb + b_emb
  {
    GemmDescW d{};
    d.A[0] = h_bf; d.W[0][0] = WTe; d.b[0][0] = b_emb;
    d.nmat = 1; d.nid = 0; d.K = IN_DIM; d.colshift = 2;
    d.out_f32[0] = x_f32; d.out_bf[0] = xb;
    k_gemm_mfma<<<GG1, 256, 0, stream>>>(d);
  }

  for (int l = 0; l < 2; ++l) {
    auto WFD = [&](int e) { return WTfd + (size_t)(l * 3 + e) * DIM * DIM; };
    auto BFD = [&](int e) { return bf_d + (size_t)(l * 3 + e) * DIM; };
    auto WFS = [&](int e) { return WTfs + (size_t)(l * 3 + e) * DIM * DIM; };
    auto BFS = [&](int e) { return bf_s + (size_t)(l * 3 + e) * DIM; };
    auto WLD = [&](int e) { return WTld + (size_t)(l * 5 + e) * DIM * DIM; };
    auto BLD = [&](int e) { return bl_d + (size_t)(l * 5 + e) * DIM; };
    auto WLS = [&](int e) { return WTls + (size_t)(l * 5 + e) * DIM * DIM; };
    auto BLS = [&](int e) { return bl_s + (size_t)(l * 5 + e) * DIM; };
    auto WFrow = [&](int e) { return wf + (l * 3 + e) * 4; };
    auto WMrow = [&](int n) { return wm + (l * 2 + n) * 4; };
    auto WLrow = [&](int e) { return wl + (l * 5 + e) * 4; };

    // aggA = mean-agg(x)
    k_segmean_bf<<<SB, 256, 0, stream>>>(xb, row_ofs, csr_src, invdeg, aggAb);

    // G1 (wide): half0 -> s1 = relu(mixed(x,e0)); half1 -> s2part = mixed(x,e1) (f32)
    {
      GemmDescW d{};
      d.A[0] = xb; d.A[1] = aggAb; d.nmat = 2; d.K = DIM; d.colshift = 3;
      d.I[0] = xb; d.nid = 1;
      d.W[0][0] = WFD(0); d.b[0][0] = BFD(0); d.c[0][0] = WFrow(0) + 2;
      d.W[0][1] = WFS(0); d.b[0][1] = BFS(0); d.c[0][1] = WFrow(0) + 3;
      d.ic[0][0] = WFrow(0) + 1; d.relu[0] = 1; d.out_bf[0] = s1b;
      d.W[1][0] = WFD(1); d.b[1][0] = BFD(1); d.c[1][0] = WFrow(1) + 2;
      d.W[1][1] = WFS(1); d.b[1][1] = BFS(1); d.c[1][1] = WFrow(1) + 3;
      d.ic[1][0] = WFrow(1) + 1; d.relu[1] = 0; d.out_f32[1] = s2part;
      k_gemm_mfma<<<GG2, 256, 0, stream>>>(d);
    }

    // mid of s1: mean -> aggB; mixture -> m0
    k_segmid_bf<<<SB, 256, 0, stream>>>(s1b, row_ofs, csr_src, invdeg, WMrow(0), aggBb, m0b);

    // G2: s2 = relu(s2part + mixed(s1,e2))
    {
      GemmDescW d{};
      d.A[0] = s1b; d.A[1] = aggBb; d.nmat = 2; d.K = DIM; d.colshift = 2;
      d.I[0] = s1b; d.nid = 1;
      d.W[0][0] = WFD(2); d.b[0][0] = BFD(2); d.c[0][0] = WFrow(2) + 2;
      d.W[0][1] = WFS(2); d.b[0][1] = BFS(2); d.c[0][1] = WFrow(2) + 3;
      d.ic[0][0] = WFrow(2) + 1; d.pre[0] = s2part; d.relu[0] = 1; d.out_bf[0] = s2b;
      k_gemm_mfma<<<GG1, 256, 0, stream>>>(d);
    }

    // mid of s2 -> m1
    k_segmid_bf<<<SB, 256, 0, stream>>>(s2b, row_ofs, csr_src, invdeg, WMrow(1), nullptr, m1b);

    // mean-aggs of m0, m1
    k_segmean2_bf<<<SB, 256, 0, stream>>>(m0b, m1b, row_ofs, csr_src, invdeg, aggAb, aggBb);

    // G3 (wide): half0 -> l0 = relu(mixed(m0,e0)+mixed(m1,e1));
    //            half1 -> xpart = mixed(m0,e2)+mixed(m1,e3) (f32)
    {
      GemmDescW d{};
      d.A[0] = m0b; d.A[1] = aggAb; d.A[2] = m1b; d.A[3] = aggBb;
      d.nmat = 4; d.K = DIM; d.colshift = 3;
      d.I[0] = m0b; d.I[1] = m1b; d.nid = 2;
      d.W[0][0] = WLD(0); d.b[0][0] = BLD(0); d.c[0][0] = WLrow(0) + 2;
      d.W[0][1] = WLS(0); d.b[0][1] = BLS(0); d.c[0][1] = WLrow(0) + 3;
      d.W[0][2] = WLD(1); d.b[0][2] = BLD(1); d.c[0][2] = WLrow(1) + 2;
      d.W[0][3] = WLS(1); d.b[0][3] = BLS(1); d.c[0][3] = WLrow(1) + 3;
      d.ic[0][0] = WLrow(0) + 1; d.ic[0][1] = WLrow(1) + 1;
      d.relu[0] = 1; d.out_bf[0] = l0b;
      d.W[1][0] = WLD(2); d.b[1][0] = BLD(2); d.c[1][0] = WLrow(2) + 2;
      d.W[1][1] = WLS(2); d.b[1][1] = BLS(2); d.c[1][1] = WLrow(2) + 3;
      d.W[1][2] = WLD(3); d.b[1][2] = BLD(3); d.c[1][2] = WLrow(3) + 2;
      d.W[1][3] = WLS(3); d.b[1][3] = BLS(3); d.c[1][3] = WLrow(3) + 3;
      d.ic[1][0] = WLrow(2) + 1; d.ic[1][1] = WLrow(3) + 1;
      d.relu[1] = 0; d.out_f32[1] = xpart;
      k_gemm_mfma<<<GG2, 256, 0, stream>>>(d);
    }

    // mean-agg of l0 -> s1b (dead)
    k_segmean_bf<<<SB, 256, 0, stream>>>(l0b, row_ofs, csr_src, invdeg, s1b);

    // G4: x = x + 0.5*(l0 + relu(xpart + mixed(l0,e4)))
    {
      GemmDescW d{};
      d.A[0] = l0b; d.A[1] = s1b; d.nmat = 2; d.K = DIM; d.colshift = 2;
      d.I[0] = l0b; d.nid = 1;
      d.W[0][0] = WLD(4); d.b[0][0] = BLD(4); d.c[0][0] = WLrow(4) + 2;
      d.W[0][1] = WLS(4); d.b[0][1] = BLS(4); d.c[0][1] = WLrow(4) + 3;
      d.ic[0][0] = WLrow(4) + 1; d.pre[0] = xpart; d.relu[0] = 1;
      d.resid[0] = x_f32; d.addl[0] = l0b;
      d.out_f32[0] = x_f32; d.out_bf[0] = xb;
      k_gemm_mfma<<<GG1, 256, 0, stream>>>(d);
    }
  }

  k_readout_mlp<<<N_GRAPHS, 256, 0, stream>>>(x_f32, gid, C1, c1b, C2, c2b, C3, c3b,
                                              (float*)d_out);
}

// Round 10
// 326.938 us; speedup vs baseline: 3.2057x; 1.0701x over previous
//
#include <hip/hip_runtime.h>

#define N_NODES   8000
#define M_PAD     8192
#define PADR      (M_PAD - N_NODES)
#define N_EDGES   128000
#define N_GRAPHS  64
#define DIM       256
#define IN_DIM    128

typedef short bf16x8 __attribute__((ext_vector_type(8)));
typedef float f32x4 __attribute__((ext_vector_type(4)));

static __device__ __forceinline__ float bf2f(unsigned v) {
  return __uint_as_float(v << 16);
}
static __device__ __forceinline__ unsigned f2bf(float f) {
  unsigned u = __float_as_uint(f);
  return (u + 0x7fffu + ((u >> 16) & 1u)) >> 16;
}

// ---------------------------------------------------------------------------
// init: zero counts + pad rows (round-6 version, known good)
// ---------------------------------------------------------------------------
__global__ __launch_bounds__(256) void k_init(int* __restrict__ counts,
                                              unsigned short* __restrict__ hpad,
                                              unsigned short* __restrict__ p0,
                                              unsigned short* __restrict__ p1,
                                              unsigned short* __restrict__ p2,
                                              unsigned short* __restrict__ p3) {
  int i = blockIdx.x * 256 + threadIdx.x;
  if (i < N_NODES) counts[i] = 0;
  if (i < PADR * IN_DIM) hpad[i] = 0;
  if (i < PADR * DIM) { p0[i] = 0; p1[i] = 0; p2[i] = 0; p3[i] = 0; }
}

// ---------------------------------------------------------------------------
// CSR build
// ---------------------------------------------------------------------------
__global__ __launch_bounds__(256) void k_count(const int* __restrict__ dst,
                                               int* __restrict__ counts) {
  int e = blockIdx.x * 256 + threadIdx.x;
  if (e < N_EDGES) atomicAdd(&counts[dst[e]], 1);
}

__global__ __launch_bounds__(256) void k_scan(const int* __restrict__ counts,
                                              int* __restrict__ row_ofs,
                                              int* __restrict__ cursor,
                                              float* __restrict__ invdeg) {
  __shared__ int chunk[256];
  const int per = (N_NODES + 255) / 256;  // 32
  int t = threadIdx.x;
  int base = t * per;
  int s = 0;
  for (int i = 0; i < per; ++i) {
    int idx = base + i;
    if (idx < N_NODES) s += counts[idx];
  }
  chunk[t] = s;
  __syncthreads();
  for (int off = 1; off < 256; off <<= 1) {
    int v = 0;
    if (t >= off) v = chunk[t - off];
    __syncthreads();
    if (t >= off) chunk[t] += v;
    __syncthreads();
  }
  int run = (t > 0) ? chunk[t - 1] : 0;
  for (int i = 0; i < per; ++i) {
    int idx = base + i;
    if (idx < N_NODES) {
      row_ofs[idx] = run;
      cursor[idx] = run;
      int c = counts[idx];
      invdeg[idx] = 1.0f / (float)(c > 1 ? c : 1);
      run += c;
    }
  }
  if (t == 0) row_ofs[N_NODES] = chunk[255];
}

__global__ __launch_bounds__(256) void k_fill(const int* __restrict__ src,
                                              const int* __restrict__ dst,
                                              int* __restrict__ cursor,
                                              int* __restrict__ csr_src) {
  int e = blockIdx.x * 256 + threadIdx.x;
  if (e < N_EDGES) {
    int p = atomicAdd(&cursor[dst[e]], 1);
    csr_src[p] = src[e];
  }
}

// ---------------------------------------------------------------------------
// Softmax over architecture rows; wsoft: [0..23]=wf, [24..39]=wm, [40..79]=wl
// ---------------------------------------------------------------------------
__global__ __launch_bounds__(64) void k_softmax(const float* __restrict__ af,
                                                const float* __restrict__ am,
                                                const float* __restrict__ al,
                                                float* __restrict__ w) {
  int t = threadIdx.x;
  const float* sp;
  float* dp;
  if (t < 6)       { sp = af + t * 4;        dp = w + t * 4; }
  else if (t < 10) { sp = am + (t - 6) * 4;  dp = w + 24 + (t - 6) * 4; }
  else if (t < 20) { sp = al + (t - 10) * 4; dp = w + 40 + (t - 10) * 4; }
  else return;
  float a0 = sp[0], a1 = sp[1], a2 = sp[2], a3 = sp[3];
  float m = fmaxf(fmaxf(a0, a1), fmaxf(a2, a3));
  float e0 = expf(a0 - m), e1 = expf(a1 - m), e2 = expf(a2 - m), e3 = expf(a3 - m);
  float si = 1.0f / (e0 + e1 + e2 + e3);
  dp[0] = e0 * si; dp[1] = e1 * si; dp[2] = e2 * si; dp[3] = e3 * si;
}

// ---------------------------------------------------------------------------
// Conversions (round-6 versions, known good)
// ---------------------------------------------------------------------------
__global__ __launch_bounds__(256) void k_cvt_bf16(const float* __restrict__ in,
                                                  unsigned short* __restrict__ out,
                                                  int n) {
  int i = blockIdx.x * 256 + threadIdx.x;
  if (i < n) out[i] = (unsigned short)f2bf(in[i]);
}

// W_emb^T only (K=IN_DIM)
__global__ __launch_bounds__(256) void k_transpose_cvt(const float* __restrict__ in,
                                                       unsigned short* __restrict__ out,
                                                       int K, int N) {
  __shared__ float tile[32][33];
  int k0 = blockIdx.x * 32, n0 = blockIdx.y * 32;
  int tx = threadIdx.x & 31, ty = threadIdx.x >> 5;  // 32 x 8
#pragma unroll
  for (int i = 0; i < 4; ++i)
    tile[ty + 8 * i][tx] = in[(size_t)(k0 + ty + 8 * i) * N + n0 + tx];
  __syncthreads();
#pragma unroll
  for (int i = 0; i < 4; ++i)
    out[(size_t)(n0 + ty + 8 * i) * K + k0 + tx] =
        (unsigned short)f2bf(tile[tx][ty + 8 * i]);
}

// all 32 DIMxDIM cell weights in one launch, coef-prescaled (reads wsoft).
__global__ __launch_bounds__(256) void k_transpose_cvt32(const float* __restrict__ Wfd,
                                                         const float* __restrict__ Wfs,
                                                         const float* __restrict__ Wld,
                                                         const float* __restrict__ Wls,
                                                         const float* __restrict__ wsoft,
                                                         unsigned short* __restrict__ out) {
  __shared__ float tile[32][33];
  int z = blockIdx.z;
  const float* in;
  float coef;
  const float* wf = wsoft;
  const float* wl = wsoft + 40;
  if (z < 6)       { in = Wfd + (size_t)z * DIM * DIM;        coef = wf[z * 4 + 2]; }
  else if (z < 12) { in = Wfs + (size_t)(z - 6) * DIM * DIM;  coef = wf[(z - 6) * 4 + 3]; }
  else if (z < 22) { in = Wld + (size_t)(z - 12) * DIM * DIM; coef = wl[(z - 12) * 4 + 2]; }
  else             { in = Wls + (size_t)(z - 22) * DIM * DIM; coef = wl[(z - 22) * 4 + 3]; }
  unsigned short* o = out + (size_t)z * DIM * DIM;
  int k0 = blockIdx.x * 32, n0 = blockIdx.y * 32;
  int tx = threadIdx.x & 31, ty = threadIdx.x >> 5;
#pragma unroll
  for (int i = 0; i < 4; ++i)
    tile[ty + 8 * i][tx] = in[(size_t)(k0 + ty + 8 * i) * DIM + n0 + tx];
  __syncthreads();
#pragma unroll
  for (int i = 0; i < 4; ++i)
    o[(size_t)(n0 + ty + 8 * i) * DIM + k0 + tx] =
        (unsigned short)f2bf(coef * tile[tx][ty + 8 * i]);
}

// ---------------------------------------------------------------------------
// Segment reductions (bf16). One wave per node, 4 nodes/block, 8-edge unroll.
// ---------------------------------------------------------------------------
#define SEG_ACC(u) \
  { s0 += bf2f((u).x & 0xffffu); s1 += bf2f((u).x >> 16); \
    s2 += bf2f((u).y & 0xffffu); s3 += bf2f((u).y >> 16); }

#define MID_ACC(u) \
  { float v0 = bf2f((u).x & 0xffffu), v1 = bf2f((u).x >> 16); \
    float v2 = bf2f((u).y & 0xffffu), v3 = bf2f((u).y >> 16); \
    s0 += v0; s1 += v1; s2 += v2; s3 += v3; \
    m0 = fmaxf(m0, v0); m1 = fmaxf(m1, v1); \
    m2 = fmaxf(m2, v2); m3 = fmaxf(m3, v3); }

__global__ __launch_bounds__(256) void k_segmean_bf(const unsigned short* __restrict__ X,
                                                    const int* __restrict__ row_ofs,
                                                    const int* __restrict__ csr_src,
                                                    const float* __restrict__ invdeg,
                                                    unsigned short* __restrict__ out) {
  int node = blockIdx.x * 4 + (threadIdx.x >> 6);
  int l = threadIdx.x & 63;
  if (node >= N_NODES) return;
  int beg = row_ofs[node], end = row_ofs[node + 1];
  float s0 = 0.f, s1 = 0.f, s2 = 0.f, s3 = 0.f;
  int e = beg;
  for (; e + 8 <= end; e += 8) {
    int i0 = csr_src[e], i1 = csr_src[e + 1], i2 = csr_src[e + 2], i3 = csr_src[e + 3];
    int i4 = csr_src[e + 4], i5 = csr_src[e + 5], i6 = csr_src[e + 6], i7 = csr_src[e + 7];
    uint2 u0 = *(const uint2*)&X[(size_t)i0 * DIM + 4 * l];
    uint2 u1 = *(const uint2*)&X[(size_t)i1 * DIM + 4 * l];
    uint2 u2 = *(const uint2*)&X[(size_t)i2 * DIM + 4 * l];
    uint2 u3 = *(const uint2*)&X[(size_t)i3 * DIM + 4 * l];
    uint2 u4 = *(const uint2*)&X[(size_t)i4 * DIM + 4 * l];
    uint2 u5 = *(const uint2*)&X[(size_t)i5 * DIM + 4 * l];
    uint2 u6 = *(const uint2*)&X[(size_t)i6 * DIM + 4 * l];
    uint2 u7 = *(const uint2*)&X[(size_t)i7 * DIM + 4 * l];
    SEG_ACC(u0) SEG_ACC(u1) SEG_ACC(u2) SEG_ACC(u3)
    SEG_ACC(u4) SEG_ACC(u5) SEG_ACC(u6) SEG_ACC(u7)
  }
  for (; e + 4 <= end; e += 4) {
    int i0 = csr_src[e], i1 = csr_src[e + 1], i2 = csr_src[e + 2], i3 = csr_src[e + 3];
    uint2 u0 = *(const uint2*)&X[(size_t)i0 * DIM + 4 * l];
    uint2 u1 = *(const uint2*)&X[(size_t)i1 * DIM + 4 * l];
    uint2 u2 = *(const uint2*)&X[(size_t)i2 * DIM + 4 * l];
    uint2 u3 = *(const uint2*)&X[(size_t)i3 * DIM + 4 * l];
    SEG_ACC(u0) SEG_ACC(u1) SEG_ACC(u2) SEG_ACC(u3)
  }
  for (; e < end; ++e) {
    uint2 u = *(const uint2*)&X[(size_t)csr_src[e] * DIM + 4 * l];
    SEG_ACC(u)
  }
  float iv = invdeg[node];
  uint2 o;
  o.x = f2bf(s0 * iv) | (f2bf(s1 * iv) << 16);
  o.y = f2bf(s2 * iv) | (f2bf(s3 * iv) << 16);
  *(uint2*)&out[(size_t)node * DIM + 4 * l] = o;
}

__global__ __launch_bounds__(256) void k_segmean2_bf(const unsigned short* __restrict__ X0,
                                                     const unsigned short* __restrict__ X1,
                                                     const int* __restrict__ row_ofs,
                                                     const int* __restrict__ csr_src,
                                                     const float* __restrict__ invdeg,
                                                     unsigned short* __restrict__ out0,
                                                     unsigned short* __restrict__ out1) {
  int node = blockIdx.x * 4 + (threadIdx.x >> 6);
  int l = threadIdx.x & 63;
  if (node >= N_NODES) return;
  int beg = row_ofs[node], end = row_ofs[node + 1];
  float a0 = 0.f, a1 = 0.f, a2 = 0.f, a3 = 0.f;
  float b0 = 0.f, b1 = 0.f, b2 = 0.f, b3 = 0.f;
  int e = beg;
  for (; e + 4 <= end; e += 4) {
    size_t r0 = (size_t)csr_src[e] * DIM + 4 * l;
    size_t r1 = (size_t)csr_src[e + 1] * DIM + 4 * l;
    size_t r2 = (size_t)csr_src[e + 2] * DIM + 4 * l;
    size_t r3 = (size_t)csr_src[e + 3] * DIM + 4 * l;
    uint2 u0 = *(const uint2*)&X0[r0];
    uint2 u1 = *(const uint2*)&X0[r1];
    uint2 u2 = *(const uint2*)&X0[r2];
    uint2 u3 = *(const uint2*)&X0[r3];
    uint2 v0 = *(const uint2*)&X1[r0];
    uint2 v1 = *(const uint2*)&X1[r1];
    uint2 v2 = *(const uint2*)&X1[r2];
    uint2 v3 = *(const uint2*)&X1[r3];
    a0 += bf2f(u0.x & 0xffffu) + bf2f(u1.x & 0xffffu) + bf2f(u2.x & 0xffffu) + bf2f(u3.x & 0xffffu);
    a1 += bf2f(u0.x >> 16) + bf2f(u1.x >> 16) + bf2f(u2.x >> 16) + bf2f(u3.x >> 16);
    a2 += bf2f(u0.y & 0xffffu) + bf2f(u1.y & 0xffffu) + bf2f(u2.y & 0xffffu) + bf2f(u3.y & 0xffffu);
    a3 += bf2f(u0.y >> 16) + bf2f(u1.y >> 16) + bf2f(u2.y >> 16) + bf2f(u3.y >> 16);
    b0 += bf2f(v0.x & 0xffffu) + bf2f(v1.x & 0xffffu) + bf2f(v2.x & 0xffffu) + bf2f(v3.x & 0xffffu);
    b1 += bf2f(v0.x >> 16) + bf2f(v1.x >> 16) + bf2f(v2.x >> 16) + bf2f(v3.x >> 16);
    b2 += bf2f(v0.y & 0xffffu) + bf2f(v1.y & 0xffffu) + bf2f(v2.y & 0xffffu) + bf2f(v3.y & 0xffffu);
    b3 += bf2f(v0.y >> 16) + bf2f(v1.y >> 16) + bf2f(v2.y >> 16) + bf2f(v3.y >> 16);
  }
  for (; e < end; ++e) {
    size_t rb = (size_t)csr_src[e] * DIM + 4 * l;
    uint2 u = *(const uint2*)&X0[rb];
    uint2 v = *(const uint2*)&X1[rb];
    a0 += bf2f(u.x & 0xffffu); a1 += bf2f(u.x >> 16);
    a2 += bf2f(u.y & 0xffffu); a3 += bf2f(u.y >> 16);
    b0 += bf2f(v.x & 0xffffu); b1 += bf2f(v.x >> 16);
    b2 += bf2f(v.y & 0xffffu); b3 += bf2f(v.y >> 16);
  }
  float iv = invdeg[node];
  uint2 o;
  o.x = f2bf(a0 * iv) | (f2bf(a1 * iv) << 16);
  o.y = f2bf(a2 * iv) | (f2bf(a3 * iv) << 16);
  *(uint2*)&out0[(size_t)node * DIM + 4 * l] = o;
  o.x = f2bf(b0 * iv) | (f2bf(b1 * iv) << 16);
  o.y = f2bf(b2 * iv) | (f2bf(b3 * iv) << 16);
  *(uint2*)&out1[(size_t)node * DIM + 4 * l] = o;
}

// sum+max over incoming msgs of relu'd input; epilogue = middle-stage mixture.
__global__ __launch_bounds__(256) void k_segmid_bf(const unsigned short* __restrict__ Xn,
                                                   const int* __restrict__ row_ofs,
                                                   const int* __restrict__ csr_src,
                                                   const float* __restrict__ invdeg,
                                                   const float* __restrict__ wrow,
                                                   unsigned short* __restrict__ mean_out,
                                                   unsigned short* __restrict__ mids_out) {
  int node = blockIdx.x * 4 + (threadIdx.x >> 6);
  int l = threadIdx.x & 63;
  if (node >= N_NODES) return;
  int beg = row_ofs[node], end = row_ofs[node + 1];
  float s0 = 0.f, s1 = 0.f, s2 = 0.f, s3 = 0.f;
  float m0 = 0.f, m1 = 0.f, m2 = 0.f, m3 = 0.f;  // inputs >= 0 (relu)
  int e = beg;
  for (; e + 8 <= end; e += 8) {
    int i0 = csr_src[e], i1 = csr_src[e + 1], i2 = csr_src[e + 2], i3 = csr_src[e + 3];
    int i4 = csr_src[e + 4], i5 = csr_src[e + 5], i6 = csr_src[e + 6], i7 = csr_src[e + 7];
    uint2 u0 = *(const uint2*)&Xn[(size_t)i0 * DIM + 4 * l];
    uint2 u1 = *(const uint2*)&Xn[(size_t)i1 * DIM + 4 * l];
    uint2 u2 = *(const uint2*)&Xn[(size_t)i2 * DIM + 4 * l];
    uint2 u3 = *(const uint2*)&Xn[(size_t)i3 * DIM + 4 * l];
    uint2 u4 = *(const uint2*)&Xn[(size_t)i4 * DIM + 4 * l];
    uint2 u5 = *(const uint2*)&Xn[(size_t)i5 * DIM + 4 * l];
    uint2 u6 = *(const uint2*)&Xn[(size_t)i6 * DIM + 4 * l];
    uint2 u7 = *(const uint2*)&Xn[(size_t)i7 * DIM + 4 * l];
    MID_ACC(u0) MID_ACC(u1) MID_ACC(u2) MID_ACC(u3)
    MID_ACC(u4) MID_ACC(u5) MID_ACC(u6) MID_ACC(u7)
  }
  for (; e + 4 <= end; e += 4) {
    int i0 = csr_src[e], i1 = csr_src[e + 1], i2 = csr_src[e + 2], i3 = csr_src[e + 3];
    uint2 u0 = *(const uint2*)&Xn[(size_t)i0 * DIM + 4 * l];
    uint2 u1 = *(const uint2*)&Xn[(size_t)i1 * DIM + 4 * l];
    uint2 u2 = *(const uint2*)&Xn[(size_t)i2 * DIM + 4 * l];
    uint2 u3 = *(const uint2*)&Xn[(size_t)i3 * DIM + 4 * l];
    MID_ACC(u0) MID_ACC(u1) MID_ACC(u2) MID_ACC(u3)
  }
  for (; e < end; ++e) {
    uint2 u = *(const uint2*)&Xn[(size_t)csr_src[e] * DIM + 4 * l];
    MID_ACC(u)
  }
  float iv = invdeg[node];
  float e0 = s0 * iv, e1 = s1 * iv, e2 = s2 * iv, e3 = s3 * iv;
  if (mean_out) {
    uint2 o;
    o.x = f2bf(e0) | (f2bf(e1) << 16);
    o.y = f2bf(e2) | (f2bf(e3) << 16);
    *(uint2*)&mean_out[(size_t)node * DIM + 4 * l] = o;
  }
  float w0 = wrow[0], w1 = wrow[1], w2 = wrow[2], w3 = wrow[3];
  uint2 xu = *(const uint2*)&Xn[(size_t)node * DIM + 4 * l];
  float x0 = bf2f(xu.x & 0xffffu), x1 = bf2f(xu.x >> 16);
  float x2 = bf2f(xu.y & 0xffffu), x3 = bf2f(xu.y >> 16);
  uint2 o;
  o.x = f2bf(w0 * x0 + w1 * m0 + w2 * e0 + w3 * s0) |
        (f2bf(w0 * x1 + w1 * m1 + w2 * e1 + w3 * s1) << 16);
  o.y = f2bf(w0 * x2 + w1 * m2 + w2 * e2 + w3 * s2) |
        (f2bf(w0 * x3 + w1 * m3 + w2 * e3 + w3 * s3) << 16);
  *(uint2*)&mids_out[(size_t)node * DIM + 4 * l] = o;
}

// ---------------------------------------------------------------------------
// Wide MFMA multi-term GEMM with per-column-half epilogues (N = 256*nhalves).
// ---------------------------------------------------------------------------
struct GemmDescW {
  const unsigned short* A[4];
  const unsigned short* W[2][4];
  const float* b[2][4];
  const float* c[2][4];
  const unsigned short* I[2];
  const float* ic[2][2];
  const float* pre[2];            // f32 pre-accumulated partial
  const float* resid[2];
  const unsigned short* addl[2];
  float* out_f32[2];
  unsigned short* out_bf[2];
  int nmat, nid, K, relu[2], colshift;
};

__global__ __launch_bounds__(256) void k_gemm_mfma(GemmDescW d) {
  __shared__ __align__(16) unsigned short As[2][64][72];
  __shared__ __align__(16) unsigned short Bs[2][64][72];
  const int tid = threadIdx.x;
  const int b = blockIdx.x;
  const int cs = d.colshift;
  const int c = (b >> 3) & ((1 << cs) - 1);
  const int bm = ((b & 7) + 8 * (b >> (3 + cs))) * 64;
  const int half = c >> 2;
  const int bn = (c & 3) * 64;
  const int w = tid >> 6, l = tid & 63;
  const int wm = (w >> 1) * 32, wn = (w & 1) * 32;
  const int lr = l & 15, lk = (l >> 4) * 8;
  const int ldr = tid >> 3, ldk = (tid & 7) * 8;

  const int K = d.K;
  const int kds = (K == 256) ? 2 : 1;
  const int kmask = (1 << kds) - 1;
  const int nsteps = d.nmat << kds;

  f32x4 zero = {0.f, 0.f, 0.f, 0.f};
  f32x4 acc[2][2];
  acc[0][0] = zero; acc[0][1] = zero; acc[1][0] = zero; acc[1][1] = zero;

  auto gload = [&](int s, uint4& a0, uint4& a1, uint4& b0, uint4& b1) {
    int t = s >> kds;
    int k0 = (s & kmask) << 6;
    const unsigned short* __restrict__ A = d.A[t];
    const unsigned short* __restrict__ W = d.W[half][t];
    a0 = *(const uint4*)&A[(size_t)(bm + ldr) * K + k0 + ldk];
    a1 = *(const uint4*)&A[(size_t)(bm + ldr + 32) * K + k0 + ldk];
    b0 = *(const uint4*)&W[(size_t)(bn + ldr) * K + k0 + ldk];
    b1 = *(const uint4*)&W[(size_t)(bn + ldr + 32) * K + k0 + ldk];
  };

  {
    uint4 a0, a1, b0, b1;
    gload(0, a0, a1, b0, b1);
    *(uint4*)&As[0][ldr][ldk] = a0;
    *(uint4*)&As[0][ldr + 32][ldk] = a1;
    *(uint4*)&Bs[0][ldr][ldk] = b0;
    *(uint4*)&Bs[0][ldr + 32][ldk] = b1;
  }
  __syncthreads();

  int buf = 0;
  for (int s = 0; s < nsteps; ++s) {
    uint4 na0, na1, nb0, nb1;
    const bool more = (s + 1 < nsteps);
    if (more) gload(s + 1, na0, na1, nb0, nb1);
#pragma unroll
    for (int ks = 0; ks < 2; ++ks) {
      bf16x8 a0 = *(const bf16x8*)&As[buf][wm + lr][ks * 32 + lk];
      bf16x8 a1 = *(const bf16x8*)&As[buf][wm + 16 + lr][ks * 32 + lk];
      bf16x8 b0 = *(const bf16x8*)&Bs[buf][wn + lr][ks * 32 + lk];
      bf16x8 b1 = *(const bf16x8*)&Bs[buf][wn + 16 + lr][ks * 32 + lk];
      acc[0][0] = __builtin_amdgcn_mfma_f32_16x16x32_bf16(a0, b0, acc[0][0], 0, 0, 0);
      acc[0][1] = __builtin_amdgcn_mfma_f32_16x16x32_bf16(a0, b1, acc[0][1], 0, 0, 0);
      acc[1][0] = __builtin_amdgcn_mfma_f32_16x16x32_bf16(a1, b0, acc[1][0], 0, 0, 0);
      acc[1][1] = __builtin_amdgcn_mfma_f32_16x16x32_bf16(a1, b1, acc[1][1], 0, 0, 0);
    }
    if (more) {
      *(uint4*)&As[buf ^ 1][ldr][ldk] = na0;
      *(uint4*)&As[buf ^ 1][ldr + 32][ldk] = na1;
      *(uint4*)&Bs[buf ^ 1][ldr][ldk] = nb0;
      *(uint4*)&Bs[buf ^ 1][ldr + 32][ldk] = nb1;
    }
    __syncthreads();
    buf ^= 1;
  }

  // epilogue (per half)
  float bias[2] = {0.f, 0.f};
  for (int t = 0; t < d.nmat; ++t) {
    const float* bp = d.b[half][t];
    if (bp) {
      float cc = d.c[half][t] ? *d.c[half][t] : 1.0f;
      bias[0] += cc * bp[bn + wn + lr];
      bias[1] += cc * bp[bn + wn + 16 + lr];
    }
  }
  float vout[2][2][4];
#pragma unroll
  for (int m = 0; m < 2; ++m)
#pragma unroll
    for (int n = 0; n < 2; ++n)
#pragma unroll
      for (int i = 0; i < 4; ++i) vout[m][n][i] = acc[m][n][i] + bias[n];
#pragma unroll
  for (int u = 0; u < 2; ++u) {
    if (u < d.nid) {
      float icu = *d.ic[half][u];
      const unsigned short* __restrict__ I = d.I[u];
#pragma unroll
      for (int m = 0; m < 2; ++m)
#pragma unroll
        for (int n = 0; n < 2; ++n)
#pragma unroll
          for (int i = 0; i < 4; ++i) {
            int row = bm + wm + m * 16 + (l >> 4) * 4 + i;
            int col = bn + wn + n * 16 + lr;
            vout[m][n][i] += icu * bf2f(I[(size_t)row * DIM + col]);
          }
    }
  }
  const float* pre = d.pre[half];
  const float* resid = d.resid[half];
  const unsigned short* addl = d.addl[half];
  unsigned short* obf = d.out_bf[half];
  float* of32 = d.out_f32[half];
  const int do_relu = d.relu[half];
#pragma unroll
  for (int m = 0; m < 2; ++m)
#pragma unroll
    for (int n = 0; n < 2; ++n)
#pragma unroll
      for (int i = 0; i < 4; ++i) {
        int row = bm + wm + m * 16 + (l >> 4) * 4 + i;
        int col = bn + wn + n * 16 + lr;
        size_t idx = (size_t)row * DIM + col;
        float v = vout[m][n][i];
        if (pre) v += pre[idx];
        if (do_relu) v = fmaxf(v, 0.f);
        if (resid) v = resid[idx] + 0.5f * (bf2f(addl[idx]) + v);
        if (obf) obf[idx] = (unsigned short)f2bf(v);
        if (of32) of32[idx] = v;
      }
}

// ---------------------------------------------------------------------------
// Fused readout + MLP with 8-way ILP on the node-sum loop.
// ---------------------------------------------------------------------------
__global__ __launch_bounds__(256) void k_readout_mlp(const float* __restrict__ x,
                                                     const int* __restrict__ gid,
                                                     const float* __restrict__ C1,
                                                     const float* __restrict__ c1b,
                                                     const float* __restrict__ C2,
                                                     const float* __restrict__ c2b,
                                                     const float* __restrict__ C3,
                                                     const float* __restrict__ c3b,
                                                     float* __restrict__ out) {
  int g = blockIdx.x, t = threadIdx.x;
  int lo = 0, hi = N_NODES;
  while (lo < hi) { int m = (lo + hi) >> 1; if (gid[m] < g) lo = m + 1; else hi = m; }
  int beg = lo;
  lo = beg; hi = N_NODES;
  while (lo < hi) { int m = (lo + hi) >> 1; if (gid[m] <= g) lo = m + 1; else hi = m; }
  int end = lo;
  // 8 independent accumulators: 8 loads in flight per thread
  float s0 = 0.f, s1 = 0.f, s2 = 0.f, s3 = 0.f;
  float s4 = 0.f, s5 = 0.f, s6 = 0.f, s7 = 0.f;
  int i = beg;
  for (; i + 8 <= end; i += 8) {
    s0 += x[(size_t)(i + 0) * DIM + t];
    s1 += x[(size_t)(i + 1) * DIM + t];
    s2 += x[(size_t)(i + 2) * DIM + t];
    s3 += x[(size_t)(i + 3) * DIM + t];
    s4 += x[(size_t)(i + 4) * DIM + t];
    s5 += x[(size_t)(i + 5) * DIM + t];
    s6 += x[(size_t)(i + 6) * DIM + t];
    s7 += x[(size_t)(i + 7) * DIM + t];
  }
  for (; i < end; ++i) s0 += x[(size_t)i * DIM + t];
  float s = ((s0 + s1) + (s2 + s3)) + ((s4 + s5) + (s6 + s7));
  int cnt = end - beg;
  __shared__ float h0[256], h1[128], h2[64];
  h0[t] = s / (float)(cnt > 1 ? cnt : 1);
  __syncthreads();
  if (t < 128) {
    float v = c1b[t];
    for (int k = 0; k < 256; ++k) v = fmaf(h0[k], C1[k * 128 + t], v);
    h1[t] = fmaxf(v, 0.f);
  }
  __syncthreads();
  if (t < 64) {
    float v = c2b[t];
    for (int k = 0; k < 128; ++k) v = fmaf(h1[k], C2[k * 64 + t], v);
    h2[t] = fmaxf(v, 0.f);
  }
  __syncthreads();
  if (t < 10) {
    float v = c3b[t];
    for (int k = 0; k < 64; ++k) v = fmaf(h2[k], C3[k * 10 + t], v);
    out[g * 10 + t] = v;
  }
}

// ---------------------------------------------------------------------------
extern "C" void kernel_launch(void* const* d_in, const int* in_sizes, int n_in,
                              void* d_out, int out_size, void* d_ws, size_t ws_size,
                              hipStream_t stream) {
  const float* h     = (const float*)d_in[0];
  const float* W_emb = (const float*)d_in[1];
  const float* b_emb = (const float*)d_in[2];
  const float* Wf_d  = (const float*)d_in[3];
  const float* bf_d  = (const float*)d_in[4];
  const float* Wf_s  = (const float*)d_in[5];
  const float* bf_s  = (const float*)d_in[6];
  const float* Wl_d  = (const float*)d_in[7];
  const float* bl_d  = (const float*)d_in[8];
  const float* Wl_s  = (const float*)d_in[9];
  const float* bl_s  = (const float*)d_in[10];
  const float* a_first = (const float*)d_in[11];
  const float* a_mid   = (const float*)d_in[12];
  const float* a_last  = (const float*)d_in[13];
  const float* C1 = (const float*)d_in[14];
  const float* c1b = (const float*)d_in[15];
  const float* C2 = (const float*)d_in[16];
  const float* c2b = (const float*)d_in[17];
  const float* C3 = (const float*)d_in[18];
  const float* c3b = (const float*)d_in[19];
  const int* src = (const int*)d_in[20];
  const int* dst = (const int*)d_in[21];
  const int* gid = (const int*)d_in[22];
  (void)in_sizes; (void)n_in; (void)out_size; (void)ws_size;

  char* p = (char*)d_ws;
  auto alloc = [&](size_t bytes) {
    void* r = (void*)p;
    p += (bytes + 255) & ~(size_t)255;
    return r;
  };
  typedef unsigned short u16;
  const size_t NBF = (size_t)M_PAD * DIM * sizeof(u16);
  float* x_f32  = (float*)alloc((size_t)M_PAD * DIM * sizeof(float));
  float* s2part = (float*)alloc((size_t)M_PAD * DIM * sizeof(float));
  float* xpart  = (float*)alloc((size_t)M_PAD * DIM * sizeof(float));
  u16* xb    = (u16*)alloc(NBF);
  u16* s1b   = (u16*)alloc(NBF);
  u16* s2b   = (u16*)alloc(NBF);
  u16* m0b   = (u16*)alloc(NBF);
  u16* m1b   = (u16*)alloc(NBF);
  u16* l0b   = (u16*)alloc(NBF);
  u16* aggAb = (u16*)alloc(NBF);
  u16* aggBb = (u16*)alloc(NBF);
  u16* h_bf  = (u16*)alloc((size_t)M_PAD * IN_DIM * sizeof(u16));
  u16* WT    = (u16*)alloc((size_t)(DIM * IN_DIM + 32 * DIM * DIM) * sizeof(u16));
  u16* WTe   = WT;
  u16* WTfd  = WT + DIM * IN_DIM;
  u16* WTfs  = WTfd + 6 * DIM * DIM;
  u16* WTld  = WTfs + 6 * DIM * DIM;
  u16* WTls  = WTld + 10 * DIM * DIM;
  float* invdeg = (float*)alloc(N_NODES * sizeof(float));
  int* counts  = (int*)alloc(N_NODES * sizeof(int));
  int* row_ofs = (int*)alloc((N_NODES + 1) * sizeof(int));
  int* cursor  = (int*)alloc(N_NODES * sizeof(int));
  int* csr_src = (int*)alloc(N_EDGES * sizeof(int));
  float* wsoft = (float*)alloc(80 * sizeof(float));

  const int EB = (N_EDGES + 255) / 256;

  // round-6 prep path (known good)
  k_init<<<192, 256, 0, stream>>>(
      counts, h_bf + (size_t)N_NODES * IN_DIM,
      aggAb + (size_t)N_NODES * DIM, aggBb + (size_t)N_NODES * DIM,
      m0b + (size_t)N_NODES * DIM, m1b + (size_t)N_NODES * DIM);

  k_count<<<EB, 256, 0, stream>>>(dst, counts);
  k_scan<<<1, 256, 0, stream>>>(counts, row_ofs, cursor, invdeg);
  k_fill<<<EB, 256, 0, stream>>>(src, dst, cursor, csr_src);
  k_softmax<<<1, 64, 0, stream>>>(a_first, a_mid, a_last, wsoft);

  const float* wf = wsoft;
  const float* wm = wsoft + 24;
  const float* wl = wsoft + 40;

  k_cvt_bf16<<<(N_NODES * IN_DIM + 255) / 256, 256, 0, stream>>>(h, h_bf, N_NODES * IN_DIM);
  k_transpose_cvt<<<dim3(IN_DIM / 32, DIM / 32, 1), 256, 0, stream>>>(W_emb, WTe, IN_DIM, DIM);
  k_transpose_cvt32<<<dim3(8, 8, 32), 256, 0, stream>>>(Wf_d, Wf_s, Wl_d, Wl_s, wsoft, WTfd);

  const int GG1 = (M_PAD / 64) * 4;  // 512 blocks (N=256)
  const int GG2 = (M_PAD / 64) * 8;  // 1024 blocks (N=512)
  const int SB = (N_NODES + 3) / 4;

  // embedding: x = h @ W_emb + b_emb
  {
    GemmDescW d{};
    d.A[0] = h_bf; d.W[0][0] = WTe; d.b[0][0] = b_emb;
    d.nmat = 1; d.nid = 0; d.K = IN_DIM; d.colshift = 2;
    d.out_f32[0] = x_f32; d.out_bf[0] = xb;
    k_gemm_mfma<<<GG1, 256, 0, stream>>>(d);
  }

  for (int l = 0; l < 2; ++l) {
    auto WFD = [&](int e) { return WTfd + (size_t)(l * 3 + e) * DIM * DIM; };
    auto BFD = [&](int e) { return bf_d + (size_t)(l * 3 + e) * DIM; };
    auto WFS = [&](int e) { return WTfs + (size_t)(l * 3 + e) * DIM * DIM; };
    auto BFS = [&](int e) { return bf_s + (size_t)(l * 3 + e) * DIM; };
    auto WLD = [&](int e) { return WTld + (size_t)(l * 5 + e) * DIM * DIM; };
    auto BLD = [&](int e) { return bl_d + (size_t)(l * 5 + e) * DIM; };
    auto WLS = [&](int e) { return WTls + (size_t)(l * 5 + e) * DIM * DIM; };
    auto BLS = [&](int e) { return bl_s + (size_t)(l * 5 + e) * DIM; };
    auto WFrow = [&](int e) { return wf + (l * 3 + e) * 4; };
    auto WMrow = [&](int n) { return wm + (l * 2 + n) * 4; };
    auto WLrow = [&](int e) { return wl + (l * 5 + e) * 4; };

    // aggA = mean-agg(x)
    k_segmean_bf<<<SB, 256, 0, stream>>>(xb, row_ofs, csr_src, invdeg, aggAb);

    // G1 (wide): half0 -> s1 = relu(mixed(x,e0)); half1 -> s2part = mixed(x,e1) (f32)
    {
      GemmDescW d{};
      d.A[0] = xb; d.A[1] = aggAb; d.nmat = 2; d.K = DIM; d.colshift = 3;
      d.I[0] = xb; d.nid = 1;
      d.W[0][0] = WFD(0); d.b[0][0] = BFD(0); d.c[0][0] = WFrow(0) + 2;
      d.W[0][1] = WFS(0); d.b[0][1] = BFS(0); d.c[0][1] = WFrow(0) + 3;
      d.ic[0][0] = WFrow(0) + 1; d.relu[0] = 1; d.out_bf[0] = s1b;
      d.W[1][0] = WFD(1); d.b[1][0] = BFD(1); d.c[1][0] = WFrow(1) + 2;
      d.W[1][1] = WFS(1); d.b[1][1] = BFS(1); d.c[1][1] = WFrow(1) + 3;
      d.ic[1][0] = WFrow(1) + 1; d.relu[1] = 0; d.out_f32[1] = s2part;
      k_gemm_mfma<<<GG2, 256, 0, stream>>>(d);
    }

    // mid of s1: mean -> aggB; mixture -> m0
    k_segmid_bf<<<SB, 256, 0, stream>>>(s1b, row_ofs, csr_src, invdeg, WMrow(0), aggBb, m0b);

    // G2: s2 = relu(s2part + mixed(s1,e2))
    {
      GemmDescW d{};
      d.A[0] = s1b; d.A[1] = aggBb; d.nmat = 2; d.K = DIM; d.colshift = 2;
      d.I[0] = s1b; d.nid = 1;
      d.W[0][0] = WFD(2); d.b[0][0] = BFD(2); d.c[0][0] = WFrow(2) + 2;
      d.W[0][1] = WFS(2); d.b[0][1] = BFS(2); d.c[0][1] = WFrow(2) + 3;
      d.ic[0][0] = WFrow(2) + 1; d.pre[0] = s2part; d.relu[0] = 1; d.out_bf[0] = s2b;
      k_gemm_mfma<<<GG1, 256, 0, stream>>>(d);
    }

    // mid of s2 -> m1
    k_segmid_bf<<<SB, 256, 0, stream>>>(s2b, row_ofs, csr_src, invdeg, WMrow(1), nullptr, m1b);

    // mean-aggs of m0, m1
    k_segmean2_bf<<<SB, 256, 0, stream>>>(m0b, m1b, row_ofs, csr_src, invdeg, aggAb, aggBb);

    // G3 (wide): half0 -> l0 = relu(mixed(m0,e0)+mixed(m1,e1));
    //            half1 -> xpart = mixed(m0,e2)+mixed(m1,e3) (f32)
    {
      GemmDescW d{};
      d.A[0] = m0b; d.A[1] = aggAb; d.A[2] = m1b; d.A[3] = aggBb;
      d.nmat = 4; d.K = DIM; d.colshift = 3;
      d.I[0] = m0b; d.I[1] = m1b; d.nid = 2;
      d.W[0][0] = WLD(0); d.b[0][0] = BLD(0); d.c[0][0] = WLrow(0) + 2;
      d.W[0][1] = WLS(0); d.b[0][1] = BLS(0); d.c[0][1] = WLrow(0) + 3;
      d.W[0][2] = WLD(1); d.b[0][2] = BLD(1); d.c[0][2] = WLrow(1) + 2;
      d.W[0][3] = WLS(1); d.b[0][3] = BLS(1); d.c[0][3] = WLrow(1) + 3;
      d.ic[0][0] = WLrow(0) + 1; d.ic[0][1] = WLrow(1) + 1;
      d.relu[0] = 1; d.out_bf[0] = l0b;
      d.W[1][0] = WLD(2); d.b[1][0] = BLD(2); d.c[1][0] = WLrow(2) + 2;
      d.W[1][1] = WLS(2); d.b[1][1] = BLS(2); d.c[1][1] = WLrow(2) + 3;
      d.W[1][2] = WLD(3); d.b[1][2] = BLD(3); d.c[1][2] = WLrow(3) + 2;
      d.W[1][3] = WLS(3); d.b[1][3] = BLS(3); d.c[1][3] = WLrow(3) + 3;
      d.ic[1][0] = WLrow(2) + 1; d.ic[1][1] = WLrow(3) + 1;
      d.relu[1] = 0; d.out_f32[1] = xpart;
      k_gemm_mfma<<<GG2, 256, 0, stream>>>(d);
    }

    // mean-agg of l0 -> s1b (dead)
    k_segmean_bf<<<SB, 256, 0, stream>>>(l0b, row_ofs, csr_src, invdeg, s1b);

    // G4: x = x + 0.5*(l0 + relu(xpart + mixed(l0,e4)))
    {
      GemmDescW d{};
      d.A[0] = l0b; d.A[1] = s1b; d.nmat = 2; d.K = DIM; d.colshift = 2;
      d.I[0] = l0b; d.nid = 1;
      d.W[0][0] = WLD(4); d.b[0][0] = BLD(4); d.c[0][0] = WLrow(4) + 2;
      d.W[0][1] = WLS(4); d.b[0][1] = BLS(4); d.c[0][1] = WLrow(4) + 3;
      d.ic[0][0] = WLrow(4) + 1; d.pre[0] = xpart; d.relu[0] = 1;
      d.resid[0] = x_f32; d.addl[0] = l0b;
      d.out_f32[0] = x_f32; d.out_bf[0] = xb;
      k_gemm_mfma<<<GG1, 256, 0, stream>>>(d);
    }
  }

  k_readout_mlp<<<N_GRAPHS, 256, 0, stream>>>(x_f32, gid, C1, c1b, C2, c2b, C3, c3b,
                                              (float*)d_out);
}

// Round 11
// 324.582 us; speedup vs baseline: 3.2290x; 1.0073x over previous
//
#include <hip/hip_runtime.h>

#define N_NODES   8000
#define M_PAD     8192
#define PADR      (M_PAD - N_NODES)
#define N_EDGES   128000
#define N_GRAPHS  64
#define DIM       256
#define IN_DIM    128

typedef short bf16x8 __attribute__((ext_vector_type(8)));
typedef float f32x4 __attribute__((ext_vector_type(4)));

static __device__ __forceinline__ float bf2f(unsigned v) {
  return __uint_as_float(v << 16);
}
static __device__ __forceinline__ unsigned f2bf(float f) {
  unsigned u = __float_as_uint(f);
  return (u + 0x7fffu + ((u >> 16) & 1u)) >> 16;
}

// ---------------------------------------------------------------------------
// init: zero counts + pad rows (round-6 version, known good)
// ---------------------------------------------------------------------------
__global__ __launch_bounds__(256) void k_init(int* __restrict__ counts,
                                              unsigned short* __restrict__ hpad,
                                              unsigned short* __restrict__ p0,
                                              unsigned short* __restrict__ p1,
                                              unsigned short* __restrict__ p2,
                                              unsigned short* __restrict__ p3) {
  int i = blockIdx.x * 256 + threadIdx.x;
  if (i < N_NODES) counts[i] = 0;
  if (i < PADR * IN_DIM) hpad[i] = 0;
  if (i < PADR * DIM) { p0[i] = 0; p1[i] = 0; p2[i] = 0; p3[i] = 0; }
}

// ---------------------------------------------------------------------------
// CSR build
// ---------------------------------------------------------------------------
__global__ __launch_bounds__(256) void k_count(const int* __restrict__ dst,
                                               int* __restrict__ counts) {
  int e = blockIdx.x * 256 + threadIdx.x;
  if (e < N_EDGES) atomicAdd(&counts[dst[e]], 1);
}

__global__ __launch_bounds__(256) void k_scan(const int* __restrict__ counts,
                                              int* __restrict__ row_ofs,
                                              int* __restrict__ cursor,
                                              float* __restrict__ invdeg) {
  __shared__ int chunk[256];
  const int per = (N_NODES + 255) / 256;  // 32
  int t = threadIdx.x;
  int base = t * per;
  int s = 0;
  for (int i = 0; i < per; ++i) {
    int idx = base + i;
    if (idx < N_NODES) s += counts[idx];
  }
  chunk[t] = s;
  __syncthreads();
  for (int off = 1; off < 256; off <<= 1) {
    int v = 0;
    if (t >= off) v = chunk[t - off];
    __syncthreads();
    if (t >= off) chunk[t] += v;
    __syncthreads();
  }
  int run = (t > 0) ? chunk[t - 1] : 0;
  for (int i = 0; i < per; ++i) {
    int idx = base + i;
    if (idx < N_NODES) {
      row_ofs[idx] = run;
      cursor[idx] = run;
      int c = counts[idx];
      invdeg[idx] = 1.0f / (float)(c > 1 ? c : 1);
      run += c;
    }
  }
  if (t == 0) row_ofs[N_NODES] = chunk[255];
}

__global__ __launch_bounds__(256) void k_fill(const int* __restrict__ src,
                                              const int* __restrict__ dst,
                                              int* __restrict__ cursor,
                                              int* __restrict__ csr_src) {
  int e = blockIdx.x * 256 + threadIdx.x;
  if (e < N_EDGES) {
    int p = atomicAdd(&cursor[dst[e]], 1);
    csr_src[p] = src[e];
  }
}

// ---------------------------------------------------------------------------
// Softmax over architecture rows; wsoft: [0..23]=wf, [24..39]=wm, [40..79]=wl
// ---------------------------------------------------------------------------
__global__ __launch_bounds__(64) void k_softmax(const float* __restrict__ af,
                                                const float* __restrict__ am,
                                                const float* __restrict__ al,
                                                float* __restrict__ w) {
  int t = threadIdx.x;
  const float* sp;
  float* dp;
  if (t < 6)       { sp = af + t * 4;        dp = w + t * 4; }
  else if (t < 10) { sp = am + (t - 6) * 4;  dp = w + 24 + (t - 6) * 4; }
  else if (t < 20) { sp = al + (t - 10) * 4; dp = w + 40 + (t - 10) * 4; }
  else return;
  float a0 = sp[0], a1 = sp[1], a2 = sp[2], a3 = sp[3];
  float m = fmaxf(fmaxf(a0, a1), fmaxf(a2, a3));
  float e0 = expf(a0 - m), e1 = expf(a1 - m), e2 = expf(a2 - m), e3 = expf(a3 - m);
  float si = 1.0f / (e0 + e1 + e2 + e3);
  dp[0] = e0 * si; dp[1] = e1 * si; dp[2] = e2 * si; dp[3] = e3 * si;
}

// ---------------------------------------------------------------------------
// Conversions
// ---------------------------------------------------------------------------
__global__ __launch_bounds__(256) void k_cvt_bf16(const float* __restrict__ in,
                                                  unsigned short* __restrict__ out,
                                                  int n) {
  int i = blockIdx.x * 256 + threadIdx.x;
  if (i < n) out[i] = (unsigned short)f2bf(in[i]);
}

// 32 DIMxDIM cell weights (coef-prescaled, reads wsoft) + z==32: W_emb^T.
__global__ __launch_bounds__(256) void k_transpose_cvt33(const float* __restrict__ Wfd,
                                                         const float* __restrict__ Wfs,
                                                         const float* __restrict__ Wld,
                                                         const float* __restrict__ Wls,
                                                         const float* __restrict__ wsoft,
                                                         unsigned short* __restrict__ out,
                                                         const float* __restrict__ W_emb,
                                                         unsigned short* __restrict__ WTe) {
  __shared__ float tile[32][33];
  int z = blockIdx.z;
  int tx = threadIdx.x & 31, ty = threadIdx.x >> 5;
  if (z == 32) {
    // W_emb: f32 [IN_DIM=128][DIM=256] -> bf16 [256][128]; 4 k-tiles x 8 n-tiles
    if (blockIdx.x >= 4) return;  // block-uniform early return
    int k0 = blockIdx.x * 32, n0 = blockIdx.y * 32;
#pragma unroll
    for (int i = 0; i < 4; ++i)
      tile[ty + 8 * i][tx] = W_emb[(size_t)(k0 + ty + 8 * i) * DIM + n0 + tx];
    __syncthreads();
#pragma unroll
    for (int i = 0; i < 4; ++i)
      WTe[(size_t)(n0 + ty + 8 * i) * IN_DIM + k0 + tx] =
          (unsigned short)f2bf(tile[tx][ty + 8 * i]);
    return;
  }
  const float* in;
  float coef;
  const float* wf = wsoft;
  const float* wl = wsoft + 40;
  if (z < 6)       { in = Wfd + (size_t)z * DIM * DIM;        coef = wf[z * 4 + 2]; }
  else if (z < 12) { in = Wfs + (size_t)(z - 6) * DIM * DIM;  coef = wf[(z - 6) * 4 + 3]; }
  else if (z < 22) { in = Wld + (size_t)(z - 12) * DIM * DIM; coef = wl[(z - 12) * 4 + 2]; }
  else             { in = Wls + (size_t)(z - 22) * DIM * DIM; coef = wl[(z - 22) * 4 + 3]; }
  unsigned short* o = out + (size_t)z * DIM * DIM;
  int k0 = blockIdx.x * 32, n0 = blockIdx.y * 32;
#pragma unroll
  for (int i = 0; i < 4; ++i)
    tile[ty + 8 * i][tx] = in[(size_t)(k0 + ty + 8 * i) * DIM + n0 + tx];
  __syncthreads();
#pragma unroll
  for (int i = 0; i < 4; ++i)
    o[(size_t)(n0 + ty + 8 * i) * DIM + k0 + tx] =
        (unsigned short)f2bf(coef * tile[tx][ty + 8 * i]);
}

// ---------------------------------------------------------------------------
// Segment reductions (bf16). One wave per node, 4 nodes/block, 8-edge unroll.
// ---------------------------------------------------------------------------
#define SEG_ACC(u) \
  { s0 += bf2f((u).x & 0xffffu); s1 += bf2f((u).x >> 16); \
    s2 += bf2f((u).y & 0xffffu); s3 += bf2f((u).y >> 16); }

#define MID_ACC(u) \
  { float v0 = bf2f((u).x & 0xffffu), v1 = bf2f((u).x >> 16); \
    float v2 = bf2f((u).y & 0xffffu), v3 = bf2f((u).y >> 16); \
    s0 += v0; s1 += v1; s2 += v2; s3 += v3; \
    m0 = fmaxf(m0, v0); m1 = fmaxf(m1, v1); \
    m2 = fmaxf(m2, v2); m3 = fmaxf(m3, v3); }

__global__ __launch_bounds__(256) void k_segmean_bf(const unsigned short* __restrict__ X,
                                                    const int* __restrict__ row_ofs,
                                                    const int* __restrict__ csr_src,
                                                    const float* __restrict__ invdeg,
                                                    unsigned short* __restrict__ out) {
  int node = blockIdx.x * 4 + (threadIdx.x >> 6);
  int l = threadIdx.x & 63;
  if (node >= N_NODES) return;
  int beg = row_ofs[node], end = row_ofs[node + 1];
  float s0 = 0.f, s1 = 0.f, s2 = 0.f, s3 = 0.f;
  int e = beg;
  for (; e + 8 <= end; e += 8) {
    int i0 = csr_src[e], i1 = csr_src[e + 1], i2 = csr_src[e + 2], i3 = csr_src[e + 3];
    int i4 = csr_src[e + 4], i5 = csr_src[e + 5], i6 = csr_src[e + 6], i7 = csr_src[e + 7];
    uint2 u0 = *(const uint2*)&X[(size_t)i0 * DIM + 4 * l];
    uint2 u1 = *(const uint2*)&X[(size_t)i1 * DIM + 4 * l];
    uint2 u2 = *(const uint2*)&X[(size_t)i2 * DIM + 4 * l];
    uint2 u3 = *(const uint2*)&X[(size_t)i3 * DIM + 4 * l];
    uint2 u4 = *(const uint2*)&X[(size_t)i4 * DIM + 4 * l];
    uint2 u5 = *(const uint2*)&X[(size_t)i5 * DIM + 4 * l];
    uint2 u6 = *(const uint2*)&X[(size_t)i6 * DIM + 4 * l];
    uint2 u7 = *(const uint2*)&X[(size_t)i7 * DIM + 4 * l];
    SEG_ACC(u0) SEG_ACC(u1) SEG_ACC(u2) SEG_ACC(u3)
    SEG_ACC(u4) SEG_ACC(u5) SEG_ACC(u6) SEG_ACC(u7)
  }
  for (; e + 4 <= end; e += 4) {
    int i0 = csr_src[e], i1 = csr_src[e + 1], i2 = csr_src[e + 2], i3 = csr_src[e + 3];
    uint2 u0 = *(const uint2*)&X[(size_t)i0 * DIM + 4 * l];
    uint2 u1 = *(const uint2*)&X[(size_t)i1 * DIM + 4 * l];
    uint2 u2 = *(const uint2*)&X[(size_t)i2 * DIM + 4 * l];
    uint2 u3 = *(const uint2*)&X[(size_t)i3 * DIM + 4 * l];
    SEG_ACC(u0) SEG_ACC(u1) SEG_ACC(u2) SEG_ACC(u3)
  }
  for (; e < end; ++e) {
    uint2 u = *(const uint2*)&X[(size_t)csr_src[e] * DIM + 4 * l];
    SEG_ACC(u)
  }
  float iv = invdeg[node];
  uint2 o;
  o.x = f2bf(s0 * iv) | (f2bf(s1 * iv) << 16);
  o.y = f2bf(s2 * iv) | (f2bf(s3 * iv) << 16);
  *(uint2*)&out[(size_t)node * DIM + 4 * l] = o;
}

__global__ __launch_bounds__(256) void k_segmean2_bf(const unsigned short* __restrict__ X0,
                                                     const unsigned short* __restrict__ X1,
                                                     const int* __restrict__ row_ofs,
                                                     const int* __restrict__ csr_src,
                                                     const float* __restrict__ invdeg,
                                                     unsigned short* __restrict__ out0,
                                                     unsigned short* __restrict__ out1) {
  int node = blockIdx.x * 4 + (threadIdx.x >> 6);
  int l = threadIdx.x & 63;
  if (node >= N_NODES) return;
  int beg = row_ofs[node], end = row_ofs[node + 1];
  float a0 = 0.f, a1 = 0.f, a2 = 0.f, a3 = 0.f;
  float b0 = 0.f, b1 = 0.f, b2 = 0.f, b3 = 0.f;
  int e = beg;
  for (; e + 4 <= end; e += 4) {
    size_t r0 = (size_t)csr_src[e] * DIM + 4 * l;
    size_t r1 = (size_t)csr_src[e + 1] * DIM + 4 * l;
    size_t r2 = (size_t)csr_src[e + 2] * DIM + 4 * l;
    size_t r3 = (size_t)csr_src[e + 3] * DIM + 4 * l;
    uint2 u0 = *(const uint2*)&X0[r0];
    uint2 u1 = *(const uint2*)&X0[r1];
    uint2 u2 = *(const uint2*)&X0[r2];
    uint2 u3 = *(const uint2*)&X0[r3];
    uint2 v0 = *(const uint2*)&X1[r0];
    uint2 v1 = *(const uint2*)&X1[r1];
    uint2 v2 = *(const uint2*)&X1[r2];
    uint2 v3 = *(const uint2*)&X1[r3];
    a0 += bf2f(u0.x & 0xffffu) + bf2f(u1.x & 0xffffu) + bf2f(u2.x & 0xffffu) + bf2f(u3.x & 0xffffu);
    a1 += bf2f(u0.x >> 16) + bf2f(u1.x >> 16) + bf2f(u2.x >> 16) + bf2f(u3.x >> 16);
    a2 += bf2f(u0.y & 0xffffu) + bf2f(u1.y & 0xffffu) + bf2f(u2.y & 0xffffu) + bf2f(u3.y & 0xffffu);
    a3 += bf2f(u0.y >> 16) + bf2f(u1.y >> 16) + bf2f(u2.y >> 16) + bf2f(u3.y >> 16);
    b0 += bf2f(v0.x & 0xffffu) + bf2f(v1.x & 0xffffu) + bf2f(v2.x & 0xffffu) + bf2f(v3.x & 0xffffu);
    b1 += bf2f(v0.x >> 16) + bf2f(v1.x >> 16) + bf2f(v2.x >> 16) + bf2f(v3.x >> 16);
    b2 += bf2f(v0.y & 0xffffu) + bf2f(v1.y & 0xffffu) + bf2f(v2.y & 0xffffu) + bf2f(v3.y & 0xffffu);
    b3 += bf2f(v0.y >> 16) + bf2f(v1.y >> 16) + bf2f(v2.y >> 16) + bf2f(v3.y >> 16);
  }
  for (; e < end; ++e) {
    size_t rb = (size_t)csr_src[e] * DIM + 4 * l;
    uint2 u = *(const uint2*)&X0[rb];
    uint2 v = *(const uint2*)&X1[rb];
    a0 += bf2f(u.x & 0xffffu); a1 += bf2f(u.x >> 16);
    a2 += bf2f(u.y & 0xffffu); a3 += bf2f(u.y >> 16);
    b0 += bf2f(v.x & 0xffffu); b1 += bf2f(v.x >> 16);
    b2 += bf2f(v.y & 0xffffu); b3 += bf2f(v.y >> 16);
  }
  float iv = invdeg[node];
  uint2 o;
  o.x = f2bf(a0 * iv) | (f2bf(a1 * iv) << 16);
  o.y = f2bf(a2 * iv) | (f2bf(a3 * iv) << 16);
  *(uint2*)&out0[(size_t)node * DIM + 4 * l] = o;
  o.x = f2bf(b0 * iv) | (f2bf(b1 * iv) << 16);
  o.y = f2bf(b2 * iv) | (f2bf(b3 * iv) << 16);
  *(uint2*)&out1[(size_t)node * DIM + 4 * l] = o;
}

// sum+max over incoming msgs of relu'd input; epilogue = middle-stage mixture.
__global__ __launch_bounds__(256) void k_segmid_bf(const unsigned short* __restrict__ Xn,
                                                   const int* __restrict__ row_ofs,
                                                   const int* __restrict__ csr_src,
                                                   const float* __restrict__ invdeg,
                                                   const float* __restrict__ wrow,
                                                   unsigned short* __restrict__ mean_out,
                                                   unsigned short* __restrict__ mids_out) {
  int node = blockIdx.x * 4 + (threadIdx.x >> 6);
  int l = threadIdx.x & 63;
  if (node >= N_NODES) return;
  int beg = row_ofs[node], end = row_ofs[node + 1];
  float s0 = 0.f, s1 = 0.f, s2 = 0.f, s3 = 0.f;
  float m0 = 0.f, m1 = 0.f, m2 = 0.f, m3 = 0.f;  // inputs >= 0 (relu)
  int e = beg;
  for (; e + 8 <= end; e += 8) {
    int i0 = csr_src[e], i1 = csr_src[e + 1], i2 = csr_src[e + 2], i3 = csr_src[e + 3];
    int i4 = csr_src[e + 4], i5 = csr_src[e + 5], i6 = csr_src[e + 6], i7 = csr_src[e + 7];
    uint2 u0 = *(const uint2*)&Xn[(size_t)i0 * DIM + 4 * l];
    uint2 u1 = *(const uint2*)&Xn[(size_t)i1 * DIM + 4 * l];
    uint2 u2 = *(const uint2*)&Xn[(size_t)i2 * DIM + 4 * l];
    uint2 u3 = *(const uint2*)&Xn[(size_t)i3 * DIM + 4 * l];
    uint2 u4 = *(const uint2*)&Xn[(size_t)i4 * DIM + 4 * l];
    uint2 u5 = *(const uint2*)&Xn[(size_t)i5 * DIM + 4 * l];
    uint2 u6 = *(const uint2*)&Xn[(size_t)i6 * DIM + 4 * l];
    uint2 u7 = *(const uint2*)&Xn[(size_t)i7 * DIM + 4 * l];
    MID_ACC(u0) MID_ACC(u1) MID_ACC(u2) MID_ACC(u3)
    MID_ACC(u4) MID_ACC(u5) MID_ACC(u6) MID_ACC(u7)
  }
  for (; e + 4 <= end; e += 4) {
    int i0 = csr_src[e], i1 = csr_src[e + 1], i2 = csr_src[e + 2], i3 = csr_src[e + 3];
    uint2 u0 = *(const uint2*)&Xn[(size_t)i0 * DIM + 4 * l];
    uint2 u1 = *(const uint2*)&Xn[(size_t)i1 * DIM + 4 * l];
    uint2 u2 = *(const uint2*)&Xn[(size_t)i2 * DIM + 4 * l];
    uint2 u3 = *(const uint2*)&Xn[(size_t)i3 * DIM + 4 * l];
    MID_ACC(u0) MID_ACC(u1) MID_ACC(u2) MID_ACC(u3)
  }
  for (; e < end; ++e) {
    uint2 u = *(const uint2*)&Xn[(size_t)csr_src[e] * DIM + 4 * l];
    MID_ACC(u)
  }
  float iv = invdeg[node];
  float e0 = s0 * iv, e1 = s1 * iv, e2 = s2 * iv, e3 = s3 * iv;
  if (mean_out) {
    uint2 o;
    o.x = f2bf(e0) | (f2bf(e1) << 16);
    o.y = f2bf(e2) | (f2bf(e3) << 16);
    *(uint2*)&mean_out[(size_t)node * DIM + 4 * l] = o;
  }
  float w0 = wrow[0], w1 = wrow[1], w2 = wrow[2], w3 = wrow[3];
  uint2 xu = *(const uint2*)&Xn[(size_t)node * DIM + 4 * l];
  float x0 = bf2f(xu.x & 0xffffu), x1 = bf2f(xu.x >> 16);
  float x2 = bf2f(xu.y & 0xffffu), x3 = bf2f(xu.y >> 16);
  uint2 o;
  o.x = f2bf(w0 * x0 + w1 * m0 + w2 * e0 + w3 * s0) |
        (f2bf(w0 * x1 + w1 * m1 + w2 * e1 + w3 * s1) << 16);
  o.y = f2bf(w0 * x2 + w1 * m2 + w2 * e2 + w3 * s2) |
        (f2bf(w0 * x3 + w1 * m3 + w2 * e3 + w3 * s3) << 16);
  *(uint2*)&mids_out[(size_t)node * DIM + 4 * l] = o;
}

// ---------------------------------------------------------------------------
// Wide MFMA multi-term GEMM with per-column-half epilogues (N = 256*nhalves).
// 2-deep register prefetch pipeline: loads for step s+2 are issued at step s,
// stored to LDS at step s+1 (a full step of latency cover). nsteps is even.
// ---------------------------------------------------------------------------
struct GemmDescW {
  const unsigned short* A[4];
  const unsigned short* W[2][4];
  const float* b[2][4];
  const float* c[2][4];
  const unsigned short* I[2];
  const float* ic[2][2];
  const float* pre[2];            // f32 pre-accumulated partial
  const float* resid[2];
  const unsigned short* addl[2];
  float* out_f32[2];
  unsigned short* out_bf[2];
  int nmat, nid, K, relu[2], colshift;
};

__global__ __launch_bounds__(256) void k_gemm_mfma(GemmDescW d) {
  __shared__ __align__(16) unsigned short As[2][64][72];
  __shared__ __align__(16) unsigned short Bs[2][64][72];
  const int tid = threadIdx.x;
  const int b = blockIdx.x;
  const int cs = d.colshift;
  const int c = (b >> 3) & ((1 << cs) - 1);
  const int bm = ((b & 7) + 8 * (b >> (3 + cs))) * 64;
  const int half = c >> 2;
  const int bn = (c & 3) * 64;
  const int w = tid >> 6, l = tid & 63;
  const int wm = (w >> 1) * 32, wn = (w & 1) * 32;
  const int lr = l & 15, lk = (l >> 4) * 8;
  const int ldr = tid >> 3, ldk = (tid & 7) * 8;

  const int K = d.K;
  const int kds = (K == 256) ? 2 : 1;
  const int kmask = (1 << kds) - 1;
  const int nsteps = d.nmat << kds;   // 2, 8, or 16 (always even, >= 2)

  f32x4 zero = {0.f, 0.f, 0.f, 0.f};
  f32x4 acc[2][2];
  acc[0][0] = zero; acc[0][1] = zero; acc[1][0] = zero; acc[1][1] = zero;

  auto gload = [&](int s, uint4& a0, uint4& a1, uint4& b0, uint4& b1) {
    int t = s >> kds;
    int k0 = (s & kmask) << 6;
    const unsigned short* __restrict__ A = d.A[t];
    const unsigned short* __restrict__ W = d.W[half][t];
    a0 = *(const uint4*)&A[(size_t)(bm + ldr) * K + k0 + ldk];
    a1 = *(const uint4*)&A[(size_t)(bm + ldr + 32) * K + k0 + ldk];
    b0 = *(const uint4*)&W[(size_t)(bn + ldr) * K + k0 + ldk];
    b1 = *(const uint4*)&W[(size_t)(bn + ldr + 32) * K + k0 + ldk];
  };
  auto lstore = [&](int buf, uint4 a0, uint4 a1, uint4 b0, uint4 b1) {
    *(uint4*)&As[buf][ldr][ldk] = a0;
    *(uint4*)&As[buf][ldr + 32][ldk] = a1;
    *(uint4*)&Bs[buf][ldr][ldk] = b0;
    *(uint4*)&Bs[buf][ldr + 32][ldk] = b1;
  };

  uint4 ra0, ra1, ra2, ra3;  // register set A (data for even steps)
  uint4 rb0, rb1, rb2, rb3;  // register set B (data for odd steps)

  // prologue: load step 0 and 1; stage step 0 into buf0
  gload(0, ra0, ra1, ra2, ra3);
  gload(1, rb0, rb1, rb2, rb3);
  lstore(0, ra0, ra1, ra2, ra3);
  __syncthreads();

#define MFMA_STEP(BUF)                                                            \
  {                                                                               \
    _Pragma("unroll")                                                             \
    for (int ks = 0; ks < 2; ++ks) {                                              \
      bf16x8 a0 = *(const bf16x8*)&As[BUF][wm + lr][ks * 32 + lk];                \
      bf16x8 a1 = *(const bf16x8*)&As[BUF][wm + 16 + lr][ks * 32 + lk];           \
      bf16x8 b0 = *(const bf16x8*)&Bs[BUF][wn + lr][ks * 32 + lk];                \
      bf16x8 b1 = *(const bf16x8*)&Bs[BUF][wn + 16 + lr][ks * 32 + lk];           \
      acc[0][0] = __builtin_amdgcn_mfma_f32_16x16x32_bf16(a0, b0, acc[0][0], 0, 0, 0); \
      acc[0][1] = __builtin_amdgcn_mfma_f32_16x16x32_bf16(a0, b1, acc[0][1], 0, 0, 0); \
      acc[1][0] = __builtin_amdgcn_mfma_f32_16x16x32_bf16(a1, b0, acc[1][0], 0, 0, 0); \
      acc[1][1] = __builtin_amdgcn_mfma_f32_16x16x32_bf16(a1, b1, acc[1][1], 0, 0, 0); \
    }                                                                             \
  }

  for (int s = 0; s < nsteps; s += 2) {
    // even step s: compute from buf0; issue loads for s+2; stage s+1 -> buf1
    if (s + 2 < nsteps) gload(s + 2, ra0, ra1, ra2, ra3);
    MFMA_STEP(0);
    lstore(1, rb0, rb1, rb2, rb3);   // s+1 < nsteps always (nsteps even)
    __syncthreads();
    // odd step s+1: compute from buf1; issue loads for s+3; stage s+2 -> buf0
    if (s + 3 < nsteps) gload(s + 3, rb0, rb1, rb2, rb3);
    MFMA_STEP(1);
    if (s + 2 < nsteps) lstore(0, ra0, ra1, ra2, ra3);
    __syncthreads();
  }
#undef MFMA_STEP

  // epilogue (per half)
  float bias[2] = {0.f, 0.f};
  for (int t = 0; t < d.nmat; ++t) {
    const float* bp = d.b[half][t];
    if (bp) {
      float cc = d.c[half][t] ? *d.c[half][t] : 1.0f;
      bias[0] += cc * bp[bn + wn + lr];
      bias[1] += cc * bp[bn + wn + 16 + lr];
    }
  }
  float vout[2][2][4];
#pragma unroll
  for (int m = 0; m < 2; ++m)
#pragma unroll
    for (int n = 0; n < 2; ++n)
#pragma unroll
      for (int i = 0; i < 4; ++i) vout[m][n][i] = acc[m][n][i] + bias[n];
#pragma unroll
  for (int u = 0; u < 2; ++u) {
    if (u < d.nid) {
      float icu = *d.ic[half][u];
      const unsigned short* __restrict__ I = d.I[u];
#pragma unroll
      for (int m = 0; m < 2; ++m)
#pragma unroll
        for (int n = 0; n < 2; ++n)
#pragma unroll
          for (int i = 0; i < 4; ++i) {
            int row = bm + wm + m * 16 + (l >> 4) * 4 + i;
            int col = bn + wn + n * 16 + lr;
            vout[m][n][i] += icu * bf2f(I[(size_t)row * DIM + col]);
          }
    }
  }
  const float* pre = d.pre[half];
  const float* resid = d.resid[half];
  const unsigned short* addl = d.addl[half];
  unsigned short* obf = d.out_bf[half];
  float* of32 = d.out_f32[half];
  const int do_relu = d.relu[half];
#pragma unroll
  for (int m = 0; m < 2; ++m)
#pragma unroll
    for (int n = 0; n < 2; ++n)
#pragma unroll
      for (int i = 0; i < 4; ++i) {
        int row = bm + wm + m * 16 + (l >> 4) * 4 + i;
        int col = bn + wn + n * 16 + lr;
        size_t idx = (size_t)row * DIM + col;
        float v = vout[m][n][i];
        if (pre) v += pre[idx];
        if (do_relu) v = fmaxf(v, 0.f);
        if (resid) v = resid[idx] + 0.5f * (bf2f(addl[idx]) + v);
        if (obf) obf[idx] = (unsigned short)f2bf(v);
        if (of32) of32[idx] = v;
      }
}

// ---------------------------------------------------------------------------
// Fused readout + MLP with 8-way ILP on the node-sum loop.
// ---------------------------------------------------------------------------
__global__ __launch_bounds__(256) void k_readout_mlp(const float* __restrict__ x,
                                                     const int* __restrict__ gid,
                                                     const float* __restrict__ C1,
                                                     const float* __restrict__ c1b,
                                                     const float* __restrict__ C2,
                                                     const float* __restrict__ c2b,
                                                     const float* __restrict__ C3,
                                                     const float* __restrict__ c3b,
                                                     float* __restrict__ out) {
  int g = blockIdx.x, t = threadIdx.x;
  int lo = 0, hi = N_NODES;
  while (lo < hi) { int m = (lo + hi) >> 1; if (gid[m] < g) lo = m + 1; else hi = m; }
  int beg = lo;
  lo = beg; hi = N_NODES;
  while (lo < hi) { int m = (lo + hi) >> 1; if (gid[m] <= g) lo = m + 1; else hi = m; }
  int end = lo;
  float s0 = 0.f, s1 = 0.f, s2 = 0.f, s3 = 0.f;
  float s4 = 0.f, s5 = 0.f, s6 = 0.f, s7 = 0.f;
  int i = beg;
  for (; i + 8 <= end; i += 8) {
    s0 += x[(size_t)(i + 0) * DIM + t];
    s1 += x[(size_t)(i + 1) * DIM + t];
    s2 += x[(size_t)(i + 2) * DIM + t];
    s3 += x[(size_t)(i + 3) * DIM + t];
    s4 += x[(size_t)(i + 4) * DIM + t];
    s5 += x[(size_t)(i + 5) * DIM + t];
    s6 += x[(size_t)(i + 6) * DIM + t];
    s7 += x[(size_t)(i + 7) * DIM + t];
  }
  for (; i < end; ++i) s0 += x[(size_t)i * DIM + t];
  float s = ((s0 + s1) + (s2 + s3)) + ((s4 + s5) + (s6 + s7));
  int cnt = end - beg;
  __shared__ float h0[256], h1[128], h2[64];
  h0[t] = s / (float)(cnt > 1 ? cnt : 1);
  __syncthreads();
  if (t < 128) {
    float v = c1b[t];
    for (int k = 0; k < 256; ++k) v = fmaf(h0[k], C1[k * 128 + t], v);
    h1[t] = fmaxf(v, 0.f);
  }
  __syncthreads();
  if (t < 64) {
    float v = c2b[t];
    for (int k = 0; k < 128; ++k) v = fmaf(h1[k], C2[k * 64 + t], v);
    h2[t] = fmaxf(v, 0.f);
  }
  __syncthreads();
  if (t < 10) {
    float v = c3b[t];
    for (int k = 0; k < 64; ++k) v = fmaf(h2[k], C3[k * 10 + t], v);
    out[g * 10 + t] = v;
  }
}

// ---------------------------------------------------------------------------
extern "C" void kernel_launch(void* const* d_in, const int* in_sizes, int n_in,
                              void* d_out, int out_size, void* d_ws, size_t ws_size,
                              hipStream_t stream) {
  const float* h     = (const float*)d_in[0];
  const float* W_emb = (const float*)d_in[1];
  const float* b_emb = (const float*)d_in[2];
  const float* Wf_d  = (const float*)d_in[3];
  const float* bf_d  = (const float*)d_in[4];
  const float* Wf_s  = (const float*)d_in[5];
  const float* bf_s  = (const float*)d_in[6];
  const float* Wl_d  = (const float*)d_in[7];
  const float* bl_d  = (const float*)d_in[8];
  const float* Wl_s  = (const float*)d_in[9];
  const float* bl_s  = (const float*)d_in[10];
  const float* a_first = (const float*)d_in[11];
  const float* a_mid   = (const float*)d_in[12];
  const float* a_last  = (const float*)d_in[13];
  const float* C1 = (const float*)d_in[14];
  const float* c1b = (const float*)d_in[15];
  const float* C2 = (const float*)d_in[16];
  const float* c2b = (const float*)d_in[17];
  const float* C3 = (const float*)d_in[18];
  const float* c3b = (const float*)d_in[19];
  const int* src = (const int*)d_in[20];
  const int* dst = (const int*)d_in[21];
  const int* gid = (const int*)d_in[22];
  (void)in_sizes; (void)n_in; (void)out_size; (void)ws_size;

  char* p = (char*)d_ws;
  auto alloc = [&](size_t bytes) {
    void* r = (void*)p;
    p += (bytes + 255) & ~(size_t)255;
    return r;
  };
  typedef unsigned short u16;
  const size_t NBF = (size_t)M_PAD * DIM * sizeof(u16);
  float* x_f32  = (float*)alloc((size_t)M_PAD * DIM * sizeof(float));
  float* s2part = (float*)alloc((size_t)M_PAD * DIM * sizeof(float));
  float* xpart  = (float*)alloc((size_t)M_PAD * DIM * sizeof(float));
  u16* xb    = (u16*)alloc(NBF);
  u16* s1b   = (u16*)alloc(NBF);
  u16* s2b   = (u16*)alloc(NBF);
  u16* m0b   = (u16*)alloc(NBF);
  u16* m1b   = (u16*)alloc(NBF);
  u16* l0b   = (u16*)alloc(NBF);
  u16* aggAb = (u16*)alloc(NBF);
  u16* aggBb = (u16*)alloc(NBF);
  u16* h_bf  = (u16*)alloc((size_t)M_PAD * IN_DIM * sizeof(u16));
  u16* WT    = (u16*)alloc((size_t)(DIM * IN_DIM + 32 * DIM * DIM) * sizeof(u16));
  u16* WTe   = WT;
  u16* WTfd  = WT + DIM * IN_DIM;
  u16* WTfs  = WTfd + 6 * DIM * DIM;
  u16* WTld  = WTfs + 6 * DIM * DIM;
  u16* WTls  = WTld + 10 * DIM * DIM;
  float* invdeg = (float*)alloc(N_NODES * sizeof(float));
  int* counts  = (int*)alloc(N_NODES * sizeof(int));
  int* row_ofs = (int*)alloc((N_NODES + 1) * sizeof(int));
  int* cursor  = (int*)alloc(N_NODES * sizeof(int));
  int* csr_src = (int*)alloc(N_EDGES * sizeof(int));
  float* wsoft = (float*)alloc(80 * sizeof(float));

  const int EB = (N_EDGES + 255) / 256;

  // round-6 prep path (known good), transposes merged into one dispatch
  k_init<<<192, 256, 0, stream>>>(
      counts, h_bf + (size_t)N_NODES * IN_DIM,
      aggAb + (size_t)N_NODES * DIM, aggBb + (size_t)N_NODES * DIM,
      m0b + (size_t)N_NODES * DIM, m1b + (size_t)N_NODES * DIM);

  k_count<<<EB, 256, 0, stream>>>(dst, counts);
  k_scan<<<1, 256, 0, stream>>>(counts, row_ofs, cursor, invdeg);
  k_fill<<<EB, 256, 0, stream>>>(src, dst, cursor, csr_src);
  k_softmax<<<1, 64, 0, stream>>>(a_first, a_mid, a_last, wsoft);

  const float* wf = wsoft;
  const float* wm = wsoft + 24;
  const float* wl = wsoft + 40;

  k_cvt_bf16<<<(N_NODES * IN_DIM + 255) / 256, 256, 0, stream>>>(h, h_bf, N_NODES * IN_DIM);
  k_transpose_cvt33<<<dim3(8, 8, 33), 256, 0, stream>>>(Wf_d, Wf_s, Wl_d, Wl_s, wsoft,
                                                        WTfd, W_emb, WTe);

  const int GG1 = (M_PAD / 64) * 4;  // 512 blocks (N=256)
  const int GG2 = (M_PAD / 64) * 8;  // 1024 blocks (N=512)
  const int SB = (N_NODES + 3) / 4;

  // embedding: x = h @ W_emb + b_emb
  {
    GemmDescW d{};
    d.A[0] = h_bf; d.W[0][0] = WTe; d.b[0][0] = b_emb;
    d.nmat = 1; d.nid = 0; d.K = IN_DIM; d.colshift = 2;
    d.out_f32[0] = x_f32; d.out_bf[0] = xb;
    k_gemm_mfma<<<GG1, 256, 0, stream>>>(d);
  }

  for (int l = 0; l < 2; ++l) {
    auto WFD = [&](int e) { return WTfd + (size_t)(l * 3 + e) * DIM * DIM; };
    auto BFD = [&](int e) { return bf_d + (size_t)(l * 3 + e) * DIM; };
    auto WFS = [&](int e) { return WTfs + (size_t)(l * 3 + e) * DIM * DIM; };
    auto BFS = [&](int e) { return bf_s + (size_t)(l * 3 + e) * DIM; };
    auto WLD = [&](int e) { return WTld + (size_t)(l * 5 + e) * DIM * DIM; };
    auto BLD = [&](int e) { return bl_d + (size_t)(l * 5 + e) * DIM; };
    auto WLS = [&](int e) { return WTls + (size_t)(l * 5 + e) * DIM * DIM; };
    auto BLS = [&](int e) { return bl_s + (size_t)(l * 5 + e) * DIM; };
    auto WFrow = [&](int e) { return wf + (l * 3 + e) * 4; };
    auto WMrow = [&](int n) { return wm + (l * 2 + n) * 4; };
    auto WLrow = [&](int e) { return wl + (l * 5 + e) * 4; };

    // aggA = mean-agg(x)
    k_segmean_bf<<<SB, 256, 0, stream>>>(xb, row_ofs, csr_src, invdeg, aggAb);

    // G1 (wide): half0 -> s1 = relu(mixed(x,e0)); half1 -> s2part = mixed(x,e1) (f32)
    {
      GemmDescW d{};
      d.A[0] = xb; d.A[1] = aggAb; d.nmat = 2; d.K = DIM; d.colshift = 3;
      d.I[0] = xb; d.nid = 1;
      d.W[0][0] = WFD(0); d.b[0][0] = BFD(0); d.c[0][0] = WFrow(0) + 2;
      d.W[0][1] = WFS(0); d.b[0][1] = BFS(0); d.c[0][1] = WFrow(0) + 3;
      d.ic[0][0] = WFrow(0) + 1; d.relu[0] = 1; d.out_bf[0] = s1b;
      d.W[1][0] = WFD(1); d.b[1][0] = BFD(1); d.c[1][0] = WFrow(1) + 2;
      d.W[1][1] = WFS(1); d.b[1][1] = BFS(1); d.c[1][1] = WFrow(1) + 3;
      d.ic[1][0] = WFrow(1) + 1; d.relu[1] = 0; d.out_f32[1] = s2part;
      k_gemm_mfma<<<GG2, 256, 0, stream>>>(d);
    }

    // mid of s1: mean -> aggB; mixture -> m0
    k_segmid_bf<<<SB, 256, 0, stream>>>(s1b, row_ofs, csr_src, invdeg, WMrow(0), aggBb, m0b);

    // G2: s2 = relu(s2part + mixed(s1,e2))
    {
      GemmDescW d{};
      d.A[0] = s1b; d.A[1] = aggBb; d.nmat = 2; d.K = DIM; d.colshift = 2;
      d.I[0] = s1b; d.nid = 1;
      d.W[0][0] = WFD(2); d.b[0][0] = BFD(2); d.c[0][0] = WFrow(2) + 2;
      d.W[0][1] = WFS(2); d.b[0][1] = BFS(2); d.c[0][1] = WFrow(2) + 3;
      d.ic[0][0] = WFrow(2) + 1; d.pre[0] = s2part; d.relu[0] = 1; d.out_bf[0] = s2b;
      k_gemm_mfma<<<GG1, 256, 0, stream>>>(d);
    }

    // mid of s2 -> m1
    k_segmid_bf<<<SB, 256, 0, stream>>>(s2b, row_ofs, csr_src, invdeg, WMrow(1), nullptr, m1b);

    // mean-aggs of m0, m1
    k_segmean2_bf<<<SB, 256, 0, stream>>>(m0b, m1b, row_ofs, csr_src, invdeg, aggAb, aggBb);

    // G3 (wide): half0 -> l0 = relu(mixed(m0,e0)+mixed(m1,e1));
    //            half1 -> xpart = mixed(m0,e2)+mixed(m1,e3) (f32)
    {
      GemmDescW d{};
      d.A[0] = m0b; d.A[1] = aggAb; d.A[2] = m1b; d.A[3] = aggBb;
      d.nmat = 4; d.K = DIM; d.colshift = 3;
      d.I[0] = m0b; d.I[1] = m1b; d.nid = 2;
      d.W[0][0] = WLD(0); d.b[0][0] = BLD(0); d.c[0][0] = WLrow(0) + 2;
      d.W[0][1] = WLS(0); d.b[0][1] = BLS(0); d.c[0][1] = WLrow(0) + 3;
      d.W[0][2] = WLD(1); d.b[0][2] = BLD(1); d.c[0][2] = WLrow(1) + 2;
      d.W[0][3] = WLS(1); d.b[0][3] = BLS(1); d.c[0][3] = WLrow(1) + 3;
      d.ic[0][0] = WLrow(0) + 1; d.ic[0][1] = WLrow(1) + 1;
      d.relu[0] = 1; d.out_bf[0] = l0b;
      d.W[1][0] = WLD(2); d.b[1][0] = BLD(2); d.c[1][0] = WLrow(2) + 2;
      d.W[1][1] = WLS(2); d.b[1][1] = BLS(2); d.c[1][1] = WLrow(2) + 3;
      d.W[1][2] = WLD(3); d.b[1][2] = BLD(3); d.c[1][2] = WLrow(3) + 2;
      d.W[1][3] = WLS(3); d.b[1][3] = BLS(3); d.c[1][3] = WLrow(3) + 3;
      d.ic[1][0] = WLrow(2) + 1; d.ic[1][1] = WLrow(3) + 1;
      d.relu[1] = 0; d.out_f32[1] = xpart;
      k_gemm_mfma<<<GG2, 256, 0, stream>>>(d);
    }

    // mean-agg of l0 -> s1b (dead)
    k_segmean_bf<<<SB, 256, 0, stream>>>(l0b, row_ofs, csr_src, invdeg, s1b);

    // G4: x = x + 0.5*(l0 + relu(xpart + mixed(l0,e4)))
    {
      GemmDescW d{};
      d.A[0] = l0b; d.A[1] = s1b; d.nmat = 2; d.K = DIM; d.colshift = 2;
      d.I[0] = l0b; d.nid = 1;
      d.W[0][0] = WLD(4); d.b[0][0] = BLD(4); d.c[0][0] = WLrow(4) + 2;
      d.W[0][1] = WLS(4); d.b[0][1] = BLS(4); d.c[0][1] = WLrow(4) + 3;
      d.ic[0][0] = WLrow(4) + 1; d.pre[0] = xpart; d.relu[0] = 1;
      d.resid[0] = x_f32; d.addl[0] = l0b;
      d.out_f32[0] = x_f32; d.out_bf[0] = xb;
      k_gemm_mfma<<<GG1, 256, 0, stream>>>(d);
    }
  }

  k_readout_mlp<<<N_GRAPHS, 256, 0, stream>>>(x_f32, gid, C1, c1b, C2, c2b, C3, c3b,
                                              (float*)d_out);
}